// Round 12
// baseline (1258.207 us; speedup 1.0000x reference)
//
#include <hip/hip_runtime.h>
#include <math.h>

#define T_ 32
#define B_ 32
#define S_ 200
#define E_ 512
#define H_ 512
#define V_ 50000
#define VP_ 50176   // padded rows for chunk-major bf16 W
#define G4_ 2048
#define NCH 196     // ceil(50000/256)

using bf16x8 = __attribute__((ext_vector_type(8))) __bf16;
using f32x4  = __attribute__((ext_vector_type(4))) float;

__device__ __forceinline__ float sigf(float x) { return 1.f / (1.f + expf(-x)); }

__device__ __forceinline__ unsigned short f2bf(float v) {
    unsigned int x = __float_as_uint(v);
    return (unsigned short)((x + 0x7FFFu + ((x >> 16) & 1u)) >> 16);
}
__device__ __forceinline__ float bf2f(unsigned short b) {
    return __uint_as_float(((unsigned int)b) << 16);
}

// async global->LDS 16B copy
__device__ __forceinline__ void async16(void* lds, const void* g) {
    __builtin_amdgcn_global_load_lds(
        (const __attribute__((address_space(1))) unsigned int*)g,
        (__attribute__((address_space(3))) unsigned int*)lds, 16, 0, 0);
}

// Coherent LLC-level exchange (relaxed agent atomics -> sc1 load/store)
__device__ __forceinline__ void g_store(float* p, float v) {
    __hip_atomic_store(p, v, __ATOMIC_RELAXED, __HIP_MEMORY_SCOPE_AGENT);
}
__device__ __forceinline__ float g_load(const float* p) {
    return __hip_atomic_load(p, __ATOMIC_RELAXED, __HIP_MEMORY_SCOPE_AGENT);
}

// ---------------------------------------------------------------------------
// Fence-free grid barrier (proven rounds 5-11).
// ---------------------------------------------------------------------------
__device__ __forceinline__ void full_sync(int* bar, int ep) {
    __syncthreads();
    if (threadIdx.x == 0) {
        const int g = blockIdx.x & 7;
        int a = __hip_atomic_fetch_add(&bar[g * 32], 1, __ATOMIC_RELAXED, __HIP_MEMORY_SCOPE_AGENT);
        if (a == ep * 32 + 31) {
            int q = __hip_atomic_fetch_add(&bar[256], 1, __ATOMIC_RELAXED, __HIP_MEMORY_SCOPE_AGENT);
            if (q == ep * 8 + 7) {
                #pragma unroll
                for (int i = 0; i < 8; i++)
                    __hip_atomic_store(&bar[288 + i * 32], ep + 1, __ATOMIC_RELAXED, __HIP_MEMORY_SCOPE_AGENT);
            }
        }
        while (__hip_atomic_load(&bar[288 + g * 32], __ATOMIC_RELAXED, __HIP_MEMORY_SCOPE_AGENT) < ep + 1)
            __builtin_amdgcn_s_sleep(1);
    }
    __syncthreads();
}

// ---------------------------------------------------------------------------
// k_init: xT rows 0..511 att=0; rows 1024..1535 = last_state^T (h slot 1).
// ---------------------------------------------------------------------------
__global__ __launch_bounds__(256) void k_init(const float* __restrict__ last_state,
                                              float* __restrict__ xT) {
    const int f = blockIdx.x * 256 + threadIdx.x;   // 0..16383
    xT[f] = 0.f;
    const int k = f >> 5, b = f & 31;
    xT[32768 + f] = last_state[b * 512 + k];
}

// ---------------------------------------------------------------------------
// k_g0: G0T[j][m] = emb(tgt_in[m]) . W_ih[j][0:512] + b_ih[j] + b_hh[j]
// ---------------------------------------------------------------------------
__global__ __launch_bounds__(256) void k_g0(const int* __restrict__ tgt_in,
                                            const float* __restrict__ emb,
                                            const float* __restrict__ Wih,
                                            const float* __restrict__ bih,
                                            const float* __restrict__ bhh,
                                            float* __restrict__ G0T) {
    __shared__ float a_s[32][66];
    __shared__ float w_s[32][130];
    const int tid = threadIdx.x;
    const int m0 = blockIdx.x * 64, n0 = blockIdx.y * 128;
    const int mq = tid >> 5, nq = tid & 31;
    float acc[8][4] = {};
    for (int k0 = 0; k0 < 512; k0 += 32) {
        {
            const int mm = tid >> 2, kq = tid & 3, kk = kq * 8;
            const float* row = emb + (size_t)tgt_in[m0 + mm] * E_ + k0 + kk;
            float4 v0 = *(const float4*)(row);
            float4 v1 = *(const float4*)(row + 4);
            a_s[kk + 0][mm] = v0.x; a_s[kk + 1][mm] = v0.y;
            a_s[kk + 2][mm] = v0.z; a_s[kk + 3][mm] = v0.w;
            a_s[kk + 4][mm] = v1.x; a_s[kk + 5][mm] = v1.y;
            a_s[kk + 6][mm] = v1.z; a_s[kk + 7][mm] = v1.w;
        }
        {
            const int nn = tid >> 1, kq = tid & 1, kk = kq * 16;
            const float* row = Wih + (size_t)(n0 + nn) * 1024 + k0 + kk;
            #pragma unroll
            for (int u = 0; u < 4; u++) {
                float4 v = *(const float4*)(row + u * 4);
                w_s[kk + u * 4 + 0][nn] = v.x; w_s[kk + u * 4 + 1][nn] = v.y;
                w_s[kk + u * 4 + 2][nn] = v.z; w_s[kk + u * 4 + 3][nn] = v.w;
            }
        }
        __syncthreads();
        for (int k = 0; k < 32; k++) {
            float a[8], wv[4];
            #pragma unroll
            for (int i = 0; i < 8; i++) a[i] = a_s[k][mq + 8 * i];
            #pragma unroll
            for (int p = 0; p < 4; p++) wv[p] = w_s[k][nq + 32 * p];
            #pragma unroll
            for (int i = 0; i < 8; i++)
                #pragma unroll
                for (int p = 0; p < 4; p++) acc[i][p] += a[i] * wv[p];
        }
        __syncthreads();
    }
    #pragma unroll
    for (int i = 0; i < 8; i++) {
        const int m = m0 + mq + 8 * i;
        #pragma unroll
        for (int p = 0; p < 4; p++) {
            const int n = n0 + nq + 32 * p;
            G0T[(size_t)n * 1024 + m] = acc[i][p] + bih[n] + bhh[n];
        }
    }
}

// ---------------------------------------------------------------------------
// k_u: U[b,s,j] = src[b,s,:] . W_attn[j, 0:512]
// ---------------------------------------------------------------------------
__global__ __launch_bounds__(256) void k_u(const float* __restrict__ src,
                                           const float* __restrict__ Wattn,
                                           float* __restrict__ U) {
    __shared__ float a_s[32][66];
    __shared__ float w_s[32][130];
    const int tid = threadIdx.x;
    const int m0 = blockIdx.x * 64, n0 = blockIdx.y * 128;
    const int mq = tid >> 5, nq = tid & 31;
    float acc[8][4] = {};
    for (int k0 = 0; k0 < 512; k0 += 32) {
        {
            const int mm = tid >> 2, kq = tid & 3, kk = kq * 8;
            const float* row = src + (size_t)(m0 + mm) * 512 + k0 + kk;
            float4 v0 = *(const float4*)(row);
            float4 v1 = *(const float4*)(row + 4);
            a_s[kk + 0][mm] = v0.x; a_s[kk + 1][mm] = v0.y;
            a_s[kk + 2][mm] = v0.z; a_s[kk + 3][mm] = v0.w;
            a_s[kk + 4][mm] = v1.x; a_s[kk + 5][mm] = v1.y;
            a_s[kk + 6][mm] = v1.z; a_s[kk + 7][mm] = v1.w;
        }
        {
            const int nn = tid >> 1, kq = tid & 1, kk = kq * 16;
            const float* row = Wattn + (size_t)(n0 + nn) * 1024 + k0 + kk;
            #pragma unroll
            for (int u = 0; u < 4; u++) {
                float4 v = *(const float4*)(row + u * 4);
                w_s[kk + u * 4 + 0][nn] = v.x; w_s[kk + u * 4 + 1][nn] = v.y;
                w_s[kk + u * 4 + 2][nn] = v.z; w_s[kk + u * 4 + 3][nn] = v.w;
            }
        }
        __syncthreads();
        for (int k = 0; k < 32; k++) {
            float a[8], wv[4];
            #pragma unroll
            for (int i = 0; i < 8; i++) a[i] = a_s[k][mq + 8 * i];
            #pragma unroll
            for (int p = 0; p < 4; p++) wv[p] = w_s[k][nq + 32 * p];
            #pragma unroll
            for (int i = 0; i < 8; i++)
                #pragma unroll
                for (int p = 0; p < 4; p++) acc[i][p] += a[i] * wv[p];
        }
        __syncthreads();
    }
    #pragma unroll
    for (int i = 0; i < 8; i++) {
        const int m = m0 + mq + 8 * i;
        #pragma unroll
        for (int p = 0; p < 4; p++)
            U[(size_t)m * 512 + n0 + nq + 32 * p] = acc[i][p];
    }
}

// ---------------------------------------------------------------------------
// k_tr: WaRT[k][j] = W_attn[j][512+k]
// ---------------------------------------------------------------------------
__global__ __launch_bounds__(256) void k_tr(const float* __restrict__ Wattn,
                                            float* __restrict__ WaRT) {
    __shared__ float t_s[32][33];
    const int tid = threadIdx.x;
    const int bx = blockIdx.x, by = blockIdx.y;
    {
        const int jj = tid >> 3, kq = (tid & 7) * 4;
        float4 v = *(const float4*)(Wattn + (size_t)(by * 32 + jj) * 1024 + 512 + bx * 32 + kq);
        t_s[jj][kq + 0] = v.x; t_s[jj][kq + 1] = v.y;
        t_s[jj][kq + 2] = v.z; t_s[jj][kq + 3] = v.w;
    }
    __syncthreads();
    {
        const int kk = tid >> 3, jq = (tid & 7) * 4;
        float4 w;
        w.x = t_s[jq + 0][kk]; w.y = t_s[jq + 1][kk];
        w.z = t_s[jq + 2][kk]; w.w = t_s[jq + 3][kk];
        *(float4*)(WaRT + (size_t)(bx * 32 + kk) * 512 + by * 32 + jq) = w;
    }
}

// ---------------------------------------------------------------------------
// k_wconv: Wread fp32 -> bf16 hi/lo, chunk-major with BAKED bank swizzle.
// ---------------------------------------------------------------------------
__global__ __launch_bounds__(256) void k_wconv(const float* __restrict__ Wread,
                                               unsigned short* __restrict__ whk,
                                               unsigned short* __restrict__ wlk) {
    const size_t q = (size_t)blockIdx.x * 256 + threadIdx.x;
    const size_t k8 = q * 8;
    const int n = (int)(k8 >> 9);
    const int k = (int)(k8 & 511);
    if (n >= VP_) return;
    uint4 h4, l4;
    if (n < V_) {
        float4 p0 = *(const float4*)(Wread + (size_t)n * 512 + k);
        float4 p1 = *(const float4*)(Wread + (size_t)n * 512 + k + 4);
        float v[8] = {p0.x, p0.y, p0.z, p0.w, p1.x, p1.y, p1.z, p1.w};
        unsigned int hb[8], lb[8];
        #pragma unroll
        for (int e = 0; e < 8; e++) {
            hb[e] = f2bf(v[e]);
            lb[e] = f2bf(v[e] - bf2f((unsigned short)hb[e]));
        }
        h4 = make_uint4(hb[0] | (hb[1] << 16), hb[2] | (hb[3] << 16),
                        hb[4] | (hb[5] << 16), hb[6] | (hb[7] << 16));
        l4 = make_uint4(lb[0] | (lb[1] << 16), lb[2] | (lb[3] << 16),
                        lb[4] | (lb[5] << 16), lb[6] | (lb[7] << 16));
    } else {
        h4 = make_uint4(0, 0, 0, 0);
        l4 = make_uint4(0, 0, 0, 0);
    }
    const int lk = (k >> 3) & 3;
    const size_t dst = (size_t)(k >> 5) * ((size_t)VP_ * 32) + (size_t)n * 32
                     + (size_t)((lk ^ ((n >> 1) & 3)) * 8);
    *(uint4*)(whk + dst) = h4;
    *(uint4*)(wlk + dst) = l4;
}

// ---------------------------------------------------------------------------
// Persistent scan, 2 syncs/step. 256 blocks x 512 threads.
// Phase A: gates + pointwise (unchanged, proven). Phase B'C: each block
// computes ALL 200 scores locally (8x redundant, same-XCD L2-shared src),
// softmax + att slice in one phase -> sub_sync and scb eliminated.
// ---------------------------------------------------------------------------
__global__ __launch_bounds__(512) void k_scan(const float* __restrict__ G0T,
                                              const float* __restrict__ U,
                                              const float* __restrict__ WaRT,
                                              const float* __restrict__ Wih,
                                              const float* __restrict__ Whh,
                                              const float* __restrict__ src,
                                              const int* __restrict__ lens,
                                              const float* __restrict__ last_cell,
                                              float* __restrict__ xT,
                                              float* __restrict__ h_b,
                                              float* __restrict__ h_hist,
                                              float* __restrict__ att_hist,
                                              int* __restrict__ bar) {
    __shared__ float Wl[8 * 1024];
    __shared__ float Ul[200 * 64];
    __shared__ float red_s[2048];
    __shared__ float gate_s[256];
    __shared__ float h_s[512];
    __shared__ float sc_s[200];
    __shared__ float al[256];
    __shared__ float pr[512];

    const int blk = blockIdx.x, tid = threadIdx.x;
    const int u0 = blk * 2;
    const int bb = blk & 31, p = blk >> 5;

    for (int f = tid; f < 2048; f += 512) {
        const int r = f >> 8, k = (f & 255) * 4;
        const int j = (r >> 1) * 512 + u0 + (r & 1);
        float4 v;
        if (k < 512) v = *(const float4*)(Wih + (size_t)j * 1024 + 512 + k);
        else         v = *(const float4*)(Whh + (size_t)j * 512 + (k - 512));
        *(float4*)&Wl[r * 1024 + k] = v;
    }
    for (int f = tid; f < 3200; f += 512) {
        const int s = f >> 4, q = (f & 15) * 4;
        *(float4*)&Ul[s * 64 + q] = *(const float4*)(U + ((size_t)bb * S_ + s) * 512 + p * 64 + q);
    }
    float creg = (tid < 64) ? last_cell[(tid & 31) * 512 + u0 + (tid >> 5)] : 0.f;
    __syncthreads();

    const int w = tid >> 6, lane = tid & 63;
    const int hf = lane >> 5, b = lane & 31;
    const int len = lens[bb];

    for (int t = 0; t < T_; t++) {
        // -------- Phase A: gates + pointwise ------------------------------
        {
            const int hoff = ((t + 1) & 1) * 512;        // slot holding h(t-1)
            const int kbase = w * 128 + hf * 64;
            const float* xp = (kbase < 512)
                ? (xT + (size_t)kbase * 32 + b)
                : (xT + (size_t)(512 + hoff + (kbase - 512)) * 32 + b);
            float acc[8] = {};
            #pragma unroll
            for (int kk = 0; kk < 64; kk += 8) {
                float xv[8];
                #pragma unroll
                for (int i = 0; i < 8; i++)
                    xv[i] = g_load(xp + (size_t)(kk + i) * 32);
                #pragma unroll
                for (int r = 0; r < 8; r++) {
                    const float* wr = &Wl[r * 1024 + kbase + kk];
                    float s0 = xv[0] * wr[0] + xv[1] * wr[1] + xv[2] * wr[2] + xv[3] * wr[3];
                    float s1 = xv[4] * wr[4] + xv[5] * wr[5] + xv[6] * wr[6] + xv[7] * wr[7];
                    acc[r] += s0 + s1;
                }
            }
            #pragma unroll
            for (int r = 0; r < 8; r++) acc[r] += __shfl_xor(acc[r], 32);
            if (hf == 0) {
                #pragma unroll
                for (int r = 0; r < 8; r++) red_s[w * 256 + r * 32 + b] = acc[r];
            }
            __syncthreads();
            if (tid < 256) {
                const int r = tid >> 5, b2 = tid & 31;
                const int j = (r >> 1) * 512 + u0 + (r & 1);
                float g = G0T[(size_t)j * 1024 + t * 32 + b2];
                #pragma unroll
                for (int ww = 0; ww < 8; ww++) g += red_s[ww * 256 + r * 32 + b2];
                gate_s[r * 32 + b2] = g;
            }
            __syncthreads();
            if (tid < 64) {
                const int ui = tid >> 5, b2 = tid & 31, u = u0 + ui;
                const float gi = gate_s[(0 + ui) * 32 + b2];
                const float gf = gate_s[(2 + ui) * 32 + b2];
                const float gg = gate_s[(4 + ui) * 32 + b2];
                const float go = gate_s[(6 + ui) * 32 + b2];
                const float cn = sigf(gf) * creg + sigf(gi) * tanhf(gg);
                const float hn = sigf(go) * tanhf(cn);
                creg = cn;
                g_store(&xT[(size_t)(512 + (t & 1) * 512 + u) * 32 + b2], hn);
                g_store(&h_b[b2 * 512 + u], hn);
                h_hist[((size_t)t * B_ + b2) * 512 + u] = hn;
            }
        }
        full_sync(bar, 2 * t);

        // -------- Phase B'C: local scores + softmax + att slice -----------
        {
            h_s[tid] = g_load(&h_b[bb * 512 + tid]);
            __syncthreads();
            for (int s = w; s < S_; s += 8) {
                const float* sr = src + ((size_t)bb * S_ + s) * 512;
                const float4 x0 = *(const float4*)(sr + lane * 4);
                const float4 x1 = *(const float4*)(sr + 256 + lane * 4);
                const float4 h0 = *(const float4*)(&h_s[lane * 4]);
                const float4 h1 = *(const float4*)(&h_s[256 + lane * 4]);
                float a = x0.x * h0.x + x0.y * h0.y + x0.z * h0.z + x0.w * h0.w
                        + x1.x * h1.x + x1.y * h1.y + x1.z * h1.z + x1.w * h1.w;
                #pragma unroll
                for (int mk = 1; mk < 64; mk <<= 1) a += __shfl_xor(a, mk);
                if (lane == 0) sc_s[s] = (s < len) ? a : -INFINITY;
            }
            __syncthreads();
            if (tid < 64) {
                const float v0 = sc_s[tid];
                const float v1 = sc_s[64 + tid];
                const float v2 = sc_s[128 + tid];
                const float v3 = (tid < 8) ? sc_s[192 + tid] : -INFINITY;
                float m = fmaxf(fmaxf(v0, v1), fmaxf(v2, v3));
                #pragma unroll
                for (int mk = 1; mk < 64; mk <<= 1) m = fmaxf(m, __shfl_xor(m, mk));
                const float e0 = expf(v0 - m), e1 = expf(v1 - m), e2 = expf(v2 - m);
                const float e3 = (tid < 8) ? expf(v3 - m) : 0.f;
                float sum = (e0 + e1) + (e2 + e3);
                #pragma unroll
                for (int mk = 1; mk < 64; mk <<= 1) sum += __shfl_xor(sum, mk);
                const float inv = 1.f / sum;
                al[tid] = e0 * inv; al[64 + tid] = e1 * inv; al[128 + tid] = e2 * inv;
                if (tid < 8) al[192 + tid] = e3 * inv;
            }
            __syncthreads();
            const int jl = tid & 63, sg = tid >> 6;
            float uacc = 0.f;
            #pragma unroll 5
            for (int s = sg * 25; s < sg * 25 + 25; s++)
                uacc += al[s] * Ul[s * 64 + jl];
            const float* wc0 = WaRT + (size_t)(sg * 64) * 512 + p * 64 + jl;
            const float* hp = &h_s[sg * 64];
            float c0 = 0.f, c1 = 0.f;
            #pragma unroll 8
            for (int kk = 0; kk < 64; kk += 2) {
                c0 += hp[kk] * wc0[(size_t)kk * 512];
                c1 += hp[kk + 1] * wc0[(size_t)(kk + 1) * 512];
            }
            pr[tid] = uacc + c0 + c1;
            __syncthreads();
            if (tid < 64) {
                float tot = 0.f;
                #pragma unroll
                for (int sgg = 0; sgg < 8; sgg++) tot += pr[sgg * 64 + tid];
                const float a = tanhf(tot);
                g_store(&xT[(size_t)(p * 64 + tid) * 32 + bb], a);
                att_hist[((size_t)t * B_ + bb) * 512 + p * 64 + tid] = a;
            }
        }
        full_sync(bar, 2 * t + 1);
    }
}

// ---------------------------------------------------------------------------
// k_dec: bf16-split decode output; row-major dh/dl + chunk-major dhk/dlk.
// ---------------------------------------------------------------------------
__global__ __launch_bounds__(256) void k_dec(const int* __restrict__ tgt_in,
                                             const float* __restrict__ emb,
                                             const float* __restrict__ h_hist,
                                             const float* __restrict__ att_hist,
                                             const float* __restrict__ Wgen,
                                             const float* __restrict__ bgen,
                                             unsigned short* __restrict__ dh,
                                             unsigned short* __restrict__ dl,
                                             unsigned short* __restrict__ dhk,
                                             unsigned short* __restrict__ dlk,
                                             int pre) {
    __shared__ float a_s[32][66];
    __shared__ float w_s[32][130];
    const int tid = threadIdx.x;
    const int m0 = blockIdx.x * 64, n0 = blockIdx.y * 128;
    const int mq = tid >> 5, nq = tid & 31;
    float acc[8][4] = {};
    for (int k0 = 0; k0 < 1536; k0 += 32) {
        {
            const int mm = tid >> 2, kq = tid & 3, kk = kq * 8;
            const int m = m0 + mm;
            const float* row;
            if (k0 < 512)       row = emb + (size_t)tgt_in[m] * E_ + k0;
            else if (k0 < 1024) row = h_hist + (size_t)m * 512 + (k0 - 512);
            else                row = att_hist + (size_t)m * 512 + (k0 - 1024);
            row += kk;
            float4 v0 = *(const float4*)(row);
            float4 v1 = *(const float4*)(row + 4);
            a_s[kk + 0][mm] = v0.x; a_s[kk + 1][mm] = v0.y;
            a_s[kk + 2][mm] = v0.z; a_s[kk + 3][mm] = v0.w;
            a_s[kk + 4][mm] = v1.x; a_s[kk + 5][mm] = v1.y;
            a_s[kk + 6][mm] = v1.z; a_s[kk + 7][mm] = v1.w;
        }
        {
            const int nn = tid >> 1, kq = tid & 1, kk = kq * 16;
            const float* row = Wgen + (size_t)(n0 + nn) * 1536 + k0 + kk;
            #pragma unroll
            for (int u = 0; u < 4; u++) {
                float4 v = *(const float4*)(row + u * 4);
                w_s[kk + u * 4 + 0][nn] = v.x; w_s[kk + u * 4 + 1][nn] = v.y;
                w_s[kk + u * 4 + 2][nn] = v.z; w_s[kk + u * 4 + 3][nn] = v.w;
            }
        }
        __syncthreads();
        for (int k = 0; k < 32; k++) {
            float a[8], wv[4];
            #pragma unroll
            for (int i = 0; i < 8; i++) a[i] = a_s[k][mq + 8 * i];
            #pragma unroll
            for (int pq = 0; pq < 4; pq++) wv[pq] = w_s[k][nq + 32 * pq];
            #pragma unroll
            for (int i = 0; i < 8; i++)
                #pragma unroll
                for (int pq = 0; pq < 4; pq++) acc[i][pq] += a[i] * wv[pq];
        }
        __syncthreads();
    }
    #pragma unroll
    for (int i = 0; i < 8; i++) {
        const int m = m0 + mq + 8 * i;
        #pragma unroll
        for (int pq = 0; pq < 4; pq++) {
            const int n = n0 + nq + 32 * pq;
            const float v = tanhf(acc[i][pq] + bgen[n]);
            const unsigned short hb = f2bf(v);
            const unsigned short lb = f2bf(v - bf2f(hb));
            dh[(size_t)m * 512 + n] = hb;
            dl[(size_t)m * 512 + n] = lb;
            if (pre) {
                const size_t ca = (size_t)(n >> 5) * 32768 + (size_t)(m >> 6) * 2048
                                + (size_t)(m & 63) * 32 + (n & 31);
                dhk[ca] = hb;
                dlk[ca] = lb;
            }
        }
    }
}

// ===========================================================================
// k_read_pre: MFMA readout, double-buffered async B staging (2-phase
// pipeline): STAGE(next) issued before MFMA(cur); single __syncthreads per
// chunk (its vmcnt(0) drain is the fence). A-frags per-lane direct from
// chunk-major dhk/dlk. Grid 3200 XCD-grouped, LDS 64 KB -> 2 blocks/CU.
// ===========================================================================
__global__ __launch_bounds__(256) void k_read_pre(const unsigned short* __restrict__ dhk,
                                                  const unsigned short* __restrict__ dlk,
                                                  const unsigned short* __restrict__ whk,
                                                  const unsigned short* __restrict__ wlk,
                                                  const int* __restrict__ tgt_out,
                                                  float4* __restrict__ part,
                                                  float* __restrict__ tgt_logit) {
    __shared__ __align__(16) unsigned short BhL[2][8192];   // 32 KB
    __shared__ __align__(16) unsigned short BlL[2][8192];   // 32 KB
    __shared__ float ep_max[64][2];
    __shared__ int   ep_idx[64][2];
    __shared__ float ep_fin[64];
    __shared__ int   ep_fidx[64];
    __shared__ float ep_sum[64][2];

    const int xcd = blockIdx.x & 7;
    const int idx = blockIdx.x >> 3;
    const int mi  = idx & 15;
    const int group = idx >> 4;
    const int ch = group * 8 + xcd;
    if (ch >= NCH) return;
    const int m0 = mi * 64, n0 = ch * 256;

    const int tid = threadIdx.x;
    const int lane = tid & 63, wid = tid >> 6;
    const int wr = wid >> 1, wc = wid & 1;
    const int l15 = lane & 15, lk = lane >> 4;

    f32x4 acc[2][8];
    #pragma unroll
    for (int mt = 0; mt < 2; mt++)
        #pragma unroll
        for (int nt = 0; nt < 8; nt++) acc[mt][nt] = {0.f, 0.f, 0.f, 0.f};

    const unsigned short* bh_src = whk + (size_t)n0 * 32;
    const unsigned short* bl_src = wlk + (size_t)n0 * 32;
    const unsigned short* ah_base = dhk + (size_t)(m0 >> 6) * 2048 + lk * 8;
    const unsigned short* al_base = dlk + (size_t)(m0 >> 6) * 2048 + lk * 8;

    // prologue: stage chunk 0 into buffer 0
    {
        const char* gh = (const char*)bh_src;
        const char* gl = (const char*)bl_src;
        #pragma unroll
        for (int c = 0; c < 4; c++) {
            const int ob = wid * 4096 + c * 1024;
            async16((char*)&BhL[0][0] + ob, gh + ob + lane * 16);
            async16((char*)&BlL[0][0] + ob, gl + ob + lane * 16);
        }
    }
    __syncthreads();

    for (int kc = 0; kc < 16; kc++) {
        const int cur = kc & 1;
        bf16x8 afh[2], afl[2];
        {   // A fragments first (so compiler's A-wait is vmcnt(stage), not 0)
            const unsigned short* ah = ah_base + (size_t)kc * 32768;
            const unsigned short* al = al_base + (size_t)kc * 32768;
            #pragma unroll
            for (int mt = 0; mt < 2; mt++) {
                const int r = wr * 32 + mt * 16 + l15;
                afh[mt] = *(const bf16x8*)(ah + r * 32);
                afl[mt] = *(const bf16x8*)(al + r * 32);
            }
        }
        if (kc < 15) {   // stage next chunk into the other buffer
            const size_t cb = (size_t)(kc + 1) * ((size_t)VP_ * 32);
            const char* gh = (const char*)(bh_src + cb);
            const char* gl = (const char*)(bl_src + cb);
            #pragma unroll
            for (int c = 0; c < 4; c++) {
                const int ob = wid * 4096 + c * 1024;
                async16((char*)&BhL[cur ^ 1][0] + ob, gh + ob + lane * 16);
                async16((char*)&BlL[cur ^ 1][0] + ob, gl + ob + lane * 16);
            }
        }
        #pragma unroll
        for (int nt = 0; nt < 8; nt++) {
            const int nn = wc * 128 + nt * 16 + l15;
            const int bo = nn * 32 + ((lk ^ ((nn >> 1) & 3)) * 8);
            bf16x8 bh = *(const bf16x8*)&BhL[cur][bo];
            bf16x8 bl = *(const bf16x8*)&BlL[cur][bo];
            #pragma unroll
            for (int mt = 0; mt < 2; mt++) {
                acc[mt][nt] = __builtin_amdgcn_mfma_f32_16x16x32_bf16(afh[mt], bh, acc[mt][nt], 0, 0, 0);
                acc[mt][nt] = __builtin_amdgcn_mfma_f32_16x16x32_bf16(afl[mt], bh, acc[mt][nt], 0, 0, 0);
                acc[mt][nt] = __builtin_amdgcn_mfma_f32_16x16x32_bf16(afh[mt], bl, acc[mt][nt], 0, 0, 0);
            }
        }
        __syncthreads();   // drains vmcnt (next stage landed) + all readers done
    }

    #pragma unroll
    for (int mt = 0; mt < 2; mt++)
        #pragma unroll
        for (int reg = 0; reg < 4; reg++) {
            float bv = -INFINITY; int bi = 0x7fffffff;
            #pragma unroll
            for (int nt = 0; nt < 8; nt++) {
                const int n = n0 + wc * 128 + nt * 16 + l15;
                const float v = (n < V_) ? acc[mt][nt][reg] : -INFINITY;
                if (v > bv || (v == bv && n < bi)) { bv = v; bi = n; }
            }
            #pragma unroll
            for (int mk = 1; mk < 16; mk <<= 1) {
                const float ov = __shfl_xor(bv, mk);
                const int oi = __shfl_xor(bi, mk);
                if (ov > bv || (ov == bv && oi < bi)) { bv = ov; bi = oi; }
            }
            if (l15 == 0) {
                const int rl = wr * 32 + mt * 16 + lk * 4 + reg;
                ep_max[rl][wc] = bv; ep_idx[rl][wc] = bi;
            }
        }
    __syncthreads();
    if (tid < 64) {
        const float a = ep_max[tid][0], b = ep_max[tid][1];
        const int ia = ep_idx[tid][0], ib = ep_idx[tid][1];
        const bool tb = (b > a) || (b == a && ib < ia);
        ep_fin[tid] = tb ? b : a; ep_fidx[tid] = tb ? ib : ia;
    }
    __syncthreads();
    #pragma unroll
    for (int mt = 0; mt < 2; mt++)
        #pragma unroll
        for (int reg = 0; reg < 4; reg++) {
            const int rl = wr * 32 + mt * 16 + lk * 4 + reg;
            const float M = ep_fin[rl];
            const int rel = tgt_out[m0 + rl] - n0;
            float se = 0.f;
            #pragma unroll
            for (int nt = 0; nt < 8; nt++) {
                const int nl = wc * 128 + nt * 16 + l15;
                if (n0 + nl < V_) {
                    const float v = acc[mt][nt][reg];
                    se += expf(v - M);
                    if (nl == rel) tgt_logit[m0 + rl] = v;
                }
            }
            #pragma unroll
            for (int mk = 1; mk < 16; mk <<= 1) se += __shfl_xor(se, mk);
            if (l15 == 0) ep_sum[rl][wc] = se;
        }
    __syncthreads();
    if (tid < 64) {
        part[(size_t)(m0 + tid) * NCH + ch] =
            make_float4(ep_fin[tid], ep_sum[tid][0] + ep_sum[tid][1],
                        __int_as_float(ep_fidx[tid]), 0.f);
    }
}

// ---------------------------------------------------------------------------
// k_read (fallback: in-kernel conversion, row-major dh/dl, grid 3200)
// ---------------------------------------------------------------------------
__global__ __launch_bounds__(256) void k_read(const unsigned short* __restrict__ dh,
                                              const unsigned short* __restrict__ dl,
                                              const float* __restrict__ Wread,
                                              const int* __restrict__ tgt_out,
                                              float4* __restrict__ part,
                                              float* __restrict__ tgt_logit) {
    __shared__ __align__(16) unsigned short Bh[4][256][8];
    __shared__ __align__(16) unsigned short Bl[4][256][8];
    __shared__ __align__(16) unsigned short Ah[4][64][8];
    __shared__ __align__(16) unsigned short Alo[4][64][8];
    __shared__ float ep_max[64][2];
    __shared__ int   ep_idx[64][2];
    __shared__ float ep_fin[64];
    __shared__ int   ep_fidx[64];
    __shared__ float ep_sum[64][2];

    const int xcd = blockIdx.x & 7;
    const int idx = blockIdx.x >> 3;
    const int mi  = idx & 15;
    const int group = idx >> 4;
    const int ch = group * 8 + xcd;
    if (ch >= NCH) return;
    const int m0 = mi * 64, n0 = ch * 256;

    const int tid = threadIdx.x;
    const int lane = tid & 63, wid = tid >> 6;
    const int wr = wid >> 1, wc = wid & 1;
    const int l15 = lane & 15, lk = lane >> 4;

    f32x4 acc[2][8];
    #pragma unroll
    for (int mt = 0; mt < 2; mt++)
        #pragma unroll
        for (int nt = 0; nt < 8; nt++) acc[mt][nt] = {0.f, 0.f, 0.f, 0.f};

    for (int kc = 0; kc < 512; kc += 32) {
        {
            const int n = n0 + tid;
            const float* row = Wread + (size_t)n * 512 + kc;
            #pragma unroll
            for (int g = 0; g < 4; g++) {
                uint4 h4, l4;
                if (n < V_) {
                    float4 p0 = *(const float4*)(row + g * 8);
                    float4 p1 = *(const float4*)(row + g * 8 + 4);
                    float v[8] = {p0.x, p0.y, p0.z, p0.w, p1.x, p1.y, p1.z, p1.w};
                    unsigned int hb[8], lb[8];
                    #pragma unroll
                    for (int e = 0; e < 8; e++) {
                        hb[e] = f2bf(v[e]);
                        lb[e] = f2bf(v[e] - bf2f((unsigned short)hb[e]));
                    }
                    h4 = make_uint4(hb[0] | (hb[1] << 16), hb[2] | (hb[3] << 16),
                                    hb[4] | (hb[5] << 16), hb[6] | (hb[7] << 16));
                    l4 = make_uint4(lb[0] | (lb[1] << 16), lb[2] | (lb[3] << 16),
                                    lb[4] | (lb[5] << 16), lb[6] | (lb[7] << 16));
                } else {
                    h4 = make_uint4(0, 0, 0, 0);
                    l4 = make_uint4(0, 0, 0, 0);
                }
                *(uint4*)&Bh[g][tid][0] = h4;
                *(uint4*)&Bl[g][tid][0] = l4;
            }
        }
        {
            const int row = tid >> 2, g = tid & 3;
            *(uint4*)&Ah[g][row][0]  = *(const uint4*)(dh + (size_t)(m0 + row) * 512 + kc + g * 8);
            *(uint4*)&Alo[g][row][0] = *(const uint4*)(dl + (size_t)(m0 + row) * 512 + kc + g * 8);
        }
        __syncthreads();
        {
            bf16x8 afh[2], afl[2];
            #pragma unroll
            for (int mt = 0; mt < 2; mt++) {
                const int r = wr * 32 + mt * 16 + l15;
                afh[mt] = *(const bf16x8*)&Ah[lk][r][0];
                afl[mt] = *(const bf16x8*)&Alo[lk][r][0];
            }
            #pragma unroll
            for (int nt = 0; nt < 8; nt++) {
                const int nn = wc * 128 + nt * 16 + l15;
                bf16x8 bh = *(const bf16x8*)&Bh[lk][nn][0];
                bf16x8 bl = *(const bf16x8*)&Bl[lk][nn][0];
                #pragma unroll
                for (int mt = 0; mt < 2; mt++) {
                    acc[mt][nt] = __builtin_amdgcn_mfma_f32_16x16x32_bf16(afh[mt], bh, acc[mt][nt], 0, 0, 0);
                    acc[mt][nt] = __builtin_amdgcn_mfma_f32_16x16x32_bf16(afl[mt], bh, acc[mt][nt], 0, 0, 0);
                    acc[mt][nt] = __builtin_amdgcn_mfma_f32_16x16x32_bf16(afh[mt], bl, acc[mt][nt], 0, 0, 0);
                }
            }
        }
        __syncthreads();
    }

    #pragma unroll
    for (int mt = 0; mt < 2; mt++)
        #pragma unroll
        for (int reg = 0; reg < 4; reg++) {
            float bv = -INFINITY; int bi = 0x7fffffff;
            #pragma unroll
            for (int nt = 0; nt < 8; nt++) {
                const int n = n0 + wc * 128 + nt * 16 + l15;
                const float v = (n < V_) ? acc[mt][nt][reg] : -INFINITY;
                if (v > bv || (v == bv && n < bi)) { bv = v; bi = n; }
            }
            #pragma unroll
            for (int mk = 1; mk < 16; mk <<= 1) {
                const float ov = __shfl_xor(bv, mk);
                const int oi = __shfl_xor(bi, mk);
                if (ov > bv || (ov == bv && oi < bi)) { bv = ov; bi = oi; }
            }
            if (l15 == 0) {
                const int rl = wr * 32 + mt * 16 + lk * 4 + reg;
                ep_max[rl][wc] = bv; ep_idx[rl][wc] = bi;
            }
        }
    __syncthreads();
    if (tid < 64) {
        const float a = ep_max[tid][0], b = ep_max[tid][1];
        const int ia = ep_idx[tid][0], ib = ep_idx[tid][1];
        const bool tb = (b > a) || (b == a && ib < ia);
        ep_fin[tid] = tb ? b : a; ep_fidx[tid] = tb ? ib : ia;
    }
    __syncthreads();
    #pragma unroll
    for (int mt = 0; mt < 2; mt++)
        #pragma unroll
        for (int reg = 0; reg < 4; reg++) {
            const int rl = wr * 32 + mt * 16 + lk * 4 + reg;
            const float M = ep_fin[rl];
            const int rel = tgt_out[m0 + rl] - n0;
            float se = 0.f;
            #pragma unroll
            for (int nt = 0; nt < 8; nt++) {
                const int nl = wc * 128 + nt * 16 + l15;
                if (n0 + nl < V_) {
                    const float v = acc[mt][nt][reg];
                    se += expf(v - M);
                    if (nl == rel) tgt_logit[m0 + rl] = v;
                }
            }
            #pragma unroll
            for (int mk = 1; mk < 16; mk <<= 1) se += __shfl_xor(se, mk);
            if (l15 == 0) ep_sum[rl][wc] = se;
        }
    __syncthreads();
    if (tid < 64) {
        part[(size_t)(m0 + tid) * NCH + ch] =
            make_float4(ep_fin[tid], ep_sum[tid][0] + ep_sum[tid][1],
                        __int_as_float(ep_fidx[tid]), 0.f);
    }
}

// ---------------------------------------------------------------------------
// k_merge: combine chunk partials -> loss + argmax
// ---------------------------------------------------------------------------
__global__ __launch_bounds__(256) void k_merge(const float4* __restrict__ part,
                                               const float* __restrict__ tgt_logit,
                                               const int* __restrict__ tgt_out,
                                               float* __restrict__ out) {
    const int tid = threadIdx.x;
    const int w = tid >> 6, lane = tid & 63;
    const int row = blockIdx.x * 4 + w;
    float bm = -INFINITY; int bi = 0x7fffffff;
    for (int ch = lane; ch < NCH; ch += 64) {
        const float4 p = part[(size_t)row * NCH + ch];
        const int pi = __float_as_int(p.z);
        if (p.x > bm || (p.x == bm && pi < bi)) { bm = p.x; bi = pi; }
    }
    #pragma unroll
    for (int mk = 1; mk < 64; mk <<= 1) {
        const float ov = __shfl_xor(bm, mk);
        const int oi = __shfl_xor(bi, mk);
        if (ov > bm || (ov == bm && oi < bi)) { bm = ov; bi = oi; }
    }
    float sum = 0.f;
    for (int ch = lane; ch < NCH; ch += 64) {
        const float4 p = part[(size_t)row * NCH + ch];
        sum += p.y * expf(p.x - bm);
    }
    #pragma unroll
    for (int mk = 1; mk < 64; mk <<= 1) sum += __shfl_xor(sum, mk);
    if (lane == 0) {
        const float lse = bm + logf(sum);
        const int tg = tgt_out[row];
        const float loss = (tg != 0) ? (lse - tgt_logit[row]) : 0.f;
        out[row] = loss;
        out[1024 + row] = (float)bi;
    }
}

// ---------------------------------------------------------------------------
extern "C" void kernel_launch(void* const* d_in, const int* in_sizes, int n_in,
                              void* d_out, int out_size, void* d_ws, size_t ws_size,
                              hipStream_t stream) {
    const int* tgt_in = (const int*)d_in[0];
    const int* tgt_out = (const int*)d_in[1];
    const int* src_lens = (const int*)d_in[2];
    const float* src = (const float*)d_in[3];
    const float* last_state = (const float*)d_in[4];
    const float* last_cell = (const float*)d_in[5];
    const float* emb = (const float*)d_in[6];
    const float* Wih = (const float*)d_in[7];
    const float* Whh = (const float*)d_in[8];
    const float* bih = (const float*)d_in[9];
    const float* bhh = (const float*)d_in[10];
    const float* Wattn = (const float*)d_in[11];
    const float* Wgen = (const float*)d_in[12];
    const float* bgen = (const float*)d_in[13];
    const float* Wread = (const float*)d_in[14];
    float* out = (float*)d_out;

    float* ws = (float*)d_ws;
    float* G0T      = ws;                    // 2,097,152 f
    float* U        = G0T + 2097152;         // 3,276,800 f
    float* WaRT     = U + 3276800;           // 262,144 f
    unsigned short* dh  = (unsigned short*)(WaRT + 262144);  // 524,288 u16
    unsigned short* dl  = dh + 524288;
    unsigned short* dhk = dl + 524288;       // chunk-major
    unsigned short* dlk = dhk + 524288;
    float* h_hist   = (float*)(dlk + 524288);
    float* att_hist = h_hist + 524288;
    float* xT       = att_hist + 524288;     // 49,152 f
    float* h_b      = xT + 49152;            // 16,384 f
    float* scb      = h_b + 16384;           // 8,192 f (unused, layout kept)
    float4* part    = (float4*)(scb + 8192); // 200,704 float4
    float* tgtl     = ((float*)part) + 802816; // 1,024 f
    int* bar        = (int*)(tgtl + 1024);     // 2,048 ints
    unsigned short* whk = (unsigned short*)(bar + 2048);   // VP_*512 u16
    unsigned short* wlk = whk + (size_t)VP_ * 512;

    const size_t need = (size_t)((char*)(wlk + (size_t)VP_ * 512) - (char*)ws);
    const int pre = (ws_size >= need) ? 1 : 0;

    hipMemsetAsync(bar, 0, 8192, stream);

    k_init<<<64, 256, 0, stream>>>(last_state, xT);
    k_g0<<<dim3(16, 16), 256, 0, stream>>>(tgt_in, emb, Wih, bih, bhh, G0T);
    k_u<<<dim3(100, 4), 256, 0, stream>>>(src, Wattn, U);
    k_tr<<<dim3(16, 16), 256, 0, stream>>>(Wattn, WaRT);
    if (pre)
        k_wconv<<<12544, 256, 0, stream>>>(Wread, whk, wlk);

    k_scan<<<256, 512, 0, stream>>>(G0T, U, WaRT, Wih, Whh, src, src_lens, last_cell,
                                    xT, h_b, h_hist, att_hist, bar);

    k_dec<<<dim3(16, 4), 256, 0, stream>>>(tgt_in, emb, h_hist, att_hist, Wgen, bgen,
                                           dh, dl, dhk, dlk, pre);
    if (pre)
        k_read_pre<<<3200, 256, 0, stream>>>(dhk, dlk, whk, wlk, tgt_out, part, tgtl);
    else
        k_read<<<3200, 256, 0, stream>>>(dh, dl, Wread, tgt_out, part, tgtl);
    k_merge<<<256, 256, 0, stream>>>(part, tgtl, tgt_out, out);
}

// Round 13
// 1182.037 us; speedup vs baseline: 1.0644x; 1.0644x over previous
//
#include <hip/hip_runtime.h>
#include <math.h>

#define T_ 32
#define B_ 32
#define S_ 200
#define E_ 512
#define H_ 512
#define V_ 50000
#define VP_ 50176   // padded rows for chunk-major bf16 W
#define G4_ 2048
#define NCH 196     // ceil(50000/256)

using bf16x8 = __attribute__((ext_vector_type(8))) __bf16;
using f32x4  = __attribute__((ext_vector_type(4))) float;

__device__ __forceinline__ float sigf(float x) { return 1.f / (1.f + expf(-x)); }

__device__ __forceinline__ unsigned short f2bf(float v) {
    unsigned int x = __float_as_uint(v);
    return (unsigned short)((x + 0x7FFFu + ((x >> 16) & 1u)) >> 16);
}
__device__ __forceinline__ float bf2f(unsigned short b) {
    return __uint_as_float(((unsigned int)b) << 16);
}

// async global->LDS 16B copy
__device__ __forceinline__ void async16(void* lds, const void* g) {
    __builtin_amdgcn_global_load_lds(
        (const __attribute__((address_space(1))) unsigned int*)g,
        (__attribute__((address_space(3))) unsigned int*)lds, 16, 0, 0);
}

// Coherent LLC-level exchange (relaxed agent atomics -> sc1 load/store)
__device__ __forceinline__ void g_store(float* p, float v) {
    __hip_atomic_store(p, v, __ATOMIC_RELAXED, __HIP_MEMORY_SCOPE_AGENT);
}
__device__ __forceinline__ float g_load(const float* p) {
    return __hip_atomic_load(p, __ATOMIC_RELAXED, __HIP_MEMORY_SCOPE_AGENT);
}

// ---------------------------------------------------------------------------
// Fence-free grid barrier (proven rounds 5-12).
// ---------------------------------------------------------------------------
__device__ __forceinline__ void full_sync(int* bar, int ep) {
    __syncthreads();
    if (threadIdx.x == 0) {
        const int g = blockIdx.x & 7;
        int a = __hip_atomic_fetch_add(&bar[g * 32], 1, __ATOMIC_RELAXED, __HIP_MEMORY_SCOPE_AGENT);
        if (a == ep * 32 + 31) {
            int q = __hip_atomic_fetch_add(&bar[256], 1, __ATOMIC_RELAXED, __HIP_MEMORY_SCOPE_AGENT);
            if (q == ep * 8 + 7) {
                #pragma unroll
                for (int i = 0; i < 8; i++)
                    __hip_atomic_store(&bar[288 + i * 32], ep + 1, __ATOMIC_RELAXED, __HIP_MEMORY_SCOPE_AGENT);
            }
        }
        while (__hip_atomic_load(&bar[288 + g * 32], __ATOMIC_RELAXED, __HIP_MEMORY_SCOPE_AGENT) < ep + 1)
            __builtin_amdgcn_s_sleep(1);
    }
    __syncthreads();
}

__device__ __forceinline__ void sub_sync(int* bar, int bb, int t) {
    __syncthreads();
    if (threadIdx.x == 0) {
        __hip_atomic_fetch_add(&bar[544 + bb * 32], 1, __ATOMIC_RELAXED, __HIP_MEMORY_SCOPE_AGENT);
        while (__hip_atomic_load(&bar[544 + bb * 32], __ATOMIC_RELAXED, __HIP_MEMORY_SCOPE_AGENT) < (t + 1) * 8)
            __builtin_amdgcn_s_sleep(1);
    }
    __syncthreads();
}

// ---------------------------------------------------------------------------
// k_init: xT rows 0..511 att=0; rows 1024..1535 = last_state^T (h slot 1).
// ---------------------------------------------------------------------------
__global__ __launch_bounds__(256) void k_init(const float* __restrict__ last_state,
                                              float* __restrict__ xT) {
    const int f = blockIdx.x * 256 + threadIdx.x;   // 0..16383
    xT[f] = 0.f;
    const int k = f >> 5, b = f & 31;
    xT[32768 + f] = last_state[b * 512 + k];
}

// ---------------------------------------------------------------------------
// k_g0: G0T[j][m] = emb(tgt_in[m]) . W_ih[j][0:512] + b_ih[j] + b_hh[j]
// ---------------------------------------------------------------------------
__global__ __launch_bounds__(256) void k_g0(const int* __restrict__ tgt_in,
                                            const float* __restrict__ emb,
                                            const float* __restrict__ Wih,
                                            const float* __restrict__ bih,
                                            const float* __restrict__ bhh,
                                            float* __restrict__ G0T) {
    __shared__ float a_s[32][66];
    __shared__ float w_s[32][130];
    const int tid = threadIdx.x;
    const int m0 = blockIdx.x * 64, n0 = blockIdx.y * 128;
    const int mq = tid >> 5, nq = tid & 31;
    float acc[8][4] = {};
    for (int k0 = 0; k0 < 512; k0 += 32) {
        {
            const int mm = tid >> 2, kq = tid & 3, kk = kq * 8;
            const float* row = emb + (size_t)tgt_in[m0 + mm] * E_ + k0 + kk;
            float4 v0 = *(const float4*)(row);
            float4 v1 = *(const float4*)(row + 4);
            a_s[kk + 0][mm] = v0.x; a_s[kk + 1][mm] = v0.y;
            a_s[kk + 2][mm] = v0.z; a_s[kk + 3][mm] = v0.w;
            a_s[kk + 4][mm] = v1.x; a_s[kk + 5][mm] = v1.y;
            a_s[kk + 6][mm] = v1.z; a_s[kk + 7][mm] = v1.w;
        }
        {
            const int nn = tid >> 1, kq = tid & 1, kk = kq * 16;
            const float* row = Wih + (size_t)(n0 + nn) * 1024 + k0 + kk;
            #pragma unroll
            for (int u = 0; u < 4; u++) {
                float4 v = *(const float4*)(row + u * 4);
                w_s[kk + u * 4 + 0][nn] = v.x; w_s[kk + u * 4 + 1][nn] = v.y;
                w_s[kk + u * 4 + 2][nn] = v.z; w_s[kk + u * 4 + 3][nn] = v.w;
            }
        }
        __syncthreads();
        for (int k = 0; k < 32; k++) {
            float a[8], wv[4];
            #pragma unroll
            for (int i = 0; i < 8; i++) a[i] = a_s[k][mq + 8 * i];
            #pragma unroll
            for (int p = 0; p < 4; p++) wv[p] = w_s[k][nq + 32 * p];
            #pragma unroll
            for (int i = 0; i < 8; i++)
                #pragma unroll
                for (int p = 0; p < 4; p++) acc[i][p] += a[i] * wv[p];
        }
        __syncthreads();
    }
    #pragma unroll
    for (int i = 0; i < 8; i++) {
        const int m = m0 + mq + 8 * i;
        #pragma unroll
        for (int p = 0; p < 4; p++) {
            const int n = n0 + nq + 32 * p;
            G0T[(size_t)n * 1024 + m] = acc[i][p] + bih[n] + bhh[n];
        }
    }
}

// ---------------------------------------------------------------------------
// k_u: U[b,s,j] = src[b,s,:] . W_attn[j, 0:512]
// ---------------------------------------------------------------------------
__global__ __launch_bounds__(256) void k_u(const float* __restrict__ src,
                                           const float* __restrict__ Wattn,
                                           float* __restrict__ U) {
    __shared__ float a_s[32][66];
    __shared__ float w_s[32][130];
    const int tid = threadIdx.x;
    const int m0 = blockIdx.x * 64, n0 = blockIdx.y * 128;
    const int mq = tid >> 5, nq = tid & 31;
    float acc[8][4] = {};
    for (int k0 = 0; k0 < 512; k0 += 32) {
        {
            const int mm = tid >> 2, kq = tid & 3, kk = kq * 8;
            const float* row = src + (size_t)(m0 + mm) * 512 + k0 + kk;
            float4 v0 = *(const float4*)(row);
            float4 v1 = *(const float4*)(row + 4);
            a_s[kk + 0][mm] = v0.x; a_s[kk + 1][mm] = v0.y;
            a_s[kk + 2][mm] = v0.z; a_s[kk + 3][mm] = v0.w;
            a_s[kk + 4][mm] = v1.x; a_s[kk + 5][mm] = v1.y;
            a_s[kk + 6][mm] = v1.z; a_s[kk + 7][mm] = v1.w;
        }
        {
            const int nn = tid >> 1, kq = tid & 1, kk = kq * 16;
            const float* row = Wattn + (size_t)(n0 + nn) * 1024 + k0 + kk;
            #pragma unroll
            for (int u = 0; u < 4; u++) {
                float4 v = *(const float4*)(row + u * 4);
                w_s[kk + u * 4 + 0][nn] = v.x; w_s[kk + u * 4 + 1][nn] = v.y;
                w_s[kk + u * 4 + 2][nn] = v.z; w_s[kk + u * 4 + 3][nn] = v.w;
            }
        }
        __syncthreads();
        for (int k = 0; k < 32; k++) {
            float a[8], wv[4];
            #pragma unroll
            for (int i = 0; i < 8; i++) a[i] = a_s[k][mq + 8 * i];
            #pragma unroll
            for (int p = 0; p < 4; p++) wv[p] = w_s[k][nq + 32 * p];
            #pragma unroll
            for (int i = 0; i < 8; i++)
                #pragma unroll
                for (int p = 0; p < 4; p++) acc[i][p] += a[i] * wv[p];
        }
        __syncthreads();
    }
    #pragma unroll
    for (int i = 0; i < 8; i++) {
        const int m = m0 + mq + 8 * i;
        #pragma unroll
        for (int p = 0; p < 4; p++)
            U[(size_t)m * 512 + n0 + nq + 32 * p] = acc[i][p];
    }
}

// ---------------------------------------------------------------------------
// k_tr: WaRT[k][j] = W_attn[j][512+k]
// ---------------------------------------------------------------------------
__global__ __launch_bounds__(256) void k_tr(const float* __restrict__ Wattn,
                                            float* __restrict__ WaRT) {
    __shared__ float t_s[32][33];
    const int tid = threadIdx.x;
    const int bx = blockIdx.x, by = blockIdx.y;
    {
        const int jj = tid >> 3, kq = (tid & 7) * 4;
        float4 v = *(const float4*)(Wattn + (size_t)(by * 32 + jj) * 1024 + 512 + bx * 32 + kq);
        t_s[jj][kq + 0] = v.x; t_s[jj][kq + 1] = v.y;
        t_s[jj][kq + 2] = v.z; t_s[jj][kq + 3] = v.w;
    }
    __syncthreads();
    {
        const int kk = tid >> 3, jq = (tid & 7) * 4;
        float4 w;
        w.x = t_s[jq + 0][kk]; w.y = t_s[jq + 1][kk];
        w.z = t_s[jq + 2][kk]; w.w = t_s[jq + 3][kk];
        *(float4*)(WaRT + (size_t)(bx * 32 + kk) * 512 + by * 32 + jq) = w;
    }
}

// ---------------------------------------------------------------------------
// k_wconv: Wread fp32 -> bf16 hi/lo, chunk-major with BAKED bank swizzle.
// ---------------------------------------------------------------------------
__global__ __launch_bounds__(256) void k_wconv(const float* __restrict__ Wread,
                                               unsigned short* __restrict__ whk,
                                               unsigned short* __restrict__ wlk) {
    const size_t q = (size_t)blockIdx.x * 256 + threadIdx.x;
    const size_t k8 = q * 8;
    const int n = (int)(k8 >> 9);
    const int k = (int)(k8 & 511);
    if (n >= VP_) return;
    uint4 h4, l4;
    if (n < V_) {
        float4 p0 = *(const float4*)(Wread + (size_t)n * 512 + k);
        float4 p1 = *(const float4*)(Wread + (size_t)n * 512 + k + 4);
        float v[8] = {p0.x, p0.y, p0.z, p0.w, p1.x, p1.y, p1.z, p1.w};
        unsigned int hb[8], lb[8];
        #pragma unroll
        for (int e = 0; e < 8; e++) {
            hb[e] = f2bf(v[e]);
            lb[e] = f2bf(v[e] - bf2f((unsigned short)hb[e]));
        }
        h4 = make_uint4(hb[0] | (hb[1] << 16), hb[2] | (hb[3] << 16),
                        hb[4] | (hb[5] << 16), hb[6] | (hb[7] << 16));
        l4 = make_uint4(lb[0] | (lb[1] << 16), lb[2] | (lb[3] << 16),
                        lb[4] | (lb[5] << 16), lb[6] | (lb[7] << 16));
    } else {
        h4 = make_uint4(0, 0, 0, 0);
        l4 = make_uint4(0, 0, 0, 0);
    }
    const int lk = (k >> 3) & 3;
    const size_t dst = (size_t)(k >> 5) * ((size_t)VP_ * 32) + (size_t)n * 32
                     + (size_t)((lk ^ ((n >> 1) & 3)) * 8);
    *(uint4*)(whk + dst) = h4;
    *(uint4*)(wlk + dst) = l4;
}

// ---------------------------------------------------------------------------
// Persistent scan (round-11 proven version, verbatim: 3 syncs/step).
// ---------------------------------------------------------------------------
__global__ __launch_bounds__(512) void k_scan(const float* __restrict__ G0T,
                                              const float* __restrict__ U,
                                              const float* __restrict__ WaRT,
                                              const float* __restrict__ Wih,
                                              const float* __restrict__ Whh,
                                              const float* __restrict__ src,
                                              const int* __restrict__ lens,
                                              const float* __restrict__ last_cell,
                                              float* __restrict__ xT,
                                              float* __restrict__ h_b,
                                              float* __restrict__ scb,
                                              float* __restrict__ h_hist,
                                              float* __restrict__ att_hist,
                                              int* __restrict__ bar) {
    __shared__ float Wl[8 * 1024];
    __shared__ float Ul[200 * 64];
    __shared__ float red_s[2048];
    __shared__ float gate_s[256];
    __shared__ float h_s[512];
    __shared__ float al[256];
    __shared__ float pr[512];

    const int blk = blockIdx.x, tid = threadIdx.x;
    const int u0 = blk * 2;
    const int bb = blk & 31, p = blk >> 5;

    for (int f = tid; f < 2048; f += 512) {
        const int r = f >> 8, k = (f & 255) * 4;
        const int j = (r >> 1) * 512 + u0 + (r & 1);
        float4 v;
        if (k < 512) v = *(const float4*)(Wih + (size_t)j * 1024 + 512 + k);
        else         v = *(const float4*)(Whh + (size_t)j * 512 + (k - 512));
        *(float4*)&Wl[r * 1024 + k] = v;
    }
    for (int f = tid; f < 3200; f += 512) {
        const int s = f >> 4, q = (f & 15) * 4;
        *(float4*)&Ul[s * 64 + q] = *(const float4*)(U + ((size_t)bb * S_ + s) * 512 + p * 64 + q);
    }
    float creg = (tid < 64) ? last_cell[(tid & 31) * 512 + u0 + (tid >> 5)] : 0.f;
    __syncthreads();

    const int w = tid >> 6, lane = tid & 63;
    const int hf = lane >> 5, b = lane & 31;
    const int len = lens[bb];

    for (int t = 0; t < T_; t++) {
        // -------- Phase A: gates + pointwise ------------------------------
        {
            const int hoff = ((t + 1) & 1) * 512;        // slot holding h(t-1)
            const int kbase = w * 128 + hf * 64;
            const float* xp = (kbase < 512)
                ? (xT + (size_t)kbase * 32 + b)
                : (xT + (size_t)(512 + hoff + (kbase - 512)) * 32 + b);
            float acc[8] = {};
            #pragma unroll
            for (int kk = 0; kk < 64; kk += 8) {
                float xv[8];
                #pragma unroll
                for (int i = 0; i < 8; i++)
                    xv[i] = g_load(xp + (size_t)(kk + i) * 32);
                #pragma unroll
                for (int r = 0; r < 8; r++) {
                    const float* wr = &Wl[r * 1024 + kbase + kk];
                    float s0 = xv[0] * wr[0] + xv[1] * wr[1] + xv[2] * wr[2] + xv[3] * wr[3];
                    float s1 = xv[4] * wr[4] + xv[5] * wr[5] + xv[6] * wr[6] + xv[7] * wr[7];
                    acc[r] += s0 + s1;
                }
            }
            #pragma unroll
            for (int r = 0; r < 8; r++) acc[r] += __shfl_xor(acc[r], 32);
            if (hf == 0) {
                #pragma unroll
                for (int r = 0; r < 8; r++) red_s[w * 256 + r * 32 + b] = acc[r];
            }
            __syncthreads();
            if (tid < 256) {
                const int r = tid >> 5, b2 = tid & 31;
                const int j = (r >> 1) * 512 + u0 + (r & 1);
                float g = G0T[(size_t)j * 1024 + t * 32 + b2];
                #pragma unroll
                for (int ww = 0; ww < 8; ww++) g += red_s[ww * 256 + r * 32 + b2];
                gate_s[r * 32 + b2] = g;
            }
            __syncthreads();
            if (tid < 64) {
                const int ui = tid >> 5, b2 = tid & 31, u = u0 + ui;
                const float gi = gate_s[(0 + ui) * 32 + b2];
                const float gf = gate_s[(2 + ui) * 32 + b2];
                const float gg = gate_s[(4 + ui) * 32 + b2];
                const float go = gate_s[(6 + ui) * 32 + b2];
                const float cn = sigf(gf) * creg + sigf(gi) * tanhf(gg);
                const float hn = sigf(go) * tanhf(cn);
                creg = cn;
                g_store(&xT[(size_t)(512 + (t & 1) * 512 + u) * 32 + b2], hn);
                g_store(&h_b[b2 * 512 + u], hn);
                h_hist[((size_t)t * B_ + b2) * 512 + u] = hn;
            }
        }
        full_sync(bar, 2 * t);

        // -------- Phase B: scores -----------------------------------------
        {
            h_s[tid] = g_load(&h_b[bb * 512 + tid]);
            __syncthreads();
            for (int i = w; i < 25; i += 8) {
                const int s = p * 25 + i;
                const float* sr = src + ((size_t)bb * S_ + s) * 512;
                const float4 x0 = *(const float4*)(sr + lane * 4);
                const float4 x1 = *(const float4*)(sr + 256 + lane * 4);
                const float4 h0 = *(const float4*)(&h_s[lane * 4]);
                const float4 h1 = *(const float4*)(&h_s[256 + lane * 4]);
                float a = x0.x * h0.x + x0.y * h0.y + x0.z * h0.z + x0.w * h0.w
                        + x1.x * h1.x + x1.y * h1.y + x1.z * h1.z + x1.w * h1.w;
                #pragma unroll
                for (int mk = 1; mk < 64; mk <<= 1) a += __shfl_xor(a, mk);
                if (lane == 0) g_store(&scb[bb * 256 + s], (s < len) ? a : -INFINITY);
            }
        }
        sub_sync(bar, bb, t);

        // -------- Phase C: softmax + att slice ----------------------------
        {
            if (tid < 64) {
                const float v0 = g_load(&scb[bb * 256 + tid]);
                const float v1 = g_load(&scb[bb * 256 + 64 + tid]);
                const float v2 = g_load(&scb[bb * 256 + 128 + tid]);
                const float v3 = (tid < 8) ? g_load(&scb[bb * 256 + 192 + tid]) : -INFINITY;
                float m = fmaxf(fmaxf(v0, v1), fmaxf(v2, v3));
                #pragma unroll
                for (int mk = 1; mk < 64; mk <<= 1) m = fmaxf(m, __shfl_xor(m, mk));
                const float e0 = expf(v0 - m), e1 = expf(v1 - m), e2 = expf(v2 - m);
                const float e3 = (tid < 8) ? expf(v3 - m) : 0.f;
                float sum = (e0 + e1) + (e2 + e3);
                #pragma unroll
                for (int mk = 1; mk < 64; mk <<= 1) sum += __shfl_xor(sum, mk);
                const float inv = 1.f / sum;
                al[tid] = e0 * inv; al[64 + tid] = e1 * inv; al[128 + tid] = e2 * inv;
                if (tid < 8) al[192 + tid] = e3 * inv;
            }
            __syncthreads();
            const int jl = tid & 63, sg = tid >> 6;
            float uacc = 0.f;
            #pragma unroll 5
            for (int s = sg * 25; s < sg * 25 + 25; s++)
                uacc += al[s] * Ul[s * 64 + jl];
            const float* wc0 = WaRT + (size_t)(sg * 64) * 512 + p * 64 + jl;
            const float* hp = &h_s[sg * 64];
            float c0 = 0.f, c1 = 0.f;
            #pragma unroll 8
            for (int kk = 0; kk < 64; kk += 2) {
                c0 += hp[kk] * wc0[(size_t)kk * 512];
                c1 += hp[kk + 1] * wc0[(size_t)(kk + 1) * 512];
            }
            pr[tid] = uacc + c0 + c1;
            __syncthreads();
            if (tid < 64) {
                float tot = 0.f;
                #pragma unroll
                for (int sgg = 0; sgg < 8; sgg++) tot += pr[sgg * 64 + tid];
                const float a = tanhf(tot);
                g_store(&xT[(size_t)(p * 64 + tid) * 32 + bb], a);
                att_hist[((size_t)t * B_ + bb) * 512 + p * 64 + tid] = a;
            }
        }
        full_sync(bar, 2 * t + 1);
    }
}

// ---------------------------------------------------------------------------
// k_dec: bf16-split decode output; row-major dh/dl + chunk-major dhk/dlk.
// ---------------------------------------------------------------------------
__global__ __launch_bounds__(256) void k_dec(const int* __restrict__ tgt_in,
                                             const float* __restrict__ emb,
                                             const float* __restrict__ h_hist,
                                             const float* __restrict__ att_hist,
                                             const float* __restrict__ Wgen,
                                             const float* __restrict__ bgen,
                                             unsigned short* __restrict__ dh,
                                             unsigned short* __restrict__ dl,
                                             unsigned short* __restrict__ dhk,
                                             unsigned short* __restrict__ dlk,
                                             int pre) {
    __shared__ float a_s[32][66];
    __shared__ float w_s[32][130];
    const int tid = threadIdx.x;
    const int m0 = blockIdx.x * 64, n0 = blockIdx.y * 128;
    const int mq = tid >> 5, nq = tid & 31;
    float acc[8][4] = {};
    for (int k0 = 0; k0 < 1536; k0 += 32) {
        {
            const int mm = tid >> 2, kq = tid & 3, kk = kq * 8;
            const int m = m0 + mm;
            const float* row;
            if (k0 < 512)       row = emb + (size_t)tgt_in[m] * E_ + k0;
            else if (k0 < 1024) row = h_hist + (size_t)m * 512 + (k0 - 512);
            else                row = att_hist + (size_t)m * 512 + (k0 - 1024);
            row += kk;
            float4 v0 = *(const float4*)(row);
            float4 v1 = *(const float4*)(row + 4);
            a_s[kk + 0][mm] = v0.x; a_s[kk + 1][mm] = v0.y;
            a_s[kk + 2][mm] = v0.z; a_s[kk + 3][mm] = v0.w;
            a_s[kk + 4][mm] = v1.x; a_s[kk + 5][mm] = v1.y;
            a_s[kk + 6][mm] = v1.z; a_s[kk + 7][mm] = v1.w;
        }
        {
            const int nn = tid >> 1, kq = tid & 1, kk = kq * 16;
            const float* row = Wgen + (size_t)(n0 + nn) * 1536 + k0 + kk;
            #pragma unroll
            for (int u = 0; u < 4; u++) {
                float4 v = *(const float4*)(row + u * 4);
                w_s[kk + u * 4 + 0][nn] = v.x; w_s[kk + u * 4 + 1][nn] = v.y;
                w_s[kk + u * 4 + 2][nn] = v.z; w_s[kk + u * 4 + 3][nn] = v.w;
            }
        }
        __syncthreads();
        for (int k = 0; k < 32; k++) {
            float a[8], wv[4];
            #pragma unroll
            for (int i = 0; i < 8; i++) a[i] = a_s[k][mq + 8 * i];
            #pragma unroll
            for (int pq = 0; pq < 4; pq++) wv[pq] = w_s[k][nq + 32 * pq];
            #pragma unroll
            for (int i = 0; i < 8; i++)
                #pragma unroll
                for (int pq = 0; pq < 4; pq++) acc[i][pq] += a[i] * wv[pq];
        }
        __syncthreads();
    }
    #pragma unroll
    for (int i = 0; i < 8; i++) {
        const int m = m0 + mq + 8 * i;
        #pragma unroll
        for (int pq = 0; pq < 4; pq++) {
            const int n = n0 + nq + 32 * pq;
            const float v = tanhf(acc[i][pq] + bgen[n]);
            const unsigned short hb = f2bf(v);
            const unsigned short lb = f2bf(v - bf2f(hb));
            dh[(size_t)m * 512 + n] = hb;
            dl[(size_t)m * 512 + n] = lb;
            if (pre) {
                const size_t ca = (size_t)(n >> 5) * 32768 + (size_t)(m >> 6) * 2048
                                + (size_t)(m & 63) * 32 + (n & 31);
                dhk[ca] = hb;
                dlk[ca] = lb;
            }
        }
    }
}

// ===========================================================================
// k_read_pre: MFMA readout, M=128 rows x N=256 cols per block, K=512.
// Double-buffered async B staging from pre-swizzled chunk-major whk/wlk;
// A-frags per-lane direct from chunk-major dhk/dlk. Grid 1600 XCD-grouped,
// LDS 64 KB -> 2 blocks/CU.
// ===========================================================================
__global__ __launch_bounds__(256) void k_read_pre(const unsigned short* __restrict__ dhk,
                                                  const unsigned short* __restrict__ dlk,
                                                  const unsigned short* __restrict__ whk,
                                                  const unsigned short* __restrict__ wlk,
                                                  const int* __restrict__ tgt_out,
                                                  float4* __restrict__ part,
                                                  float* __restrict__ tgt_logit) {
    __shared__ __align__(16) unsigned short BhL[2][8192];   // 32 KB
    __shared__ __align__(16) unsigned short BlL[2][8192];   // 32 KB
    __shared__ float ep_max[128][2];
    __shared__ int   ep_idx[128][2];
    __shared__ float ep_fin[128];
    __shared__ int   ep_fidx[128];
    __shared__ float ep_sum[128][2];

    const int xcd = blockIdx.x & 7;
    const int idx = blockIdx.x >> 3;
    const int m2  = idx & 7;              // 0..7 (128-row tile)
    const int group = idx >> 3;           // 0..24
    const int ch = group * 8 + xcd;
    if (ch >= NCH) return;
    const int m0 = m2 * 128, n0 = ch * 256;

    const int tid = threadIdx.x;
    const int lane = tid & 63, wid = tid >> 6;
    const int wr = wid >> 1, wc = wid & 1;
    const int l15 = lane & 15, lk = lane >> 4;

    f32x4 acc[2][2][8];                   // [mhalf][mt][nt]
    #pragma unroll
    for (int mh = 0; mh < 2; mh++)
        #pragma unroll
        for (int mt = 0; mt < 2; mt++)
            #pragma unroll
            for (int nt = 0; nt < 8; nt++) acc[mh][mt][nt] = {0.f, 0.f, 0.f, 0.f};

    const unsigned short* bh_src = whk + (size_t)n0 * 32;
    const unsigned short* bl_src = wlk + (size_t)n0 * 32;
    const unsigned short* ah_base = dhk + (size_t)(m0 >> 6) * 2048 + lk * 8;
    const unsigned short* al_base = dlk + (size_t)(m0 >> 6) * 2048 + lk * 8;

    // prologue: stage chunk 0 into buffer 0
    {
        const char* gh = (const char*)bh_src;
        const char* gl = (const char*)bl_src;
        #pragma unroll
        for (int c = 0; c < 4; c++) {
            const int ob = wid * 4096 + c * 1024;
            async16((char*)&BhL[0][0] + ob, gh + ob + lane * 16);
            async16((char*)&BlL[0][0] + ob, gl + ob + lane * 16);
        }
    }
    __syncthreads();

    for (int kc = 0; kc < 16; kc++) {
        const int cur = kc & 1;
        bf16x8 afh[2][2], afl[2][2];      // [mhalf][mt]
        {   // A fragments first (compiler's A-wait then counts stage behind it)
            const unsigned short* ah = ah_base + (size_t)kc * 32768;
            const unsigned short* al = al_base + (size_t)kc * 32768;
            #pragma unroll
            for (int mh = 0; mh < 2; mh++)
                #pragma unroll
                for (int mt = 0; mt < 2; mt++) {
                    const int r = wr * 32 + mt * 16 + l15;
                    afh[mh][mt] = *(const bf16x8*)(ah + mh * 2048 + r * 32);
                    afl[mh][mt] = *(const bf16x8*)(al + mh * 2048 + r * 32);
                }
        }
        if (kc < 15) {   // stage next chunk into the other buffer
            const size_t cb = (size_t)(kc + 1) * ((size_t)VP_ * 32);
            const char* gh = (const char*)(bh_src + cb);
            const char* gl = (const char*)(bl_src + cb);
            #pragma unroll
            for (int c = 0; c < 4; c++) {
                const int ob = wid * 4096 + c * 1024;
                async16((char*)&BhL[cur ^ 1][0] + ob, gh + ob + lane * 16);
                async16((char*)&BlL[cur ^ 1][0] + ob, gl + ob + lane * 16);
            }
        }
        #pragma unroll
        for (int nt = 0; nt < 8; nt++) {
            const int nn = wc * 128 + nt * 16 + l15;
            const int bo = nn * 32 + ((lk ^ ((nn >> 1) & 3)) * 8);
            bf16x8 bh = *(const bf16x8*)&BhL[cur][bo];
            bf16x8 bl = *(const bf16x8*)&BlL[cur][bo];
            #pragma unroll
            for (int mh = 0; mh < 2; mh++)
                #pragma unroll
                for (int mt = 0; mt < 2; mt++) {
                    acc[mh][mt][nt] = __builtin_amdgcn_mfma_f32_16x16x32_bf16(afh[mh][mt], bh, acc[mh][mt][nt], 0, 0, 0);
                    acc[mh][mt][nt] = __builtin_amdgcn_mfma_f32_16x16x32_bf16(afl[mh][mt], bh, acc[mh][mt][nt], 0, 0, 0);
                    acc[mh][mt][nt] = __builtin_amdgcn_mfma_f32_16x16x32_bf16(afh[mh][mt], bl, acc[mh][mt][nt], 0, 0, 0);
                }
        }
        __syncthreads();   // drains vmcnt (next stage landed) + readers done
    }

    // ---- epilogue: per-row max/idx over this block's 256-col chunk ----
    #pragma unroll
    for (int mh = 0; mh < 2; mh++)
        #pragma unroll
        for (int mt = 0; mt < 2; mt++)
            #pragma unroll
            for (int reg = 0; reg < 4; reg++) {
                float bv = -INFINITY; int bi = 0x7fffffff;
                #pragma unroll
                for (int nt = 0; nt < 8; nt++) {
                    const int n = n0 + wc * 128 + nt * 16 + l15;
                    const float v = (n < V_) ? acc[mh][mt][nt][reg] : -INFINITY;
                    if (v > bv || (v == bv && n < bi)) { bv = v; bi = n; }
                }
                #pragma unroll
                for (int mk = 1; mk < 16; mk <<= 1) {
                    const float ov = __shfl_xor(bv, mk);
                    const int oi = __shfl_xor(bi, mk);
                    if (ov > bv || (ov == bv && oi < bi)) { bv = ov; bi = oi; }
                }
                if (l15 == 0) {
                    const int rl = mh * 64 + wr * 32 + mt * 16 + lk * 4 + reg;
                    ep_max[rl][wc] = bv; ep_idx[rl][wc] = bi;
                }
            }
    __syncthreads();
    if (tid < 128) {
        const float a = ep_max[tid][0], b = ep_max[tid][1];
        const int ia = ep_idx[tid][0], ib = ep_idx[tid][1];
        const bool tb = (b > a) || (b == a && ib < ia);
        ep_fin[tid] = tb ? b : a; ep_fidx[tid] = tb ? ib : ia;
    }
    __syncthreads();
    #pragma unroll
    for (int mh = 0; mh < 2; mh++)
        #pragma unroll
        for (int mt = 0; mt < 2; mt++)
            #pragma unroll
            for (int reg = 0; reg < 4; reg++) {
                const int rl = mh * 64 + wr * 32 + mt * 16 + lk * 4 + reg;
                const float M = ep_fin[rl];
                const int rel = tgt_out[m0 + rl] - n0;
                float se = 0.f;
                #pragma unroll
                for (int nt = 0; nt < 8; nt++) {
                    const int nl = wc * 128 + nt * 16 + l15;
                    if (n0 + nl < V_) {
                        const float v = acc[mh][mt][nt][reg];
                        se += expf(v - M);
                        if (nl == rel) tgt_logit[m0 + rl] = v;
                    }
                }
                #pragma unroll
                for (int mk = 1; mk < 16; mk <<= 1) se += __shfl_xor(se, mk);
                if (l15 == 0) ep_sum[rl][wc] = se;
            }
    __syncthreads();
    if (tid < 128) {
        part[(size_t)(m0 + tid) * NCH + ch] =
            make_float4(ep_fin[tid], ep_sum[tid][0] + ep_sum[tid][1],
                        __int_as_float(ep_fidx[tid]), 0.f);
    }
}

// ---------------------------------------------------------------------------
// k_read (fallback: in-kernel conversion, row-major dh/dl, grid 3200)
// ---------------------------------------------------------------------------
__global__ __launch_bounds__(256) void k_read(const unsigned short* __restrict__ dh,
                                              const unsigned short* __restrict__ dl,
                                              const float* __restrict__ Wread,
                                              const int* __restrict__ tgt_out,
                                              float4* __restrict__ part,
                                              float* __restrict__ tgt_logit) {
    __shared__ __align__(16) unsigned short Bh[4][256][8];
    __shared__ __align__(16) unsigned short Bl[4][256][8];
    __shared__ __align__(16) unsigned short Ah[4][64][8];
    __shared__ __align__(16) unsigned short Alo[4][64][8];
    __shared__ float ep_max[64][2];
    __shared__ int   ep_idx[64][2];
    __shared__ float ep_fin[64];
    __shared__ int   ep_fidx[64];
    __shared__ float ep_sum[64][2];

    const int xcd = blockIdx.x & 7;
    const int idx = blockIdx.x >> 3;
    const int mi  = idx & 15;
    const int group = idx >> 4;
    const int ch = group * 8 + xcd;
    if (ch >= NCH) return;
    const int m0 = mi * 64, n0 = ch * 256;

    const int tid = threadIdx.x;
    const int lane = tid & 63, wid = tid >> 6;
    const int wr = wid >> 1, wc = wid & 1;
    const int l15 = lane & 15, lk = lane >> 4;

    f32x4 acc[2][8];
    #pragma unroll
    for (int mt = 0; mt < 2; mt++)
        #pragma unroll
        for (int nt = 0; nt < 8; nt++) acc[mt][nt] = {0.f, 0.f, 0.f, 0.f};

    for (int kc = 0; kc < 512; kc += 32) {
        {
            const int n = n0 + tid;
            const float* row = Wread + (size_t)n * 512 + kc;
            #pragma unroll
            for (int g = 0; g < 4; g++) {
                uint4 h4, l4;
                if (n < V_) {
                    float4 p0 = *(const float4*)(row + g * 8);
                    float4 p1 = *(const float4*)(row + g * 8 + 4);
                    float v[8] = {p0.x, p0.y, p0.z, p0.w, p1.x, p1.y, p1.z, p1.w};
                    unsigned int hb[8], lb[8];
                    #pragma unroll
                    for (int e = 0; e < 8; e++) {
                        hb[e] = f2bf(v[e]);
                        lb[e] = f2bf(v[e] - bf2f((unsigned short)hb[e]));
                    }
                    h4 = make_uint4(hb[0] | (hb[1] << 16), hb[2] | (hb[3] << 16),
                                    hb[4] | (hb[5] << 16), hb[6] | (hb[7] << 16));
                    l4 = make_uint4(lb[0] | (lb[1] << 16), lb[2] | (lb[3] << 16),
                                    lb[4] | (lb[5] << 16), lb[6] | (lb[7] << 16));
                } else {
                    h4 = make_uint4(0, 0, 0, 0);
                    l4 = make_uint4(0, 0, 0, 0);
                }
                *(uint4*)&Bh[g][tid][0] = h4;
                *(uint4*)&Bl[g][tid][0] = l4;
            }
        }
        {
            const int row = tid >> 2, g = tid & 3;
            *(uint4*)&Ah[g][row][0]  = *(const uint4*)(dh + (size_t)(m0 + row) * 512 + kc + g * 8);
            *(uint4*)&Alo[g][row][0] = *(const uint4*)(dl + (size_t)(m0 + row) * 512 + kc + g * 8);
        }
        __syncthreads();
        {
            bf16x8 afh[2], afl[2];
            #pragma unroll
            for (int mt = 0; mt < 2; mt++) {
                const int r = wr * 32 + mt * 16 + l15;
                afh[mt] = *(const bf16x8*)&Ah[lk][r][0];
                afl[mt] = *(const bf16x8*)&Alo[lk][r][0];
            }
            #pragma unroll
            for (int nt = 0; nt < 8; nt++) {
                const int nn = wc * 128 + nt * 16 + l15;
                bf16x8 bh = *(const bf16x8*)&Bh[lk][nn][0];
                bf16x8 bl = *(const bf16x8*)&Bl[lk][nn][0];
                #pragma unroll
                for (int mt = 0; mt < 2; mt++) {
                    acc[mt][nt] = __builtin_amdgcn_mfma_f32_16x16x32_bf16(afh[mt], bh, acc[mt][nt], 0, 0, 0);
                    acc[mt][nt] = __builtin_amdgcn_mfma_f32_16x16x32_bf16(afl[mt], bh, acc[mt][nt], 0, 0, 0);
                    acc[mt][nt] = __builtin_amdgcn_mfma_f32_16x16x32_bf16(afh[mt], bl, acc[mt][nt], 0, 0, 0);
                }
            }
        }
        __syncthreads();
    }

    #pragma unroll
    for (int mt = 0; mt < 2; mt++)
        #pragma unroll
        for (int reg = 0; reg < 4; reg++) {
            float bv = -INFINITY; int bi = 0x7fffffff;
            #pragma unroll
            for (int nt = 0; nt < 8; nt++) {
                const int n = n0 + wc * 128 + nt * 16 + l15;
                const float v = (n < V_) ? acc[mt][nt][reg] : -INFINITY;
                if (v > bv || (v == bv && n < bi)) { bv = v; bi = n; }
            }
            #pragma unroll
            for (int mk = 1; mk < 16; mk <<= 1) {
                const float ov = __shfl_xor(bv, mk);
                const int oi = __shfl_xor(bi, mk);
                if (ov > bv || (ov == bv && oi < bi)) { bv = ov; bi = oi; }
            }
            if (l15 == 0) {
                const int rl = wr * 32 + mt * 16 + lk * 4 + reg;
                ep_max[rl][wc] = bv; ep_idx[rl][wc] = bi;
            }
        }
    __syncthreads();
    if (tid < 64) {
        const float a = ep_max[tid][0], b = ep_max[tid][1];
        const int ia = ep_idx[tid][0], ib = ep_idx[tid][1];
        const bool tb = (b > a) || (b == a && ib < ia);
        ep_fin[tid] = tb ? b : a; ep_fidx[tid] = tb ? ib : ia;
    }
    __syncthreads();
    #pragma unroll
    for (int mt = 0; mt < 2; mt++)
        #pragma unroll
        for (int reg = 0; reg < 4; reg++) {
            const int rl = wr * 32 + mt * 16 + lk * 4 + reg;
            const float M = ep_fin[rl];
            const int rel = tgt_out[m0 + rl] - n0;
            float se = 0.f;
            #pragma unroll
            for (int nt = 0; nt < 8; nt++) {
                const int nl = wc * 128 + nt * 16 + l15;
                if (n0 + nl < V_) {
                    const float v = acc[mt][nt][reg];
                    se += expf(v - M);
                    if (nl == rel) tgt_logit[m0 + rl] = v;
                }
            }
            #pragma unroll
            for (int mk = 1; mk < 16; mk <<= 1) se += __shfl_xor(se, mk);
            if (l15 == 0) ep_sum[rl][wc] = se;
        }
    __syncthreads();
    if (tid < 64) {
        part[(size_t)(m0 + tid) * NCH + ch] =
            make_float4(ep_fin[tid], ep_sum[tid][0] + ep_sum[tid][1],
                        __int_as_float(ep_fidx[tid]), 0.f);
    }
}

// ---------------------------------------------------------------------------
// k_merge: combine chunk partials -> loss + argmax
// ---------------------------------------------------------------------------
__global__ __launch_bounds__(256) void k_merge(const float4* __restrict__ part,
                                               const float* __restrict__ tgt_logit,
                                               const int* __restrict__ tgt_out,
                                               float* __restrict__ out) {
    const int tid = threadIdx.x;
    const int w = tid >> 6, lane = tid & 63;
    const int row = blockIdx.x * 4 + w;
    float bm = -INFINITY; int bi = 0x7fffffff;
    for (int ch = lane; ch < NCH; ch += 64) {
        const float4 p = part[(size_t)row * NCH + ch];
        const int pi = __float_as_int(p.z);
        if (p.x > bm || (p.x == bm && pi < bi)) { bm = p.x; bi = pi; }
    }
    #pragma unroll
    for (int mk = 1; mk < 64; mk <<= 1) {
        const float ov = __shfl_xor(bm, mk);
        const int oi = __shfl_xor(bi, mk);
        if (ov > bm || (ov == bm && oi < bi)) { bm = ov; bi = oi; }
    }
    float sum = 0.f;
    for (int ch = lane; ch < NCH; ch += 64) {
        const float4 p = part[(size_t)row * NCH + ch];
        sum += p.y * expf(p.x - bm);
    }
    #pragma unroll
    for (int mk = 1; mk < 64; mk <<= 1) sum += __shfl_xor(sum, mk);
    if (lane == 0) {
        const float lse = bm + logf(sum);
        const int tg = tgt_out[row];
        const float loss = (tg != 0) ? (lse - tgt_logit[row]) : 0.f;
        out[row] = loss;
        out[1024 + row] = (float)bi;
    }
}

// ---------------------------------------------------------------------------
extern "C" void kernel_launch(void* const* d_in, const int* in_sizes, int n_in,
                              void* d_out, int out_size, void* d_ws, size_t ws_size,
                              hipStream_t stream) {
    const int* tgt_in = (const int*)d_in[0];
    const int* tgt_out = (const int*)d_in[1];
    const int* src_lens = (const int*)d_in[2];
    const float* src = (const float*)d_in[3];
    const float* last_state = (const float*)d_in[4];
    const float* last_cell = (const float*)d_in[5];
    const float* emb = (const float*)d_in[6];
    const float* Wih = (const float*)d_in[7];
    const float* Whh = (const float*)d_in[8];
    const float* bih = (const float*)d_in[9];
    const float* bhh = (const float*)d_in[10];
    const float* Wattn = (const float*)d_in[11];
    const float* Wgen = (const float*)d_in[12];
    const float* bgen = (const float*)d_in[13];
    const float* Wread = (const float*)d_in[14];
    float* out = (float*)d_out;

    float* ws = (float*)d_ws;
    float* G0T      = ws;                    // 2,097,152 f
    float* U        = G0T + 2097152;         // 3,276,800 f
    float* WaRT     = U + 3276800;           // 262,144 f
    unsigned short* dh  = (unsigned short*)(WaRT + 262144);  // 524,288 u16
    unsigned short* dl  = dh + 524288;
    unsigned short* dhk = dl + 524288;       // chunk-major
    unsigned short* dlk = dhk + 524288;
    float* h_hist   = (float*)(dlk + 524288);
    float* att_hist = h_hist + 524288;
    float* xT       = att_hist + 524288;     // 49,152 f
    float* h_b      = xT + 49152;            // 16,384 f
    float* scb      = h_b + 16384;           // 8,192 f
    float4* part    = (float4*)(scb + 8192); // 200,704 float4
    float* tgtl     = ((float*)part) + 802816; // 1,024 f
    int* bar        = (int*)(tgtl + 1024);     // 2,048 ints
    unsigned short* whk = (unsigned short*)(bar + 2048);   // VP_*512 u16
    unsigned short* wlk = whk + (size_t)VP_ * 512;

    const size_t need = (size_t)((char*)(wlk + (size_t)VP_ * 512) - (char*)ws);
    const int pre = (ws_size >= need) ? 1 : 0;

    hipMemsetAsync(bar, 0, 8192, stream);

    k_init<<<64, 256, 0, stream>>>(last_state, xT);
    k_g0<<<dim3(16, 16), 256, 0, stream>>>(tgt_in, emb, Wih, bih, bhh, G0T);
    k_u<<<dim3(100, 4), 256, 0, stream>>>(src, Wattn, U);
    k_tr<<<dim3(16, 16), 256, 0, stream>>>(Wattn, WaRT);
    if (pre)
        k_wconv<<<12544, 256, 0, stream>>>(Wread, whk, wlk);

    k_scan<<<256, 512, 0, stream>>>(G0T, U, WaRT, Wih, Whh, src, src_lens, last_cell,
                                    xT, h_b, scb, h_hist, att_hist, bar);

    k_dec<<<dim3(16, 4), 256, 0, stream>>>(tgt_in, emb, h_hist, att_hist, Wgen, bgen,
                                           dh, dl, dhk, dlk, pre);
    if (pre)
        k_read_pre<<<1600, 256, 0, stream>>>(dhk, dlk, whk, wlk, tgt_out, part, tgtl);
    else
        k_read<<<3200, 256, 0, stream>>>(dh, dl, Wread, tgt_out, part, tgtl);
    k_merge<<<256, 256, 0, stream>>>(part, tgtl, tgt_out, out);
}

// Round 14
// 1021.814 us; speedup vs baseline: 1.2313x; 1.1568x over previous
//
#include <hip/hip_runtime.h>
#include <math.h>

#define T_ 32
#define B_ 32
#define S_ 200
#define E_ 512
#define H_ 512
#define V_ 50000
#define VP_ 50176   // padded rows for chunk-major bf16 W
#define G4_ 2048
#define NCH 196     // ceil(50000/256)

using bf16x8 = __attribute__((ext_vector_type(8))) __bf16;
using f32x4  = __attribute__((ext_vector_type(4))) float;

__device__ __forceinline__ float sigf(float x) { return 1.f / (1.f + expf(-x)); }

__device__ __forceinline__ unsigned short f2bf(float v) {
    unsigned int x = __float_as_uint(v);
    return (unsigned short)((x + 0x7FFFu + ((x >> 16) & 1u)) >> 16);
}
__device__ __forceinline__ float bf2f(unsigned short b) {
    return __uint_as_float(((unsigned int)b) << 16);
}

// async global->LDS 16B copy
__device__ __forceinline__ void async16(void* lds, const void* g) {
    __builtin_amdgcn_global_load_lds(
        (const __attribute__((address_space(1))) unsigned int*)g,
        (__attribute__((address_space(3))) unsigned int*)lds, 16, 0, 0);
}

// Coherent LLC-level exchange (relaxed agent atomics -> sc1 load/store)
__device__ __forceinline__ void g_store(float* p, float v) {
    __hip_atomic_store(p, v, __ATOMIC_RELAXED, __HIP_MEMORY_SCOPE_AGENT);
}
__device__ __forceinline__ float g_load(const float* p) {
    return __hip_atomic_load(p, __ATOMIC_RELAXED, __HIP_MEMORY_SCOPE_AGENT);
}

// ---------------------------------------------------------------------------
// Fence-free grid barrier (proven rounds 5-13).
// ---------------------------------------------------------------------------
__device__ __forceinline__ void full_sync(int* bar, int ep) {
    __syncthreads();
    if (threadIdx.x == 0) {
        const int g = blockIdx.x & 7;
        int a = __hip_atomic_fetch_add(&bar[g * 32], 1, __ATOMIC_RELAXED, __HIP_MEMORY_SCOPE_AGENT);
        if (a == ep * 32 + 31) {
            int q = __hip_atomic_fetch_add(&bar[256], 1, __ATOMIC_RELAXED, __HIP_MEMORY_SCOPE_AGENT);
            if (q == ep * 8 + 7) {
                #pragma unroll
                for (int i = 0; i < 8; i++)
                    __hip_atomic_store(&bar[288 + i * 32], ep + 1, __ATOMIC_RELAXED, __HIP_MEMORY_SCOPE_AGENT);
            }
        }
        while (__hip_atomic_load(&bar[288 + g * 32], __ATOMIC_RELAXED, __HIP_MEMORY_SCOPE_AGENT) < ep + 1)
            __builtin_amdgcn_s_sleep(1);
    }
    __syncthreads();
}

__device__ __forceinline__ void sub_sync(int* bar, int bb, int t) {
    __syncthreads();
    if (threadIdx.x == 0) {
        __hip_atomic_fetch_add(&bar[544 + bb * 32], 1, __ATOMIC_RELAXED, __HIP_MEMORY_SCOPE_AGENT);
        while (__hip_atomic_load(&bar[544 + bb * 32], __ATOMIC_RELAXED, __HIP_MEMORY_SCOPE_AGENT) < (t + 1) * 8)
            __builtin_amdgcn_s_sleep(1);
    }
    __syncthreads();
}

// ---------------------------------------------------------------------------
// k_init: xT rows 0..511 att=0; rows 1024..1535 = last_state^T (h slot 1).
// ---------------------------------------------------------------------------
__global__ __launch_bounds__(256) void k_init(const float* __restrict__ last_state,
                                              float* __restrict__ xT) {
    const int f = blockIdx.x * 256 + threadIdx.x;   // 0..16383
    xT[f] = 0.f;
    const int k = f >> 5, b = f & 31;
    xT[32768 + f] = last_state[b * 512 + k];
}

// ---------------------------------------------------------------------------
// k_cvt: fp32 -> bf16 hi/lo for prologue GEMM operands.
//  R0 src   (6400x512)  -> sh/sl
//  R1 WattnL (512x512)  -> wah/wal   (Wattn[:, 0:512])
//  R2 WihL  (2048x512)  -> wih_h/wih_l (Wih[:, 0:512])
//  R3 embg  (1024x512)  -> eh/el    (gathered emb rows)
// One float4 item per thread; grid covers all items.
// ---------------------------------------------------------------------------
#define CVT_R0 819200
#define CVT_R1 (CVT_R0 + 65536)
#define CVT_R2 (CVT_R1 + 262144)
#define CVT_R3 (CVT_R2 + 131072)
__global__ __launch_bounds__(256) void k_cvt(const float* __restrict__ src,
                                             const float* __restrict__ Wattn,
                                             const float* __restrict__ Wih,
                                             const float* __restrict__ emb,
                                             const int* __restrict__ tgt_in,
                                             unsigned short* __restrict__ sh,
                                             unsigned short* __restrict__ sl,
                                             unsigned short* __restrict__ wah,
                                             unsigned short* __restrict__ wal,
                                             unsigned short* __restrict__ wih_h,
                                             unsigned short* __restrict__ wih_l,
                                             unsigned short* __restrict__ eh,
                                             unsigned short* __restrict__ el) {
    const int u = blockIdx.x * 256 + threadIdx.x;
    if (u >= CVT_R3) return;
    const float* sp;
    unsigned short *dh_, *dl_;
    size_t doff;
    if (u < CVT_R0) {
        sp = src + (size_t)u * 4;
        dh_ = sh; dl_ = sl; doff = (size_t)u * 4;
    } else if (u < CVT_R1) {
        const int idx = u - CVT_R0;
        const int k4 = idx & 127, n = idx >> 7;
        sp = Wattn + (size_t)n * 1024 + k4 * 4;
        dh_ = wah; dl_ = wal; doff = (size_t)n * 512 + k4 * 4;
    } else if (u < CVT_R2) {
        const int idx = u - CVT_R1;
        const int k4 = idx & 127, j = idx >> 7;
        sp = Wih + (size_t)j * 1024 + k4 * 4;
        dh_ = wih_h; dl_ = wih_l; doff = (size_t)j * 512 + k4 * 4;
    } else {
        const int idx = u - CVT_R2;
        const int k4 = idx & 127, m = idx >> 7;
        sp = emb + (size_t)tgt_in[m] * 512 + k4 * 4;
        dh_ = eh; dl_ = el; doff = (size_t)m * 512 + k4 * 4;
    }
    const float4 v = *(const float4*)sp;
    const float vv[4] = {v.x, v.y, v.z, v.w};
    unsigned int hb[4], lb[4];
    #pragma unroll
    for (int e = 0; e < 4; e++) {
        hb[e] = f2bf(vv[e]);
        lb[e] = f2bf(vv[e] - bf2f((unsigned short)hb[e]));
    }
    *(uint2*)(dh_ + doff) = make_uint2(hb[0] | (hb[1] << 16), hb[2] | (hb[3] << 16));
    *(uint2*)(dl_ + doff) = make_uint2(lb[0] | (lb[1] << 16), lb[2] | (lb[3] << 16));
}

// ---------------------------------------------------------------------------
// k_gbt: C = A . B^T via bf16-split MFMA (3 terms). A[m][k], B[n][k] bf16
// hi/lo row-major K=512. 64(M)x256(N) tile, LDS-free (per-lane direct 16B
// fragment loads, B is L2-hot). mode 0: out[m*512+n] (U). mode 1:
// out[n*1024+m] + bih[n] + bhh[n] (G0T).
// ---------------------------------------------------------------------------
__global__ __launch_bounds__(256) void k_gbt(const unsigned short* __restrict__ Ah,
                                             const unsigned short* __restrict__ Al,
                                             const unsigned short* __restrict__ Bh,
                                             const unsigned short* __restrict__ Bl,
                                             const float* __restrict__ bih,
                                             const float* __restrict__ bhh,
                                             float* __restrict__ out,
                                             int nbn, int mode) {
    const int m0 = (blockIdx.x / nbn) * 64;
    const int n0 = (blockIdx.x % nbn) * 256;
    const int tid = threadIdx.x;
    const int lane = tid & 63, wid = tid >> 6;
    const int wr = wid >> 1, wc = wid & 1;
    const int l15 = lane & 15, lk = lane >> 4;

    f32x4 acc[2][8];
    #pragma unroll
    for (int mt = 0; mt < 2; mt++)
        #pragma unroll
        for (int nt = 0; nt < 8; nt++) acc[mt][nt] = {0.f, 0.f, 0.f, 0.f};

    for (int kc = 0; kc < 512; kc += 32) {
        bf16x8 afh[2], afl[2];
        #pragma unroll
        for (int mt = 0; mt < 2; mt++) {
            const int r = wr * 32 + mt * 16 + l15;
            const size_t ao = (size_t)(m0 + r) * 512 + kc + lk * 8;
            afh[mt] = *(const bf16x8*)(Ah + ao);
            afl[mt] = *(const bf16x8*)(Al + ao);
        }
        #pragma unroll
        for (int nt = 0; nt < 8; nt++) {
            const int nn = wc * 128 + nt * 16 + l15;
            const size_t bo = (size_t)(n0 + nn) * 512 + kc + lk * 8;
            bf16x8 bh = *(const bf16x8*)(Bh + bo);
            bf16x8 bl = *(const bf16x8*)(Bl + bo);
            #pragma unroll
            for (int mt = 0; mt < 2; mt++) {
                acc[mt][nt] = __builtin_amdgcn_mfma_f32_16x16x32_bf16(afh[mt], bh, acc[mt][nt], 0, 0, 0);
                acc[mt][nt] = __builtin_amdgcn_mfma_f32_16x16x32_bf16(afl[mt], bh, acc[mt][nt], 0, 0, 0);
                acc[mt][nt] = __builtin_amdgcn_mfma_f32_16x16x32_bf16(afh[mt], bl, acc[mt][nt], 0, 0, 0);
            }
        }
    }
    #pragma unroll
    for (int mt = 0; mt < 2; mt++)
        #pragma unroll
        for (int reg = 0; reg < 4; reg++) {
            const int row = m0 + wr * 32 + mt * 16 + lk * 4 + reg;
            #pragma unroll
            for (int nt = 0; nt < 8; nt++) {
                const int col = n0 + wc * 128 + nt * 16 + l15;
                const float v = acc[mt][nt][reg];
                if (mode == 0) out[(size_t)row * 512 + col] = v;
                else           out[(size_t)col * 1024 + row] = v + bih[col] + bhh[col];
            }
        }
}

// ---------------------------------------------------------------------------
// k_g0 (fp32 fallback): G0T[j][m] = emb(tgt_in[m]) . W_ih[j][0:512] + biases
// ---------------------------------------------------------------------------
__global__ __launch_bounds__(256) void k_g0(const int* __restrict__ tgt_in,
                                            const float* __restrict__ emb,
                                            const float* __restrict__ Wih,
                                            const float* __restrict__ bih,
                                            const float* __restrict__ bhh,
                                            float* __restrict__ G0T) {
    __shared__ float a_s[32][66];
    __shared__ float w_s[32][130];
    const int tid = threadIdx.x;
    const int m0 = blockIdx.x * 64, n0 = blockIdx.y * 128;
    const int mq = tid >> 5, nq = tid & 31;
    float acc[8][4] = {};
    for (int k0 = 0; k0 < 512; k0 += 32) {
        {
            const int mm = tid >> 2, kq = tid & 3, kk = kq * 8;
            const float* row = emb + (size_t)tgt_in[m0 + mm] * E_ + k0 + kk;
            float4 v0 = *(const float4*)(row);
            float4 v1 = *(const float4*)(row + 4);
            a_s[kk + 0][mm] = v0.x; a_s[kk + 1][mm] = v0.y;
            a_s[kk + 2][mm] = v0.z; a_s[kk + 3][mm] = v0.w;
            a_s[kk + 4][mm] = v1.x; a_s[kk + 5][mm] = v1.y;
            a_s[kk + 6][mm] = v1.z; a_s[kk + 7][mm] = v1.w;
        }
        {
            const int nn = tid >> 1, kq = tid & 1, kk = kq * 16;
            const float* row = Wih + (size_t)(n0 + nn) * 1024 + k0 + kk;
            #pragma unroll
            for (int u = 0; u < 4; u++) {
                float4 v = *(const float4*)(row + u * 4);
                w_s[kk + u * 4 + 0][nn] = v.x; w_s[kk + u * 4 + 1][nn] = v.y;
                w_s[kk + u * 4 + 2][nn] = v.z; w_s[kk + u * 4 + 3][nn] = v.w;
            }
        }
        __syncthreads();
        for (int k = 0; k < 32; k++) {
            float a[8], wv[4];
            #pragma unroll
            for (int i = 0; i < 8; i++) a[i] = a_s[k][mq + 8 * i];
            #pragma unroll
            for (int p = 0; p < 4; p++) wv[p] = w_s[k][nq + 32 * p];
            #pragma unroll
            for (int i = 0; i < 8; i++)
                #pragma unroll
                for (int p = 0; p < 4; p++) acc[i][p] += a[i] * wv[p];
        }
        __syncthreads();
    }
    #pragma unroll
    for (int i = 0; i < 8; i++) {
        const int m = m0 + mq + 8 * i;
        #pragma unroll
        for (int p = 0; p < 4; p++) {
            const int n = n0 + nq + 32 * p;
            G0T[(size_t)n * 1024 + m] = acc[i][p] + bih[n] + bhh[n];
        }
    }
}

// ---------------------------------------------------------------------------
// k_u (fp32 fallback): U[b,s,j] = src[b,s,:] . W_attn[j, 0:512]
// ---------------------------------------------------------------------------
__global__ __launch_bounds__(256) void k_u(const float* __restrict__ src,
                                           const float* __restrict__ Wattn,
                                           float* __restrict__ U) {
    __shared__ float a_s[32][66];
    __shared__ float w_s[32][130];
    const int tid = threadIdx.x;
    const int m0 = blockIdx.x * 64, n0 = blockIdx.y * 128;
    const int mq = tid >> 5, nq = tid & 31;
    float acc[8][4] = {};
    for (int k0 = 0; k0 < 512; k0 += 32) {
        {
            const int mm = tid >> 2, kq = tid & 3, kk = kq * 8;
            const float* row = src + (size_t)(m0 + mm) * 512 + k0 + kk;
            float4 v0 = *(const float4*)(row);
            float4 v1 = *(const float4*)(row + 4);
            a_s[kk + 0][mm] = v0.x; a_s[kk + 1][mm] = v0.y;
            a_s[kk + 2][mm] = v0.z; a_s[kk + 3][mm] = v0.w;
            a_s[kk + 4][mm] = v1.x; a_s[kk + 5][mm] = v1.y;
            a_s[kk + 6][mm] = v1.z; a_s[kk + 7][mm] = v1.w;
        }
        {
            const int nn = tid >> 1, kq = tid & 1, kk = kq * 16;
            const float* row = Wattn + (size_t)(n0 + nn) * 1024 + k0 + kk;
            #pragma unroll
            for (int u = 0; u < 4; u++) {
                float4 v = *(const float4*)(row + u * 4);
                w_s[kk + u * 4 + 0][nn] = v.x; w_s[kk + u * 4 + 1][nn] = v.y;
                w_s[kk + u * 4 + 2][nn] = v.z; w_s[kk + u * 4 + 3][nn] = v.w;
            }
        }
        __syncthreads();
        for (int k = 0; k < 32; k++) {
            float a[8], wv[4];
            #pragma unroll
            for (int i = 0; i < 8; i++) a[i] = a_s[k][mq + 8 * i];
            #pragma unroll
            for (int p = 0; p < 4; p++) wv[p] = w_s[k][nq + 32 * p];
            #pragma unroll
            for (int i = 0; i < 8; i++)
                #pragma unroll
                for (int p = 0; p < 4; p++) acc[i][p] += a[i] * wv[p];
        }
        __syncthreads();
    }
    #pragma unroll
    for (int i = 0; i < 8; i++) {
        const int m = m0 + mq + 8 * i;
        #pragma unroll
        for (int p = 0; p < 4; p++)
            U[(size_t)m * 512 + n0 + nq + 32 * p] = acc[i][p];
    }
}

// ---------------------------------------------------------------------------
// k_tr: WaRT[k][j] = W_attn[j][512+k]
// ---------------------------------------------------------------------------
__global__ __launch_bounds__(256) void k_tr(const float* __restrict__ Wattn,
                                            float* __restrict__ WaRT) {
    __shared__ float t_s[32][33];
    const int tid = threadIdx.x;
    const int bx = blockIdx.x, by = blockIdx.y;
    {
        const int jj = tid >> 3, kq = (tid & 7) * 4;
        float4 v = *(const float4*)(Wattn + (size_t)(by * 32 + jj) * 1024 + 512 + bx * 32 + kq);
        t_s[jj][kq + 0] = v.x; t_s[jj][kq + 1] = v.y;
        t_s[jj][kq + 2] = v.z; t_s[jj][kq + 3] = v.w;
    }
    __syncthreads();
    {
        const int kk = tid >> 3, jq = (tid & 7) * 4;
        float4 w;
        w.x = t_s[jq + 0][kk]; w.y = t_s[jq + 1][kk];
        w.z = t_s[jq + 2][kk]; w.w = t_s[jq + 3][kk];
        *(float4*)(WaRT + (size_t)(bx * 32 + kk) * 512 + by * 32 + jq) = w;
    }
}

// ---------------------------------------------------------------------------
// k_wconv: Wread fp32 -> bf16 hi/lo, chunk-major with BAKED bank swizzle.
// ---------------------------------------------------------------------------
__global__ __launch_bounds__(256) void k_wconv(const float* __restrict__ Wread,
                                               unsigned short* __restrict__ whk,
                                               unsigned short* __restrict__ wlk) {
    const size_t q = (size_t)blockIdx.x * 256 + threadIdx.x;
    const size_t k8 = q * 8;
    const int n = (int)(k8 >> 9);
    const int k = (int)(k8 & 511);
    if (n >= VP_) return;
    uint4 h4, l4;
    if (n < V_) {
        float4 p0 = *(const float4*)(Wread + (size_t)n * 512 + k);
        float4 p1 = *(const float4*)(Wread + (size_t)n * 512 + k + 4);
        float v[8] = {p0.x, p0.y, p0.z, p0.w, p1.x, p1.y, p1.z, p1.w};
        unsigned int hb[8], lb[8];
        #pragma unroll
        for (int e = 0; e < 8; e++) {
            hb[e] = f2bf(v[e]);
            lb[e] = f2bf(v[e] - bf2f((unsigned short)hb[e]));
        }
        h4 = make_uint4(hb[0] | (hb[1] << 16), hb[2] | (hb[3] << 16),
                        hb[4] | (hb[5] << 16), hb[6] | (hb[7] << 16));
        l4 = make_uint4(lb[0] | (lb[1] << 16), lb[2] | (lb[3] << 16),
                        lb[4] | (lb[5] << 16), lb[6] | (lb[7] << 16));
    } else {
        h4 = make_uint4(0, 0, 0, 0);
        l4 = make_uint4(0, 0, 0, 0);
    }
    const int lk = (k >> 3) & 3;
    const size_t dst = (size_t)(k >> 5) * ((size_t)VP_ * 32) + (size_t)n * 32
                     + (size_t)((lk ^ ((n >> 1) & 3)) * 8);
    *(uint4*)(whk + dst) = h4;
    *(uint4*)(wlk + dst) = l4;
}

// ---------------------------------------------------------------------------
// Persistent scan (round-11 proven version, verbatim: 3 syncs/step).
// ---------------------------------------------------------------------------
__global__ __launch_bounds__(512) void k_scan(const float* __restrict__ G0T,
                                              const float* __restrict__ U,
                                              const float* __restrict__ WaRT,
                                              const float* __restrict__ Wih,
                                              const float* __restrict__ Whh,
                                              const float* __restrict__ src,
                                              const int* __restrict__ lens,
                                              const float* __restrict__ last_cell,
                                              float* __restrict__ xT,
                                              float* __restrict__ h_b,
                                              float* __restrict__ scb,
                                              float* __restrict__ h_hist,
                                              float* __restrict__ att_hist,
                                              int* __restrict__ bar) {
    __shared__ float Wl[8 * 1024];
    __shared__ float Ul[200 * 64];
    __shared__ float red_s[2048];
    __shared__ float gate_s[256];
    __shared__ float h_s[512];
    __shared__ float al[256];
    __shared__ float pr[512];

    const int blk = blockIdx.x, tid = threadIdx.x;
    const int u0 = blk * 2;
    const int bb = blk & 31, p = blk >> 5;

    for (int f = tid; f < 2048; f += 512) {
        const int r = f >> 8, k = (f & 255) * 4;
        const int j = (r >> 1) * 512 + u0 + (r & 1);
        float4 v;
        if (k < 512) v = *(const float4*)(Wih + (size_t)j * 1024 + 512 + k);
        else         v = *(const float4*)(Whh + (size_t)j * 512 + (k - 512));
        *(float4*)&Wl[r * 1024 + k] = v;
    }
    for (int f = tid; f < 3200; f += 512) {
        const int s = f >> 4, q = (f & 15) * 4;
        *(float4*)&Ul[s * 64 + q] = *(const float4*)(U + ((size_t)bb * S_ + s) * 512 + p * 64 + q);
    }
    float creg = (tid < 64) ? last_cell[(tid & 31) * 512 + u0 + (tid >> 5)] : 0.f;
    __syncthreads();

    const int w = tid >> 6, lane = tid & 63;
    const int hf = lane >> 5, b = lane & 31;
    const int len = lens[bb];

    for (int t = 0; t < T_; t++) {
        // -------- Phase A: gates + pointwise ------------------------------
        {
            const int hoff = ((t + 1) & 1) * 512;        // slot holding h(t-1)
            const int kbase = w * 128 + hf * 64;
            const float* xp = (kbase < 512)
                ? (xT + (size_t)kbase * 32 + b)
                : (xT + (size_t)(512 + hoff + (kbase - 512)) * 32 + b);
            float acc[8] = {};
            #pragma unroll
            for (int kk = 0; kk < 64; kk += 8) {
                float xv[8];
                #pragma unroll
                for (int i = 0; i < 8; i++)
                    xv[i] = g_load(xp + (size_t)(kk + i) * 32);
                #pragma unroll
                for (int r = 0; r < 8; r++) {
                    const float* wr = &Wl[r * 1024 + kbase + kk];
                    float s0 = xv[0] * wr[0] + xv[1] * wr[1] + xv[2] * wr[2] + xv[3] * wr[3];
                    float s1 = xv[4] * wr[4] + xv[5] * wr[5] + xv[6] * wr[6] + xv[7] * wr[7];
                    acc[r] += s0 + s1;
                }
            }
            #pragma unroll
            for (int r = 0; r < 8; r++) acc[r] += __shfl_xor(acc[r], 32);
            if (hf == 0) {
                #pragma unroll
                for (int r = 0; r < 8; r++) red_s[w * 256 + r * 32 + b] = acc[r];
            }
            __syncthreads();
            if (tid < 256) {
                const int r = tid >> 5, b2 = tid & 31;
                const int j = (r >> 1) * 512 + u0 + (r & 1);
                float g = G0T[(size_t)j * 1024 + t * 32 + b2];
                #pragma unroll
                for (int ww = 0; ww < 8; ww++) g += red_s[ww * 256 + r * 32 + b2];
                gate_s[r * 32 + b2] = g;
            }
            __syncthreads();
            if (tid < 64) {
                const int ui = tid >> 5, b2 = tid & 31, u = u0 + ui;
                const float gi = gate_s[(0 + ui) * 32 + b2];
                const float gf = gate_s[(2 + ui) * 32 + b2];
                const float gg = gate_s[(4 + ui) * 32 + b2];
                const float go = gate_s[(6 + ui) * 32 + b2];
                const float cn = sigf(gf) * creg + sigf(gi) * tanhf(gg);
                const float hn = sigf(go) * tanhf(cn);
                creg = cn;
                g_store(&xT[(size_t)(512 + (t & 1) * 512 + u) * 32 + b2], hn);
                g_store(&h_b[b2 * 512 + u], hn);
                h_hist[((size_t)t * B_ + b2) * 512 + u] = hn;
            }
        }
        full_sync(bar, 2 * t);

        // -------- Phase B: scores -----------------------------------------
        {
            h_s[tid] = g_load(&h_b[bb * 512 + tid]);
            __syncthreads();
            for (int i = w; i < 25; i += 8) {
                const int s = p * 25 + i;
                const float* sr = src + ((size_t)bb * S_ + s) * 512;
                const float4 x0 = *(const float4*)(sr + lane * 4);
                const float4 x1 = *(const float4*)(sr + 256 + lane * 4);
                const float4 h0 = *(const float4*)(&h_s[lane * 4]);
                const float4 h1 = *(const float4*)(&h_s[256 + lane * 4]);
                float a = x0.x * h0.x + x0.y * h0.y + x0.z * h0.z + x0.w * h0.w
                        + x1.x * h1.x + x1.y * h1.y + x1.z * h1.z + x1.w * h1.w;
                #pragma unroll
                for (int mk = 1; mk < 64; mk <<= 1) a += __shfl_xor(a, mk);
                if (lane == 0) g_store(&scb[bb * 256 + s], (s < len) ? a : -INFINITY);
            }
        }
        sub_sync(bar, bb, t);

        // -------- Phase C: softmax + att slice ----------------------------
        {
            if (tid < 64) {
                const float v0 = g_load(&scb[bb * 256 + tid]);
                const float v1 = g_load(&scb[bb * 256 + 64 + tid]);
                const float v2 = g_load(&scb[bb * 256 + 128 + tid]);
                const float v3 = (tid < 8) ? g_load(&scb[bb * 256 + 192 + tid]) : -INFINITY;
                float m = fmaxf(fmaxf(v0, v1), fmaxf(v2, v3));
                #pragma unroll
                for (int mk = 1; mk < 64; mk <<= 1) m = fmaxf(m, __shfl_xor(m, mk));
                const float e0 = expf(v0 - m), e1 = expf(v1 - m), e2 = expf(v2 - m);
                const float e3 = (tid < 8) ? expf(v3 - m) : 0.f;
                float sum = (e0 + e1) + (e2 + e3);
                #pragma unroll
                for (int mk = 1; mk < 64; mk <<= 1) sum += __shfl_xor(sum, mk);
                const float inv = 1.f / sum;
                al[tid] = e0 * inv; al[64 + tid] = e1 * inv; al[128 + tid] = e2 * inv;
                if (tid < 8) al[192 + tid] = e3 * inv;
            }
            __syncthreads();
            const int jl = tid & 63, sg = tid >> 6;
            float uacc = 0.f;
            #pragma unroll 5
            for (int s = sg * 25; s < sg * 25 + 25; s++)
                uacc += al[s] * Ul[s * 64 + jl];
            const float* wc0 = WaRT + (size_t)(sg * 64) * 512 + p * 64 + jl;
            const float* hp = &h_s[sg * 64];
            float c0 = 0.f, c1 = 0.f;
            #pragma unroll 8
            for (int kk = 0; kk < 64; kk += 2) {
                c0 += hp[kk] * wc0[(size_t)kk * 512];
                c1 += hp[kk + 1] * wc0[(size_t)(kk + 1) * 512];
            }
            pr[tid] = uacc + c0 + c1;
            __syncthreads();
            if (tid < 64) {
                float tot = 0.f;
                #pragma unroll
                for (int sgg = 0; sgg < 8; sgg++) tot += pr[sgg * 64 + tid];
                const float a = tanhf(tot);
                g_store(&xT[(size_t)(p * 64 + tid) * 32 + bb], a);
                att_hist[((size_t)t * B_ + bb) * 512 + p * 64 + tid] = a;
            }
        }
        full_sync(bar, 2 * t + 1);
    }
}

// ---------------------------------------------------------------------------
// k_dec: bf16-split decode output; row-major dh/dl + chunk-major dhk/dlk.
// ---------------------------------------------------------------------------
__global__ __launch_bounds__(256) void k_dec(const int* __restrict__ tgt_in,
                                             const float* __restrict__ emb,
                                             const float* __restrict__ h_hist,
                                             const float* __restrict__ att_hist,
                                             const float* __restrict__ Wgen,
                                             const float* __restrict__ bgen,
                                             unsigned short* __restrict__ dh,
                                             unsigned short* __restrict__ dl,
                                             unsigned short* __restrict__ dhk,
                                             unsigned short* __restrict__ dlk,
                                             int pre) {
    __shared__ float a_s[32][66];
    __shared__ float w_s[32][130];
    const int tid = threadIdx.x;
    const int m0 = blockIdx.x * 64, n0 = blockIdx.y * 128;
    const int mq = tid >> 5, nq = tid & 31;
    float acc[8][4] = {};
    for (int k0 = 0; k0 < 1536; k0 += 32) {
        {
            const int mm = tid >> 2, kq = tid & 3, kk = kq * 8;
            const int m = m0 + mm;
            const float* row;
            if (k0 < 512)       row = emb + (size_t)tgt_in[m] * E_ + k0;
            else if (k0 < 1024) row = h_hist + (size_t)m * 512 + (k0 - 512);
            else                row = att_hist + (size_t)m * 512 + (k0 - 1024);
            row += kk;
            float4 v0 = *(const float4*)(row);
            float4 v1 = *(const float4*)(row + 4);
            a_s[kk + 0][mm] = v0.x; a_s[kk + 1][mm] = v0.y;
            a_s[kk + 2][mm] = v0.z; a_s[kk + 3][mm] = v0.w;
            a_s[kk + 4][mm] = v1.x; a_s[kk + 5][mm] = v1.y;
            a_s[kk + 6][mm] = v1.z; a_s[kk + 7][mm] = v1.w;
        }
        {
            const int nn = tid >> 1, kq = tid & 1, kk = kq * 16;
            const float* row = Wgen + (size_t)(n0 + nn) * 1536 + k0 + kk;
            #pragma unroll
            for (int u = 0; u < 4; u++) {
                float4 v = *(const float4*)(row + u * 4);
                w_s[kk + u * 4 + 0][nn] = v.x; w_s[kk + u * 4 + 1][nn] = v.y;
                w_s[kk + u * 4 + 2][nn] = v.z; w_s[kk + u * 4 + 3][nn] = v.w;
            }
        }
        __syncthreads();
        for (int k = 0; k < 32; k++) {
            float a[8], wv[4];
            #pragma unroll
            for (int i = 0; i < 8; i++) a[i] = a_s[k][mq + 8 * i];
            #pragma unroll
            for (int pq = 0; pq < 4; pq++) wv[pq] = w_s[k][nq + 32 * pq];
            #pragma unroll
            for (int i = 0; i < 8; i++)
                #pragma unroll
                for (int pq = 0; pq < 4; pq++) acc[i][pq] += a[i] * wv[pq];
        }
        __syncthreads();
    }
    #pragma unroll
    for (int i = 0; i < 8; i++) {
        const int m = m0 + mq + 8 * i;
        #pragma unroll
        for (int pq = 0; pq < 4; pq++) {
            const int n = n0 + nq + 32 * pq;
            const float v = tanhf(acc[i][pq] + bgen[n]);
            const unsigned short hb = f2bf(v);
            const unsigned short lb = f2bf(v - bf2f(hb));
            dh[(size_t)m * 512 + n] = hb;
            dl[(size_t)m * 512 + n] = lb;
            if (pre) {
                const size_t ca = (size_t)(n >> 5) * 32768 + (size_t)(m >> 6) * 2048
                                + (size_t)(m & 63) * 32 + (n & 31);
                dhk[ca] = hb;
                dlk[ca] = lb;
            }
        }
    }
}

// ===========================================================================
// k_read_pre (round-11 proven): B staged via global_load_lds from pre-swizzled
// chunk-major whk/wlk; A-frags per-lane direct from chunk-major dhk/dlk.
// 64-row tiles, grid 3200 XCD-grouped, LDS 32KB.
// ===========================================================================
__global__ __launch_bounds__(256) void k_read_pre(const unsigned short* __restrict__ dhk,
                                                  const unsigned short* __restrict__ dlk,
                                                  const unsigned short* __restrict__ whk,
                                                  const unsigned short* __restrict__ wlk,
                                                  const int* __restrict__ tgt_out,
                                                  float4* __restrict__ part,
                                                  float* __restrict__ tgt_logit) {
    __shared__ __align__(16) unsigned short BhL[8192];   // 16 KB
    __shared__ __align__(16) unsigned short BlL[8192];   // 16 KB
    __shared__ float ep_max[64][2];
    __shared__ int   ep_idx[64][2];
    __shared__ float ep_fin[64];
    __shared__ int   ep_fidx[64];
    __shared__ float ep_sum[64][2];

    const int xcd = blockIdx.x & 7;
    const int idx = blockIdx.x >> 3;
    const int mi  = idx & 15;
    const int group = idx >> 4;
    const int ch = group * 8 + xcd;
    if (ch >= NCH) return;
    const int m0 = mi * 64, n0 = ch * 256;

    const int tid = threadIdx.x;
    const int lane = tid & 63, wid = tid >> 6;
    const int wr = wid >> 1, wc = wid & 1;
    const int l15 = lane & 15, lk = lane >> 4;

    f32x4 acc[2][8];
    #pragma unroll
    for (int mt = 0; mt < 2; mt++)
        #pragma unroll
        for (int nt = 0; nt < 8; nt++) acc[mt][nt] = {0.f, 0.f, 0.f, 0.f};

    const unsigned short* bh_src = whk + (size_t)n0 * 32;
    const unsigned short* bl_src = wlk + (size_t)n0 * 32;
    const unsigned short* ah_base = dhk + (size_t)(m0 >> 6) * 2048 + lk * 8;
    const unsigned short* al_base = dlk + (size_t)(m0 >> 6) * 2048 + lk * 8;

    for (int kc = 0; kc < 16; kc++) {
        {   // async B stage: 2 x 16 KB linear copies (pre-swizzled source)
            const size_t cb = (size_t)kc * ((size_t)VP_ * 32);
            const char* gh = (const char*)(bh_src + cb);
            const char* gl = (const char*)(bl_src + cb);
            #pragma unroll
            for (int c = 0; c < 4; c++) {
                const int ob = wid * 4096 + c * 1024;    // wave-uniform
                async16((char*)BhL + ob, gh + ob + lane * 16);
                async16((char*)BlL + ob, gl + ob + lane * 16);
            }
        }
        bf16x8 afh[2], afl[2];
        {   // A fragments: per-lane direct global (chunk-major)
            const unsigned short* ah = ah_base + (size_t)kc * 32768;
            const unsigned short* al = al_base + (size_t)kc * 32768;
            #pragma unroll
            for (int mt = 0; mt < 2; mt++) {
                const int r = wr * 32 + mt * 16 + l15;
                afh[mt] = *(const bf16x8*)(ah + r * 32);
                afl[mt] = *(const bf16x8*)(al + r * 32);
            }
        }
        __syncthreads();     // drains vmcnt -> B in LDS, A in regs
        #pragma unroll
        for (int nt = 0; nt < 8; nt++) {
            const int nn = wc * 128 + nt * 16 + l15;
            const int bo = nn * 32 + ((lk ^ ((nn >> 1) & 3)) * 8);
            bf16x8 bh = *(const bf16x8*)&BhL[bo];
            bf16x8 bl = *(const bf16x8*)&BlL[bo];
            #pragma unroll
            for (int mt = 0; mt < 2; mt++) {
                acc[mt][nt] = __builtin_amdgcn_mfma_f32_16x16x32_bf16(afh[mt], bh, acc[mt][nt], 0, 0, 0);
                acc[mt][nt] = __builtin_amdgcn_mfma_f32_16x16x32_bf16(afl[mt], bh, acc[mt][nt], 0, 0, 0);
                acc[mt][nt] = __builtin_amdgcn_mfma_f32_16x16x32_bf16(afh[mt], bl, acc[mt][nt], 0, 0, 0);
            }
        }
        __syncthreads();
    }

    #pragma unroll
    for (int mt = 0; mt < 2; mt++)
        #pragma unroll
        for (int reg = 0; reg < 4; reg++) {
            float bv = -INFINITY; int bi = 0x7fffffff;
            #pragma unroll
            for (int nt = 0; nt < 8; nt++) {
                const int n = n0 + wc * 128 + nt * 16 + l15;
                const float v = (n < V_) ? acc[mt][nt][reg] : -INFINITY;
                if (v > bv || (v == bv && n < bi)) { bv = v; bi = n; }
            }
            #pragma unroll
            for (int mk = 1; mk < 16; mk <<= 1) {
                const float ov = __shfl_xor(bv, mk);
                const int oi = __shfl_xor(bi, mk);
                if (ov > bv || (ov == bv && oi < bi)) { bv = ov; bi = oi; }
            }
            if (l15 == 0) {
                const int rl = wr * 32 + mt * 16 + lk * 4 + reg;
                ep_max[rl][wc] = bv; ep_idx[rl][wc] = bi;
            }
        }
    __syncthreads();
    if (tid < 64) {
        const float a = ep_max[tid][0], b = ep_max[tid][1];
        const int ia = ep_idx[tid][0], ib = ep_idx[tid][1];
        const bool tb = (b > a) || (b == a && ib < ia);
        ep_fin[tid] = tb ? b : a; ep_fidx[tid] = tb ? ib : ia;
    }
    __syncthreads();
    #pragma unroll
    for (int mt = 0; mt < 2; mt++)
        #pragma unroll
        for (int reg = 0; reg < 4; reg++) {
            const int rl = wr * 32 + mt * 16 + lk * 4 + reg;
            const float M = ep_fin[rl];
            const int rel = tgt_out[m0 + rl] - n0;
            float se = 0.f;
            #pragma unroll
            for (int nt = 0; nt < 8; nt++) {
                const int nl = wc * 128 + nt * 16 + l15;
                if (n0 + nl < V_) {
                    const float v = acc[mt][nt][reg];
                    se += expf(v - M);
                    if (nl == rel) tgt_logit[m0 + rl] = v;
                }
            }
            #pragma unroll
            for (int mk = 1; mk < 16; mk <<= 1) se += __shfl_xor(se, mk);
            if (l15 == 0) ep_sum[rl][wc] = se;
        }
    __syncthreads();
    if (tid < 64) {
        part[(size_t)(m0 + tid) * NCH + ch] =
            make_float4(ep_fin[tid], ep_sum[tid][0] + ep_sum[tid][1],
                        __int_as_float(ep_fidx[tid]), 0.f);
    }
}

// ---------------------------------------------------------------------------
// k_read (fallback: in-kernel conversion, row-major dh/dl, grid 3200)
// ---------------------------------------------------------------------------
__global__ __launch_bounds__(256) void k_read(const unsigned short* __restrict__ dh,
                                              const unsigned short* __restrict__ dl,
                                              const float* __restrict__ Wread,
                                              const int* __restrict__ tgt_out,
                                              float4* __restrict__ part,
                                              float* __restrict__ tgt_logit) {
    __shared__ __align__(16) unsigned short Bh[4][256][8];
    __shared__ __align__(16) unsigned short Bl[4][256][8];
    __shared__ __align__(16) unsigned short Ah[4][64][8];
    __shared__ __align__(16) unsigned short Alo[4][64][8];
    __shared__ float ep_max[64][2];
    __shared__ int   ep_idx[64][2];
    __shared__ float ep_fin[64];
    __shared__ int   ep_fidx[64];
    __shared__ float ep_sum[64][2];

    const int xcd = blockIdx.x & 7;
    const int idx = blockIdx.x >> 3;
    const int mi  = idx & 15;
    const int group = idx >> 4;
    const int ch = group * 8 + xcd;
    if (ch >= NCH) return;
    const int m0 = mi * 64, n0 = ch * 256;

    const int tid = threadIdx.x;
    const int lane = tid & 63, wid = tid >> 6;
    const int wr = wid >> 1, wc = wid & 1;
    const int l15 = lane & 15, lk = lane >> 4;

    f32x4 acc[2][8];
    #pragma unroll
    for (int mt = 0; mt < 2; mt++)
        #pragma unroll
        for (int nt = 0; nt < 8; nt++) acc[mt][nt] = {0.f, 0.f, 0.f, 0.f};

    for (int kc = 0; kc < 512; kc += 32) {
        {
            const int n = n0 + tid;
            const float* row = Wread + (size_t)n * 512 + kc;
            #pragma unroll
            for (int g = 0; g < 4; g++) {
                uint4 h4, l4;
                if (n < V_) {
                    float4 p0 = *(const float4*)(row + g * 8);
                    float4 p1 = *(const float4*)(row + g * 8 + 4);
                    float v[8] = {p0.x, p0.y, p0.z, p0.w, p1.x, p1.y, p1.z, p1.w};
                    unsigned int hb[8], lb[8];
                    #pragma unroll
                    for (int e = 0; e < 8; e++) {
                        hb[e] = f2bf(v[e]);
                        lb[e] = f2bf(v[e] - bf2f((unsigned short)hb[e]));
                    }
                    h4 = make_uint4(hb[0] | (hb[1] << 16), hb[2] | (hb[3] << 16),
                                    hb[4] | (hb[5] << 16), hb[6] | (hb[7] << 16));
                    l4 = make_uint4(lb[0] | (lb[1] << 16), lb[2] | (lb[3] << 16),
                                    lb[4] | (lb[5] << 16), lb[6] | (lb[7] << 16));
                } else {
                    h4 = make_uint4(0, 0, 0, 0);
                    l4 = make_uint4(0, 0, 0, 0);
                }
                *(uint4*)&Bh[g][tid][0] = h4;
                *(uint4*)&Bl[g][tid][0] = l4;
            }
        }
        {
            const int row = tid >> 2, g = tid & 3;
            *(uint4*)&Ah[g][row][0]  = *(const uint4*)(dh + (size_t)(m0 + row) * 512 + kc + g * 8);
            *(uint4*)&Alo[g][row][0] = *(const uint4*)(dl + (size_t)(m0 + row) * 512 + kc + g * 8);
        }
        __syncthreads();
        {
            bf16x8 afh[2], afl[2];
            #pragma unroll
            for (int mt = 0; mt < 2; mt++) {
                const int r = wr * 32 + mt * 16 + l15;
                afh[mt] = *(const bf16x8*)&Ah[lk][r][0];
                afl[mt] = *(const bf16x8*)&Alo[lk][r][0];
            }
            #pragma unroll
            for (int nt = 0; nt < 8; nt++) {
                const int nn = wc * 128 + nt * 16 + l15;
                bf16x8 bh = *(const bf16x8*)&Bh[lk][nn][0];
                bf16x8 bl = *(const bf16x8*)&Bl[lk][nn][0];
                #pragma unroll
                for (int mt = 0; mt < 2; mt++) {
                    acc[mt][nt] = __builtin_amdgcn_mfma_f32_16x16x32_bf16(afh[mt], bh, acc[mt][nt], 0, 0, 0);
                    acc[mt][nt] = __builtin_amdgcn_mfma_f32_16x16x32_bf16(afl[mt], bh, acc[mt][nt], 0, 0, 0);
                    acc[mt][nt] = __builtin_amdgcn_mfma_f32_16x16x32_bf16(afh[mt], bl, acc[mt][nt], 0, 0, 0);
                }
            }
        }
        __syncthreads();
    }

    #pragma unroll
    for (int mt = 0; mt < 2; mt++)
        #pragma unroll
        for (int reg = 0; reg < 4; reg++) {
            float bv = -INFINITY; int bi = 0x7fffffff;
            #pragma unroll
            for (int nt = 0; nt < 8; nt++) {
                const int n = n0 + wc * 128 + nt * 16 + l15;
                const float v = (n < V_) ? acc[mt][nt][reg] : -INFINITY;
                if (v > bv || (v == bv && n < bi)) { bv = v; bi = n; }
            }
            #pragma unroll
            for (int mk = 1; mk < 16; mk <<= 1) {
                const float ov = __shfl_xor(bv, mk);
                const int oi = __shfl_xor(bi, mk);
                if (ov > bv || (ov == bv && oi < bi)) { bv = ov; bi = oi; }
            }
            if (l15 == 0) {
                const int rl = wr * 32 + mt * 16 + lk * 4 + reg;
                ep_max[rl][wc] = bv; ep_idx[rl][wc] = bi;
            }
        }
    __syncthreads();
    if (tid < 64) {
        const float a = ep_max[tid][0], b = ep_max[tid][1];
        const int ia = ep_idx[tid][0], ib = ep_idx[tid][1];
        const bool tb = (b > a) || (b == a && ib < ia);
        ep_fin[tid] = tb ? b : a; ep_fidx[tid] = tb ? ib : ia;
    }
    __syncthreads();
    #pragma unroll
    for (int mt = 0; mt < 2; mt++)
        #pragma unroll
        for (int reg = 0; reg < 4; reg++) {
            const int rl = wr * 32 + mt * 16 + lk * 4 + reg;
            const float M = ep_fin[rl];
            const int rel = tgt_out[m0 + rl] - n0;
            float se = 0.f;
            #pragma unroll
            for (int nt = 0; nt < 8; nt++) {
                const int nl = wc * 128 + nt * 16 + l15;
                if (n0 + nl < V_) {
                    const float v = acc[mt][nt][reg];
                    se += expf(v - M);
                    if (nl == rel) tgt_logit[m0 + rl] = v;
                }
            }
            #pragma unroll
            for (int mk = 1; mk < 16; mk <<= 1) se += __shfl_xor(se, mk);
            if (l15 == 0) ep_sum[rl][wc] = se;
        }
    __syncthreads();
    if (tid < 64) {
        part[(size_t)(m0 + tid) * NCH + ch] =
            make_float4(ep_fin[tid], ep_sum[tid][0] + ep_sum[tid][1],
                        __int_as_float(ep_fidx[tid]), 0.f);
    }
}

// ---------------------------------------------------------------------------
// k_merge: combine chunk partials -> loss + argmax
// ---------------------------------------------------------------------------
__global__ __launch_bounds__(256) void k_merge(const float4* __restrict__ part,
                                               const float* __restrict__ tgt_logit,
                                               const int* __restrict__ tgt_out,
                                               float* __restrict__ out) {
    const int tid = threadIdx.x;
    const int w = tid >> 6, lane = tid & 63;
    const int row = blockIdx.x * 4 + w;
    float bm = -INFINITY; int bi = 0x7fffffff;
    for (int ch = lane; ch < NCH; ch += 64) {
        const float4 p = part[(size_t)row * NCH + ch];
        const int pi = __float_as_int(p.z);
        if (p.x > bm || (p.x == bm && pi < bi)) { bm = p.x; bi = pi; }
    }
    #pragma unroll
    for (int mk = 1; mk < 64; mk <<= 1) {
        const float ov = __shfl_xor(bm, mk);
        const int oi = __shfl_xor(bi, mk);
        if (ov > bm || (ov == bm && oi < bi)) { bm = ov; bi = oi; }
    }
    float sum = 0.f;
    for (int ch = lane; ch < NCH; ch += 64) {
        const float4 p = part[(size_t)row * NCH + ch];
        sum += p.y * expf(p.x - bm);
    }
    #pragma unroll
    for (int mk = 1; mk < 64; mk <<= 1) sum += __shfl_xor(sum, mk);
    if (lane == 0) {
        const float lse = bm + logf(sum);
        const int tg = tgt_out[row];
        const float loss = (tg != 0) ? (lse - tgt_logit[row]) : 0.f;
        out[row] = loss;
        out[1024 + row] = (float)bi;
    }
}

// ---------------------------------------------------------------------------
extern "C" void kernel_launch(void* const* d_in, const int* in_sizes, int n_in,
                              void* d_out, int out_size, void* d_ws, size_t ws_size,
                              hipStream_t stream) {
    const int* tgt_in = (const int*)d_in[0];
    const int* tgt_out = (const int*)d_in[1];
    const int* src_lens = (const int*)d_in[2];
    const float* src = (const float*)d_in[3];
    const float* last_state = (const float*)d_in[4];
    const float* last_cell = (const float*)d_in[5];
    const float* emb = (const float*)d_in[6];
    const float* Wih = (const float*)d_in[7];
    const float* Whh = (const float*)d_in[8];
    const float* bih = (const float*)d_in[9];
    const float* bhh = (const float*)d_in[10];
    const float* Wattn = (const float*)d_in[11];
    const float* Wgen = (const float*)d_in[12];
    const float* bgen = (const float*)d_in[13];
    const float* Wread = (const float*)d_in[14];
    float* out = (float*)d_out;

    float* ws = (float*)d_ws;
    float* G0T      = ws;                    // 2,097,152 f
    float* U        = G0T + 2097152;         // 3,276,800 f
    float* WaRT     = U + 3276800;           // 262,144 f
    unsigned short* dh  = (unsigned short*)(WaRT + 262144);  // 524,288 u16
    unsigned short* dl  = dh + 524288;
    unsigned short* dhk = dl + 524288;       // chunk-major
    unsigned short* dlk = dhk + 524288;
    float* h_hist   = (float*)(dlk + 524288);
    float* att_hist = h_hist + 524288;
    float* xT       = att_hist + 524288;     // 49,152 f
    float* h_b      = xT + 49152;            // 16,384 f
    float* scb      = h_b + 16384;           // 8,192 f
    float4* part    = (float4*)(scb + 8192); // 200,704 float4
    float* tgtl     = ((float*)part) + 802816; // 1,024 f
    int* bar        = (int*)(tgtl + 1024);     // 2,048 ints
    unsigned short* whk = (unsigned short*)(bar + 2048);   // VP_*512 u16
    unsigned short* wlk = whk + (size_t)VP_ * 512;
    // prologue bf16 operands
    unsigned short* sh    = wlk + (size_t)VP_ * 512;  // 3,276,800 u16
    unsigned short* sl    = sh + 3276800;
    unsigned short* wah   = sl + 3276800;             // 262,144
    unsigned short* wal   = wah + 262144;
    unsigned short* wih_h = wal + 262144;             // 1,048,576
    unsigned short* wih_l = wih_h + 1048576;
    unsigned short* eh    = wih_l + 1048576;          // 524,288
    unsigned short* el    = eh + 524288;

    const size_t need = (size_t)((char*)(el + 524288) - (char*)ws);
    const int pre = (ws_size >= need) ? 1 : 0;

    hipMemsetAsync(bar, 0, 8192, stream);

    k_init<<<64, 256, 0, stream>>>(last_state, xT);
    if (pre) {
        k_cvt<<<(CVT_R3 + 255) / 256, 256, 0, stream>>>(src, Wattn, Wih, emb, tgt_in,
                                                        sh, sl, wah, wal, wih_h, wih_l, eh, el);
        k_gbt<<<200, 256, 0, stream>>>(sh, sl, wah, wal, nullptr, nullptr, U, 2, 0);
        k_gbt<<<128, 256, 0, stream>>>(eh, el, wih_h, wih_l, bih, bhh, G0T, 8, 1);
    } else {
        k_g0<<<dim3(16, 16), 256, 0, stream>>>(tgt_in, emb, Wih, bih, bhh, G0T);
        k_u<<<dim3(100, 4), 256, 0, stream>>>(src, Wattn, U);
    }
    k_tr<<<dim3(16, 16), 256, 0, stream>>>(Wattn, WaRT);
    if (pre)
        k_wconv<<<12544, 256, 0, stream>>>(Wread, whk, wlk);

    k_scan<<<256, 512, 0, stream>>>(G0T, U, WaRT, Wih, Whh, src, src_lens, last_cell,
                                    xT, h_b, scb, h_hist, att_hist, bar);

    k_dec<<<dim3(16, 4), 256, 0, stream>>>(tgt_in, emb, h_hist, att_hist, Wgen, bgen,
                                           dh, dl, dhk, dlk, pre);
    if (pre)
        k_read_pre<<<3200, 256, 0, stream>>>(dhk, dlk, whk, wlk, tgt_out, part, tgtl);
    else
        k_read<<<3200, 256, 0, stream>>>(dh, dl, Wread, tgt_out, part, tgtl);
    k_merge<<<256, 256, 0, stream>>>(part, tgtl, tgt_out, out);
}

// Round 15
// 942.841 us; speedup vs baseline: 1.3345x; 1.0838x over previous
//
#include <hip/hip_runtime.h>
#include <math.h>

#define T_ 32
#define B_ 32
#define S_ 200
#define E_ 512
#define H_ 512
#define V_ 50000
#define VP_ 50176   // padded rows for chunk-major bf16 W
#define G4_ 2048
#define NCH 196     // ceil(50000/256)

using bf16x8 = __attribute__((ext_vector_type(8))) __bf16;
using f32x4  = __attribute__((ext_vector_type(4))) float;

__device__ __forceinline__ float sigf(float x) { return 1.f / (1.f + expf(-x)); }

__device__ __forceinline__ unsigned short f2bf(float v) {
    unsigned int x = __float_as_uint(v);
    return (unsigned short)((x + 0x7FFFu + ((x >> 16) & 1u)) >> 16);
}
__device__ __forceinline__ float bf2f(unsigned short b) {
    return __uint_as_float(((unsigned int)b) << 16);
}

// async global->LDS 16B copy
__device__ __forceinline__ void async16(void* lds, const void* g) {
    __builtin_amdgcn_global_load_lds(
        (const __attribute__((address_space(1))) unsigned int*)g,
        (__attribute__((address_space(3))) unsigned int*)lds, 16, 0, 0);
}

// Coherent LLC-level exchange (relaxed agent atomics -> sc1 load/store)
__device__ __forceinline__ void g_store(float* p, float v) {
    __hip_atomic_store(p, v, __ATOMIC_RELAXED, __HIP_MEMORY_SCOPE_AGENT);
}
__device__ __forceinline__ float g_load(const float* p) {
    return __hip_atomic_load(p, __ATOMIC_RELAXED, __HIP_MEMORY_SCOPE_AGENT);
}

// ---------------------------------------------------------------------------
// Fence-free grid barrier (proven rounds 5-14).
// ---------------------------------------------------------------------------
__device__ __forceinline__ void full_sync(int* bar, int ep) {
    __syncthreads();
    if (threadIdx.x == 0) {
        const int g = blockIdx.x & 7;
        int a = __hip_atomic_fetch_add(&bar[g * 32], 1, __ATOMIC_RELAXED, __HIP_MEMORY_SCOPE_AGENT);
        if (a == ep * 32 + 31) {
            int q = __hip_atomic_fetch_add(&bar[256], 1, __ATOMIC_RELAXED, __HIP_MEMORY_SCOPE_AGENT);
            if (q == ep * 8 + 7) {
                #pragma unroll
                for (int i = 0; i < 8; i++)
                    __hip_atomic_store(&bar[288 + i * 32], ep + 1, __ATOMIC_RELAXED, __HIP_MEMORY_SCOPE_AGENT);
            }
        }
        while (__hip_atomic_load(&bar[288 + g * 32], __ATOMIC_RELAXED, __HIP_MEMORY_SCOPE_AGENT) < ep + 1)
            __builtin_amdgcn_s_sleep(1);
    }
    __syncthreads();
}

__device__ __forceinline__ void sub_sync(int* bar, int bb, int t) {
    __syncthreads();
    if (threadIdx.x == 0) {
        __hip_atomic_fetch_add(&bar[544 + bb * 32], 1, __ATOMIC_RELAXED, __HIP_MEMORY_SCOPE_AGENT);
        while (__hip_atomic_load(&bar[544 + bb * 32], __ATOMIC_RELAXED, __HIP_MEMORY_SCOPE_AGENT) < (t + 1) * 8)
            __builtin_amdgcn_s_sleep(1);
    }
    __syncthreads();
}

// ---------------------------------------------------------------------------
// k_init: xT rows 0..511 att=0; rows 1024..1535 = last_state^T (h slot 1).
// ---------------------------------------------------------------------------
__global__ __launch_bounds__(256) void k_init(const float* __restrict__ last_state,
                                              float* __restrict__ xT) {
    const int f = blockIdx.x * 256 + threadIdx.x;   // 0..16383
    xT[f] = 0.f;
    const int k = f >> 5, b = f & 31;
    xT[32768 + f] = last_state[b * 512 + k];
}

// ---------------------------------------------------------------------------
// k_cvt: fp32 -> bf16 hi/lo for prologue/dec GEMM operands.
//  R0 src (6400x512), R1 WattnL (512x512), R2 WihL (2048x512),
//  R3 gathered emb (1024x512), R4 Wgen (512x1536)
// ---------------------------------------------------------------------------
#define CVT_R0 819200
#define CVT_R1 (CVT_R0 + 65536)
#define CVT_R2 (CVT_R1 + 262144)
#define CVT_R3 (CVT_R2 + 131072)
#define CVT_R4 (CVT_R3 + 196608)
__global__ __launch_bounds__(256) void k_cvt(const float* __restrict__ src,
                                             const float* __restrict__ Wattn,
                                             const float* __restrict__ Wih,
                                             const float* __restrict__ emb,
                                             const float* __restrict__ Wgen,
                                             const int* __restrict__ tgt_in,
                                             unsigned short* __restrict__ sh,
                                             unsigned short* __restrict__ sl,
                                             unsigned short* __restrict__ wah,
                                             unsigned short* __restrict__ wal,
                                             unsigned short* __restrict__ wih_h,
                                             unsigned short* __restrict__ wih_l,
                                             unsigned short* __restrict__ eh,
                                             unsigned short* __restrict__ el,
                                             unsigned short* __restrict__ wgh,
                                             unsigned short* __restrict__ wgl) {
    const int u = blockIdx.x * 256 + threadIdx.x;
    if (u >= CVT_R4) return;
    const float* sp;
    unsigned short *dh_, *dl_;
    size_t doff;
    if (u < CVT_R0) {
        sp = src + (size_t)u * 4;
        dh_ = sh; dl_ = sl; doff = (size_t)u * 4;
    } else if (u < CVT_R1) {
        const int idx = u - CVT_R0;
        const int k4 = idx & 127, n = idx >> 7;
        sp = Wattn + (size_t)n * 1024 + k4 * 4;
        dh_ = wah; dl_ = wal; doff = (size_t)n * 512 + k4 * 4;
    } else if (u < CVT_R2) {
        const int idx = u - CVT_R1;
        const int k4 = idx & 127, j = idx >> 7;
        sp = Wih + (size_t)j * 1024 + k4 * 4;
        dh_ = wih_h; dl_ = wih_l; doff = (size_t)j * 512 + k4 * 4;
    } else if (u < CVT_R3) {
        const int idx = u - CVT_R2;
        const int k4 = idx & 127, m = idx >> 7;
        sp = emb + (size_t)tgt_in[m] * 512 + k4 * 4;
        dh_ = eh; dl_ = el; doff = (size_t)m * 512 + k4 * 4;
    } else {
        const int idx = u - CVT_R3;
        const int n = idx / 384, k4 = idx - n * 384;
        sp = Wgen + (size_t)n * 1536 + k4 * 4;
        dh_ = wgh; dl_ = wgl; doff = (size_t)n * 1536 + k4 * 4;
    }
    const float4 v = *(const float4*)sp;
    const float vv[4] = {v.x, v.y, v.z, v.w};
    unsigned int hb[4], lb[4];
    #pragma unroll
    for (int e = 0; e < 4; e++) {
        hb[e] = f2bf(vv[e]);
        lb[e] = f2bf(vv[e] - bf2f((unsigned short)hb[e]));
    }
    *(uint2*)(dh_ + doff) = make_uint2(hb[0] | (hb[1] << 16), hb[2] | (hb[3] << 16));
    *(uint2*)(dl_ + doff) = make_uint2(lb[0] | (lb[1] << 16), lb[2] | (lb[3] << 16));
}

// ---------------------------------------------------------------------------
// k_gbt: C = A . B^T via bf16-split MFMA. 64(M)x256(N), K=512, LDS-free.
// mode 0: out[m*512+n] (U). mode 1: out[n*1024+m] + bih[n]+bhh[n] (G0T).
// ---------------------------------------------------------------------------
__global__ __launch_bounds__(256) void k_gbt(const unsigned short* __restrict__ Ah,
                                             const unsigned short* __restrict__ Al,
                                             const unsigned short* __restrict__ Bh,
                                             const unsigned short* __restrict__ Bl,
                                             const float* __restrict__ bih,
                                             const float* __restrict__ bhh,
                                             float* __restrict__ out,
                                             int nbn, int mode) {
    const int m0 = (blockIdx.x / nbn) * 64;
    const int n0 = (blockIdx.x % nbn) * 256;
    const int tid = threadIdx.x;
    const int lane = tid & 63, wid = tid >> 6;
    const int wr = wid >> 1, wc = wid & 1;
    const int l15 = lane & 15, lk = lane >> 4;

    f32x4 acc[2][8];
    #pragma unroll
    for (int mt = 0; mt < 2; mt++)
        #pragma unroll
        for (int nt = 0; nt < 8; nt++) acc[mt][nt] = {0.f, 0.f, 0.f, 0.f};

    for (int kc = 0; kc < 512; kc += 32) {
        bf16x8 afh[2], afl[2];
        #pragma unroll
        for (int mt = 0; mt < 2; mt++) {
            const int r = wr * 32 + mt * 16 + l15;
            const size_t ao = (size_t)(m0 + r) * 512 + kc + lk * 8;
            afh[mt] = *(const bf16x8*)(Ah + ao);
            afl[mt] = *(const bf16x8*)(Al + ao);
        }
        #pragma unroll
        for (int nt = 0; nt < 8; nt++) {
            const int nn = wc * 128 + nt * 16 + l15;
            const size_t bo = (size_t)(n0 + nn) * 512 + kc + lk * 8;
            bf16x8 bh = *(const bf16x8*)(Bh + bo);
            bf16x8 bl = *(const bf16x8*)(Bl + bo);
            #pragma unroll
            for (int mt = 0; mt < 2; mt++) {
                acc[mt][nt] = __builtin_amdgcn_mfma_f32_16x16x32_bf16(afh[mt], bh, acc[mt][nt], 0, 0, 0);
                acc[mt][nt] = __builtin_amdgcn_mfma_f32_16x16x32_bf16(afl[mt], bh, acc[mt][nt], 0, 0, 0);
                acc[mt][nt] = __builtin_amdgcn_mfma_f32_16x16x32_bf16(afh[mt], bl, acc[mt][nt], 0, 0, 0);
            }
        }
    }
    #pragma unroll
    for (int mt = 0; mt < 2; mt++)
        #pragma unroll
        for (int reg = 0; reg < 4; reg++) {
            const int row = m0 + wr * 32 + mt * 16 + lk * 4 + reg;
            #pragma unroll
            for (int nt = 0; nt < 8; nt++) {
                const int col = n0 + wc * 128 + nt * 16 + l15;
                const float v = acc[mt][nt][reg];
                if (mode == 0) out[(size_t)row * 512 + col] = v;
                else           out[(size_t)col * 1024 + row] = v + bih[col] + bhh[col];
            }
        }
}

// ---------------------------------------------------------------------------
// k_gbt_dec: dec GEMM via bf16-split MFMA. M=1024, N=512, K=1536 (A regions
// emb|h|att), epilogue tanh(+bgen) -> chunk-major dhk/dlk. Grid 32 blocks.
// ---------------------------------------------------------------------------
__global__ __launch_bounds__(256) void k_gbt_dec(const unsigned short* __restrict__ eh,
                                                 const unsigned short* __restrict__ el,
                                                 const unsigned short* __restrict__ hh,
                                                 const unsigned short* __restrict__ hl,
                                                 const unsigned short* __restrict__ ath,
                                                 const unsigned short* __restrict__ atl,
                                                 const unsigned short* __restrict__ wgh,
                                                 const unsigned short* __restrict__ wgl,
                                                 const float* __restrict__ bgen,
                                                 unsigned short* __restrict__ dhk,
                                                 unsigned short* __restrict__ dlk) {
    const int m0 = (blockIdx.x >> 1) * 64;
    const int n0 = (blockIdx.x & 1) * 256;
    const int tid = threadIdx.x;
    const int lane = tid & 63, wid = tid >> 6;
    const int wr = wid >> 1, wc = wid & 1;
    const int l15 = lane & 15, lk = lane >> 4;

    f32x4 acc[2][8];
    #pragma unroll
    for (int mt = 0; mt < 2; mt++)
        #pragma unroll
        for (int nt = 0; nt < 8; nt++) acc[mt][nt] = {0.f, 0.f, 0.f, 0.f};

    for (int kc = 0; kc < 1536; kc += 32) {
        const unsigned short *Ah, *Al;
        int ko;
        if (kc < 512)       { Ah = eh;  Al = el;  ko = kc; }
        else if (kc < 1024) { Ah = hh;  Al = hl;  ko = kc - 512; }
        else                { Ah = ath; Al = atl; ko = kc - 1024; }
        bf16x8 afh[2], afl[2];
        #pragma unroll
        for (int mt = 0; mt < 2; mt++) {
            const int r = wr * 32 + mt * 16 + l15;
            const size_t ao = (size_t)(m0 + r) * 512 + ko + lk * 8;
            afh[mt] = *(const bf16x8*)(Ah + ao);
            afl[mt] = *(const bf16x8*)(Al + ao);
        }
        #pragma unroll
        for (int nt = 0; nt < 8; nt++) {
            const int nn = wc * 128 + nt * 16 + l15;
            const size_t bo = (size_t)(n0 + nn) * 1536 + kc + lk * 8;
            bf16x8 bh = *(const bf16x8*)(wgh + bo);
            bf16x8 bl = *(const bf16x8*)(wgl + bo);
            #pragma unroll
            for (int mt = 0; mt < 2; mt++) {
                acc[mt][nt] = __builtin_amdgcn_mfma_f32_16x16x32_bf16(afh[mt], bh, acc[mt][nt], 0, 0, 0);
                acc[mt][nt] = __builtin_amdgcn_mfma_f32_16x16x32_bf16(afl[mt], bh, acc[mt][nt], 0, 0, 0);
                acc[mt][nt] = __builtin_amdgcn_mfma_f32_16x16x32_bf16(afh[mt], bl, acc[mt][nt], 0, 0, 0);
            }
        }
    }
    #pragma unroll
    for (int mt = 0; mt < 2; mt++)
        #pragma unroll
        for (int reg = 0; reg < 4; reg++) {
            const int row = m0 + wr * 32 + mt * 16 + lk * 4 + reg;
            #pragma unroll
            for (int nt = 0; nt < 8; nt++) {
                const int col = n0 + wc * 128 + nt * 16 + l15;
                const float v = tanhf(acc[mt][nt][reg] + bgen[col]);
                const unsigned short hb = f2bf(v);
                const unsigned short lb = f2bf(v - bf2f(hb));
                const size_t ca = (size_t)(col >> 5) * 32768 + (size_t)(row >> 6) * 2048
                                + (size_t)(row & 63) * 32 + (col & 31);
                dhk[ca] = hb;
                dlk[ca] = lb;
            }
        }
}

// ---------------------------------------------------------------------------
// k_g0 (fp32 fallback)
// ---------------------------------------------------------------------------
__global__ __launch_bounds__(256) void k_g0(const int* __restrict__ tgt_in,
                                            const float* __restrict__ emb,
                                            const float* __restrict__ Wih,
                                            const float* __restrict__ bih,
                                            const float* __restrict__ bhh,
                                            float* __restrict__ G0T) {
    __shared__ float a_s[32][66];
    __shared__ float w_s[32][130];
    const int tid = threadIdx.x;
    const int m0 = blockIdx.x * 64, n0 = blockIdx.y * 128;
    const int mq = tid >> 5, nq = tid & 31;
    float acc[8][4] = {};
    for (int k0 = 0; k0 < 512; k0 += 32) {
        {
            const int mm = tid >> 2, kq = tid & 3, kk = kq * 8;
            const float* row = emb + (size_t)tgt_in[m0 + mm] * E_ + k0 + kk;
            float4 v0 = *(const float4*)(row);
            float4 v1 = *(const float4*)(row + 4);
            a_s[kk + 0][mm] = v0.x; a_s[kk + 1][mm] = v0.y;
            a_s[kk + 2][mm] = v0.z; a_s[kk + 3][mm] = v0.w;
            a_s[kk + 4][mm] = v1.x; a_s[kk + 5][mm] = v1.y;
            a_s[kk + 6][mm] = v1.z; a_s[kk + 7][mm] = v1.w;
        }
        {
            const int nn = tid >> 1, kq = tid & 1, kk = kq * 16;
            const float* row = Wih + (size_t)(n0 + nn) * 1024 + k0 + kk;
            #pragma unroll
            for (int u = 0; u < 4; u++) {
                float4 v = *(const float4*)(row + u * 4);
                w_s[kk + u * 4 + 0][nn] = v.x; w_s[kk + u * 4 + 1][nn] = v.y;
                w_s[kk + u * 4 + 2][nn] = v.z; w_s[kk + u * 4 + 3][nn] = v.w;
            }
        }
        __syncthreads();
        for (int k = 0; k < 32; k++) {
            float a[8], wv[4];
            #pragma unroll
            for (int i = 0; i < 8; i++) a[i] = a_s[k][mq + 8 * i];
            #pragma unroll
            for (int p = 0; p < 4; p++) wv[p] = w_s[k][nq + 32 * p];
            #pragma unroll
            for (int i = 0; i < 8; i++)
                #pragma unroll
                for (int p = 0; p < 4; p++) acc[i][p] += a[i] * wv[p];
        }
        __syncthreads();
    }
    #pragma unroll
    for (int i = 0; i < 8; i++) {
        const int m = m0 + mq + 8 * i;
        #pragma unroll
        for (int p = 0; p < 4; p++) {
            const int n = n0 + nq + 32 * p;
            G0T[(size_t)n * 1024 + m] = acc[i][p] + bih[n] + bhh[n];
        }
    }
}

// ---------------------------------------------------------------------------
// k_u (fp32 fallback)
// ---------------------------------------------------------------------------
__global__ __launch_bounds__(256) void k_u(const float* __restrict__ src,
                                           const float* __restrict__ Wattn,
                                           float* __restrict__ U) {
    __shared__ float a_s[32][66];
    __shared__ float w_s[32][130];
    const int tid = threadIdx.x;
    const int m0 = blockIdx.x * 64, n0 = blockIdx.y * 128;
    const int mq = tid >> 5, nq = tid & 31;
    float acc[8][4] = {};
    for (int k0 = 0; k0 < 512; k0 += 32) {
        {
            const int mm = tid >> 2, kq = tid & 3, kk = kq * 8;
            const float* row = src + (size_t)(m0 + mm) * 512 + k0 + kk;
            float4 v0 = *(const float4*)(row);
            float4 v1 = *(const float4*)(row + 4);
            a_s[kk + 0][mm] = v0.x; a_s[kk + 1][mm] = v0.y;
            a_s[kk + 2][mm] = v0.z; a_s[kk + 3][mm] = v0.w;
            a_s[kk + 4][mm] = v1.x; a_s[kk + 5][mm] = v1.y;
            a_s[kk + 6][mm] = v1.z; a_s[kk + 7][mm] = v1.w;
        }
        {
            const int nn = tid >> 1, kq = tid & 1, kk = kq * 16;
            const float* row = Wattn + (size_t)(n0 + nn) * 1024 + k0 + kk;
            #pragma unroll
            for (int u = 0; u < 4; u++) {
                float4 v = *(const float4*)(row + u * 4);
                w_s[kk + u * 4 + 0][nn] = v.x; w_s[kk + u * 4 + 1][nn] = v.y;
                w_s[kk + u * 4 + 2][nn] = v.z; w_s[kk + u * 4 + 3][nn] = v.w;
            }
        }
        __syncthreads();
        for (int k = 0; k < 32; k++) {
            float a[8], wv[4];
            #pragma unroll
            for (int i = 0; i < 8; i++) a[i] = a_s[k][mq + 8 * i];
            #pragma unroll
            for (int p = 0; p < 4; p++) wv[p] = w_s[k][nq + 32 * p];
            #pragma unroll
            for (int i = 0; i < 8; i++)
                #pragma unroll
                for (int p = 0; p < 4; p++) acc[i][p] += a[i] * wv[p];
        }
        __syncthreads();
    }
    #pragma unroll
    for (int i = 0; i < 8; i++) {
        const int m = m0 + mq + 8 * i;
        #pragma unroll
        for (int p = 0; p < 4; p++)
            U[(size_t)m * 512 + n0 + nq + 32 * p] = acc[i][p];
    }
}

// ---------------------------------------------------------------------------
// k_tr: WaRT[k][j] = W_attn[j][512+k]
// ---------------------------------------------------------------------------
__global__ __launch_bounds__(256) void k_tr(const float* __restrict__ Wattn,
                                            float* __restrict__ WaRT) {
    __shared__ float t_s[32][33];
    const int tid = threadIdx.x;
    const int bx = blockIdx.x, by = blockIdx.y;
    {
        const int jj = tid >> 3, kq = (tid & 7) * 4;
        float4 v = *(const float4*)(Wattn + (size_t)(by * 32 + jj) * 1024 + 512 + bx * 32 + kq);
        t_s[jj][kq + 0] = v.x; t_s[jj][kq + 1] = v.y;
        t_s[jj][kq + 2] = v.z; t_s[jj][kq + 3] = v.w;
    }
    __syncthreads();
    {
        const int kk = tid >> 3, jq = (tid & 7) * 4;
        float4 w;
        w.x = t_s[jq + 0][kk]; w.y = t_s[jq + 1][kk];
        w.z = t_s[jq + 2][kk]; w.w = t_s[jq + 3][kk];
        *(float4*)(WaRT + (size_t)(bx * 32 + kk) * 512 + by * 32 + jq) = w;
    }
}

// ---------------------------------------------------------------------------
// k_wconv: Wread fp32 -> bf16 hi/lo, chunk-major with BAKED bank swizzle.
// ---------------------------------------------------------------------------
__global__ __launch_bounds__(256) void k_wconv(const float* __restrict__ Wread,
                                               unsigned short* __restrict__ whk,
                                               unsigned short* __restrict__ wlk) {
    const size_t q = (size_t)blockIdx.x * 256 + threadIdx.x;
    const size_t k8 = q * 8;
    const int n = (int)(k8 >> 9);
    const int k = (int)(k8 & 511);
    if (n >= VP_) return;
    uint4 h4, l4;
    if (n < V_) {
        float4 p0 = *(const float4*)(Wread + (size_t)n * 512 + k);
        float4 p1 = *(const float4*)(Wread + (size_t)n * 512 + k + 4);
        float v[8] = {p0.x, p0.y, p0.z, p0.w, p1.x, p1.y, p1.z, p1.w};
        unsigned int hb[8], lb[8];
        #pragma unroll
        for (int e = 0; e < 8; e++) {
            hb[e] = f2bf(v[e]);
            lb[e] = f2bf(v[e] - bf2f((unsigned short)hb[e]));
        }
        h4 = make_uint4(hb[0] | (hb[1] << 16), hb[2] | (hb[3] << 16),
                        hb[4] | (hb[5] << 16), hb[6] | (hb[7] << 16));
        l4 = make_uint4(lb[0] | (lb[1] << 16), lb[2] | (lb[3] << 16),
                        lb[4] | (lb[5] << 16), lb[6] | (lb[7] << 16));
    } else {
        h4 = make_uint4(0, 0, 0, 0);
        l4 = make_uint4(0, 0, 0, 0);
    }
    const int lk = (k >> 3) & 3;
    const size_t dst = (size_t)(k >> 5) * ((size_t)VP_ * 32) + (size_t)n * 32
                     + (size_t)((lk ^ ((n >> 1) & 3)) * 8);
    *(uint4*)(whk + dst) = h4;
    *(uint4*)(wlk + dst) = l4;
}

// ---------------------------------------------------------------------------
// Persistent scan (round-11 proven; + optional bf16-split h/att emission).
// ---------------------------------------------------------------------------
__global__ __launch_bounds__(512) void k_scan(const float* __restrict__ G0T,
                                              const float* __restrict__ U,
                                              const float* __restrict__ WaRT,
                                              const float* __restrict__ Wih,
                                              const float* __restrict__ Whh,
                                              const float* __restrict__ src,
                                              const int* __restrict__ lens,
                                              const float* __restrict__ last_cell,
                                              float* __restrict__ xT,
                                              float* __restrict__ h_b,
                                              float* __restrict__ scb,
                                              float* __restrict__ h_hist,
                                              float* __restrict__ att_hist,
                                              unsigned short* __restrict__ hh,
                                              unsigned short* __restrict__ hl,
                                              unsigned short* __restrict__ ath,
                                              unsigned short* __restrict__ atl,
                                              int pre,
                                              int* __restrict__ bar) {
    __shared__ float Wl[8 * 1024];
    __shared__ float Ul[200 * 64];
    __shared__ float red_s[2048];
    __shared__ float gate_s[256];
    __shared__ float h_s[512];
    __shared__ float al[256];
    __shared__ float pr[512];

    const int blk = blockIdx.x, tid = threadIdx.x;
    const int u0 = blk * 2;
    const int bb = blk & 31, p = blk >> 5;

    for (int f = tid; f < 2048; f += 512) {
        const int r = f >> 8, k = (f & 255) * 4;
        const int j = (r >> 1) * 512 + u0 + (r & 1);
        float4 v;
        if (k < 512) v = *(const float4*)(Wih + (size_t)j * 1024 + 512 + k);
        else         v = *(const float4*)(Whh + (size_t)j * 512 + (k - 512));
        *(float4*)&Wl[r * 1024 + k] = v;
    }
    for (int f = tid; f < 3200; f += 512) {
        const int s = f >> 4, q = (f & 15) * 4;
        *(float4*)&Ul[s * 64 + q] = *(const float4*)(U + ((size_t)bb * S_ + s) * 512 + p * 64 + q);
    }
    float creg = (tid < 64) ? last_cell[(tid & 31) * 512 + u0 + (tid >> 5)] : 0.f;
    __syncthreads();

    const int w = tid >> 6, lane = tid & 63;
    const int hf = lane >> 5, b = lane & 31;
    const int len = lens[bb];

    for (int t = 0; t < T_; t++) {
        // -------- Phase A: gates + pointwise ------------------------------
        {
            const int hoff = ((t + 1) & 1) * 512;        // slot holding h(t-1)
            const int kbase = w * 128 + hf * 64;
            const float* xp = (kbase < 512)
                ? (xT + (size_t)kbase * 32 + b)
                : (xT + (size_t)(512 + hoff + (kbase - 512)) * 32 + b);
            float acc[8] = {};
            #pragma unroll
            for (int kk = 0; kk < 64; kk += 8) {
                float xv[8];
                #pragma unroll
                for (int i = 0; i < 8; i++)
                    xv[i] = g_load(xp + (size_t)(kk + i) * 32);
                #pragma unroll
                for (int r = 0; r < 8; r++) {
                    const float* wr = &Wl[r * 1024 + kbase + kk];
                    float s0 = xv[0] * wr[0] + xv[1] * wr[1] + xv[2] * wr[2] + xv[3] * wr[3];
                    float s1 = xv[4] * wr[4] + xv[5] * wr[5] + xv[6] * wr[6] + xv[7] * wr[7];
                    acc[r] += s0 + s1;
                }
            }
            #pragma unroll
            for (int r = 0; r < 8; r++) acc[r] += __shfl_xor(acc[r], 32);
            if (hf == 0) {
                #pragma unroll
                for (int r = 0; r < 8; r++) red_s[w * 256 + r * 32 + b] = acc[r];
            }
            __syncthreads();
            if (tid < 256) {
                const int r = tid >> 5, b2 = tid & 31;
                const int j = (r >> 1) * 512 + u0 + (r & 1);
                float g = G0T[(size_t)j * 1024 + t * 32 + b2];
                #pragma unroll
                for (int ww = 0; ww < 8; ww++) g += red_s[ww * 256 + r * 32 + b2];
                gate_s[r * 32 + b2] = g;
            }
            __syncthreads();
            if (tid < 64) {
                const int ui = tid >> 5, b2 = tid & 31, u = u0 + ui;
                const float gi = gate_s[(0 + ui) * 32 + b2];
                const float gf = gate_s[(2 + ui) * 32 + b2];
                const float gg = gate_s[(4 + ui) * 32 + b2];
                const float go = gate_s[(6 + ui) * 32 + b2];
                const float cn = sigf(gf) * creg + sigf(gi) * tanhf(gg);
                const float hn = sigf(go) * tanhf(cn);
                creg = cn;
                g_store(&xT[(size_t)(512 + (t & 1) * 512 + u) * 32 + b2], hn);
                g_store(&h_b[b2 * 512 + u], hn);
                h_hist[((size_t)t * B_ + b2) * 512 + u] = hn;
                if (pre) {
                    const unsigned short hb2 = f2bf(hn);
                    const size_t ho = ((size_t)t * B_ + b2) * 512 + u;
                    hh[ho] = hb2;
                    hl[ho] = f2bf(hn - bf2f(hb2));
                }
            }
        }
        full_sync(bar, 2 * t);

        // -------- Phase B: scores -----------------------------------------
        {
            h_s[tid] = g_load(&h_b[bb * 512 + tid]);
            __syncthreads();
            for (int i = w; i < 25; i += 8) {
                const int s = p * 25 + i;
                const float* sr = src + ((size_t)bb * S_ + s) * 512;
                const float4 x0 = *(const float4*)(sr + lane * 4);
                const float4 x1 = *(const float4*)(sr + 256 + lane * 4);
                const float4 h0 = *(const float4*)(&h_s[lane * 4]);
                const float4 h1 = *(const float4*)(&h_s[256 + lane * 4]);
                float a = x0.x * h0.x + x0.y * h0.y + x0.z * h0.z + x0.w * h0.w
                        + x1.x * h1.x + x1.y * h1.y + x1.z * h1.z + x1.w * h1.w;
                #pragma unroll
                for (int mk = 1; mk < 64; mk <<= 1) a += __shfl_xor(a, mk);
                if (lane == 0) g_store(&scb[bb * 256 + s], (s < len) ? a : -INFINITY);
            }
        }
        sub_sync(bar, bb, t);

        // -------- Phase C: softmax + att slice ----------------------------
        {
            if (tid < 64) {
                const float v0 = g_load(&scb[bb * 256 + tid]);
                const float v1 = g_load(&scb[bb * 256 + 64 + tid]);
                const float v2 = g_load(&scb[bb * 256 + 128 + tid]);
                const float v3 = (tid < 8) ? g_load(&scb[bb * 256 + 192 + tid]) : -INFINITY;
                float m = fmaxf(fmaxf(v0, v1), fmaxf(v2, v3));
                #pragma unroll
                for (int mk = 1; mk < 64; mk <<= 1) m = fmaxf(m, __shfl_xor(m, mk));
                const float e0 = expf(v0 - m), e1 = expf(v1 - m), e2 = expf(v2 - m);
                const float e3 = (tid < 8) ? expf(v3 - m) : 0.f;
                float sum = (e0 + e1) + (e2 + e3);
                #pragma unroll
                for (int mk = 1; mk < 64; mk <<= 1) sum += __shfl_xor(sum, mk);
                const float inv = 1.f / sum;
                al[tid] = e0 * inv; al[64 + tid] = e1 * inv; al[128 + tid] = e2 * inv;
                if (tid < 8) al[192 + tid] = e3 * inv;
            }
            __syncthreads();
            const int jl = tid & 63, sg = tid >> 6;
            float uacc = 0.f;
            #pragma unroll 5
            for (int s = sg * 25; s < sg * 25 + 25; s++)
                uacc += al[s] * Ul[s * 64 + jl];
            const float* wc0 = WaRT + (size_t)(sg * 64) * 512 + p * 64 + jl;
            const float* hp = &h_s[sg * 64];
            float c0 = 0.f, c1 = 0.f;
            #pragma unroll 8
            for (int kk = 0; kk < 64; kk += 2) {
                c0 += hp[kk] * wc0[(size_t)kk * 512];
                c1 += hp[kk + 1] * wc0[(size_t)(kk + 1) * 512];
            }
            pr[tid] = uacc + c0 + c1;
            __syncthreads();
            if (tid < 64) {
                float tot = 0.f;
                #pragma unroll
                for (int sgg = 0; sgg < 8; sgg++) tot += pr[sgg * 64 + tid];
                const float a = tanhf(tot);
                g_store(&xT[(size_t)(p * 64 + tid) * 32 + bb], a);
                att_hist[((size_t)t * B_ + bb) * 512 + p * 64 + tid] = a;
                if (pre) {
                    const unsigned short ab = f2bf(a);
                    const size_t ao = ((size_t)t * B_ + bb) * 512 + p * 64 + tid;
                    ath[ao] = ab;
                    atl[ao] = f2bf(a - bf2f(ab));
                }
            }
        }
        full_sync(bar, 2 * t + 1);
    }
}

// ---------------------------------------------------------------------------
// k_dec (fp32 fallback): writes row-major dh/dl for k_read.
// ---------------------------------------------------------------------------
__global__ __launch_bounds__(256) void k_dec(const int* __restrict__ tgt_in,
                                             const float* __restrict__ emb,
                                             const float* __restrict__ h_hist,
                                             const float* __restrict__ att_hist,
                                             const float* __restrict__ Wgen,
                                             const float* __restrict__ bgen,
                                             unsigned short* __restrict__ dh,
                                             unsigned short* __restrict__ dl) {
    __shared__ float a_s[32][66];
    __shared__ float w_s[32][130];
    const int tid = threadIdx.x;
    const int m0 = blockIdx.x * 64, n0 = blockIdx.y * 128;
    const int mq = tid >> 5, nq = tid & 31;
    float acc[8][4] = {};
    for (int k0 = 0; k0 < 1536; k0 += 32) {
        {
            const int mm = tid >> 2, kq = tid & 3, kk = kq * 8;
            const int m = m0 + mm;
            const float* row;
            if (k0 < 512)       row = emb + (size_t)tgt_in[m] * E_ + k0;
            else if (k0 < 1024) row = h_hist + (size_t)m * 512 + (k0 - 512);
            else                row = att_hist + (size_t)m * 512 + (k0 - 1024);
            row += kk;
            float4 v0 = *(const float4*)(row);
            float4 v1 = *(const float4*)(row + 4);
            a_s[kk + 0][mm] = v0.x; a_s[kk + 1][mm] = v0.y;
            a_s[kk + 2][mm] = v0.z; a_s[kk + 3][mm] = v0.w;
            a_s[kk + 4][mm] = v1.x; a_s[kk + 5][mm] = v1.y;
            a_s[kk + 6][mm] = v1.z; a_s[kk + 7][mm] = v1.w;
        }
        {
            const int nn = tid >> 1, kq = tid & 1, kk = kq * 16;
            const float* row = Wgen + (size_t)(n0 + nn) * 1536 + k0 + kk;
            #pragma unroll
            for (int u = 0; u < 4; u++) {
                float4 v = *(const float4*)(row + u * 4);
                w_s[kk + u * 4 + 0][nn] = v.x; w_s[kk + u * 4 + 1][nn] = v.y;
                w_s[kk + u * 4 + 2][nn] = v.z; w_s[kk + u * 4 + 3][nn] = v.w;
            }
        }
        __syncthreads();
        for (int k = 0; k < 32; k++) {
            float a[8], wv[4];
            #pragma unroll
            for (int i = 0; i < 8; i++) a[i] = a_s[k][mq + 8 * i];
            #pragma unroll
            for (int pq = 0; pq < 4; pq++) wv[pq] = w_s[k][nq + 32 * pq];
            #pragma unroll
            for (int i = 0; i < 8; i++)
                #pragma unroll
                for (int pq = 0; pq < 4; pq++) acc[i][pq] += a[i] * wv[pq];
        }
        __syncthreads();
    }
    #pragma unroll
    for (int i = 0; i < 8; i++) {
        const int m = m0 + mq + 8 * i;
        #pragma unroll
        for (int pq = 0; pq < 4; pq++) {
            const int n = n0 + nq + 32 * pq;
            const float v = tanhf(acc[i][pq] + bgen[n]);
            const unsigned short hb = f2bf(v);
            dh[(size_t)m * 512 + n] = hb;
            dl[(size_t)m * 512 + n] = f2bf(v - bf2f(hb));
        }
    }
}

// ===========================================================================
// k_read_pre (round-11 proven): B via global_load_lds from pre-swizzled
// chunk-major whk/wlk; A-frags per-lane direct from chunk-major dhk/dlk.
// ===========================================================================
__global__ __launch_bounds__(256) void k_read_pre(const unsigned short* __restrict__ dhk,
                                                  const unsigned short* __restrict__ dlk,
                                                  const unsigned short* __restrict__ whk,
                                                  const unsigned short* __restrict__ wlk,
                                                  const int* __restrict__ tgt_out,
                                                  float4* __restrict__ part,
                                                  float* __restrict__ tgt_logit) {
    __shared__ __align__(16) unsigned short BhL[8192];   // 16 KB
    __shared__ __align__(16) unsigned short BlL[8192];   // 16 KB
    __shared__ float ep_max[64][2];
    __shared__ int   ep_idx[64][2];
    __shared__ float ep_fin[64];
    __shared__ int   ep_fidx[64];
    __shared__ float ep_sum[64][2];

    const int xcd = blockIdx.x & 7;
    const int idx = blockIdx.x >> 3;
    const int mi  = idx & 15;
    const int group = idx >> 4;
    const int ch = group * 8 + xcd;
    if (ch >= NCH) return;
    const int m0 = mi * 64, n0 = ch * 256;

    const int tid = threadIdx.x;
    const int lane = tid & 63, wid = tid >> 6;
    const int wr = wid >> 1, wc = wid & 1;
    const int l15 = lane & 15, lk = lane >> 4;

    f32x4 acc[2][8];
    #pragma unroll
    for (int mt = 0; mt < 2; mt++)
        #pragma unroll
        for (int nt = 0; nt < 8; nt++) acc[mt][nt] = {0.f, 0.f, 0.f, 0.f};

    const unsigned short* bh_src = whk + (size_t)n0 * 32;
    const unsigned short* bl_src = wlk + (size_t)n0 * 32;
    const unsigned short* ah_base = dhk + (size_t)(m0 >> 6) * 2048 + lk * 8;
    const unsigned short* al_base = dlk + (size_t)(m0 >> 6) * 2048 + lk * 8;

    for (int kc = 0; kc < 16; kc++) {
        {
            const size_t cb = (size_t)kc * ((size_t)VP_ * 32);
            const char* gh = (const char*)(bh_src + cb);
            const char* gl = (const char*)(bl_src + cb);
            #pragma unroll
            for (int c = 0; c < 4; c++) {
                const int ob = wid * 4096 + c * 1024;
                async16((char*)BhL + ob, gh + ob + lane * 16);
                async16((char*)BlL + ob, gl + ob + lane * 16);
            }
        }
        bf16x8 afh[2], afl[2];
        {
            const unsigned short* ah = ah_base + (size_t)kc * 32768;
            const unsigned short* al = al_base + (size_t)kc * 32768;
            #pragma unroll
            for (int mt = 0; mt < 2; mt++) {
                const int r = wr * 32 + mt * 16 + l15;
                afh[mt] = *(const bf16x8*)(ah + r * 32);
                afl[mt] = *(const bf16x8*)(al + r * 32);
            }
        }
        __syncthreads();
        #pragma unroll
        for (int nt = 0; nt < 8; nt++) {
            const int nn = wc * 128 + nt * 16 + l15;
            const int bo = nn * 32 + ((lk ^ ((nn >> 1) & 3)) * 8);
            bf16x8 bh = *(const bf16x8*)&BhL[bo];
            bf16x8 bl = *(const bf16x8*)&BlL[bo];
            #pragma unroll
            for (int mt = 0; mt < 2; mt++) {
                acc[mt][nt] = __builtin_amdgcn_mfma_f32_16x16x32_bf16(afh[mt], bh, acc[mt][nt], 0, 0, 0);
                acc[mt][nt] = __builtin_amdgcn_mfma_f32_16x16x32_bf16(afl[mt], bh, acc[mt][nt], 0, 0, 0);
                acc[mt][nt] = __builtin_amdgcn_mfma_f32_16x16x32_bf16(afh[mt], bl, acc[mt][nt], 0, 0, 0);
            }
        }
        __syncthreads();
    }

    #pragma unroll
    for (int mt = 0; mt < 2; mt++)
        #pragma unroll
        for (int reg = 0; reg < 4; reg++) {
            float bv = -INFINITY; int bi = 0x7fffffff;
            #pragma unroll
            for (int nt = 0; nt < 8; nt++) {
                const int n = n0 + wc * 128 + nt * 16 + l15;
                const float v = (n < V_) ? acc[mt][nt][reg] : -INFINITY;
                if (v > bv || (v == bv && n < bi)) { bv = v; bi = n; }
            }
            #pragma unroll
            for (int mk = 1; mk < 16; mk <<= 1) {
                const float ov = __shfl_xor(bv, mk);
                const int oi = __shfl_xor(bi, mk);
                if (ov > bv || (ov == bv && oi < bi)) { bv = ov; bi = oi; }
            }
            if (l15 == 0) {
                const int rl = wr * 32 + mt * 16 + lk * 4 + reg;
                ep_max[rl][wc] = bv; ep_idx[rl][wc] = bi;
            }
        }
    __syncthreads();
    if (tid < 64) {
        const float a = ep_max[tid][0], b = ep_max[tid][1];
        const int ia = ep_idx[tid][0], ib = ep_idx[tid][1];
        const bool tb = (b > a) || (b == a && ib < ia);
        ep_fin[tid] = tb ? b : a; ep_fidx[tid] = tb ? ib : ia;
    }
    __syncthreads();
    #pragma unroll
    for (int mt = 0; mt < 2; mt++)
        #pragma unroll
        for (int reg = 0; reg < 4; reg++) {
            const int rl = wr * 32 + mt * 16 + lk * 4 + reg;
            const float M = ep_fin[rl];
            const int rel = tgt_out[m0 + rl] - n0;
            float se = 0.f;
            #pragma unroll
            for (int nt = 0; nt < 8; nt++) {
                const int nl = wc * 128 + nt * 16 + l15;
                if (n0 + nl < V_) {
                    const float v = acc[mt][nt][reg];
                    se += expf(v - M);
                    if (nl == rel) tgt_logit[m0 + rl] = v;
                }
            }
            #pragma unroll
            for (int mk = 1; mk < 16; mk <<= 1) se += __shfl_xor(se, mk);
            if (l15 == 0) ep_sum[rl][wc] = se;
        }
    __syncthreads();
    if (tid < 64) {
        part[(size_t)(m0 + tid) * NCH + ch] =
            make_float4(ep_fin[tid], ep_sum[tid][0] + ep_sum[tid][1],
                        __int_as_float(ep_fidx[tid]), 0.f);
    }
}

// ---------------------------------------------------------------------------
// k_read (fallback: in-kernel conversion, row-major dh/dl, grid 3200)
// ---------------------------------------------------------------------------
__global__ __launch_bounds__(256) void k_read(const unsigned short* __restrict__ dh,
                                              const unsigned short* __restrict__ dl,
                                              const float* __restrict__ Wread,
                                              const int* __restrict__ tgt_out,
                                              float4* __restrict__ part,
                                              float* __restrict__ tgt_logit) {
    __shared__ __align__(16) unsigned short Bh[4][256][8];
    __shared__ __align__(16) unsigned short Bl[4][256][8];
    __shared__ __align__(16) unsigned short Ah[4][64][8];
    __shared__ __align__(16) unsigned short Alo[4][64][8];
    __shared__ float ep_max[64][2];
    __shared__ int   ep_idx[64][2];
    __shared__ float ep_fin[64];
    __shared__ int   ep_fidx[64];
    __shared__ float ep_sum[64][2];

    const int xcd = blockIdx.x & 7;
    const int idx = blockIdx.x >> 3;
    const int mi  = idx & 15;
    const int group = idx >> 4;
    const int ch = group * 8 + xcd;
    if (ch >= NCH) return;
    const int m0 = mi * 64, n0 = ch * 256;

    const int tid = threadIdx.x;
    const int lane = tid & 63, wid = tid >> 6;
    const int wr = wid >> 1, wc = wid & 1;
    const int l15 = lane & 15, lk = lane >> 4;

    f32x4 acc[2][8];
    #pragma unroll
    for (int mt = 0; mt < 2; mt++)
        #pragma unroll
        for (int nt = 0; nt < 8; nt++) acc[mt][nt] = {0.f, 0.f, 0.f, 0.f};

    for (int kc = 0; kc < 512; kc += 32) {
        {
            const int n = n0 + tid;
            const float* row = Wread + (size_t)n * 512 + kc;
            #pragma unroll
            for (int g = 0; g < 4; g++) {
                uint4 h4, l4;
                if (n < V_) {
                    float4 p0 = *(const float4*)(row + g * 8);
                    float4 p1 = *(const float4*)(row + g * 8 + 4);
                    float v[8] = {p0.x, p0.y, p0.z, p0.w, p1.x, p1.y, p1.z, p1.w};
                    unsigned int hb[8], lb[8];
                    #pragma unroll
                    for (int e = 0; e < 8; e++) {
                        hb[e] = f2bf(v[e]);
                        lb[e] = f2bf(v[e] - bf2f((unsigned short)hb[e]));
                    }
                    h4 = make_uint4(hb[0] | (hb[1] << 16), hb[2] | (hb[3] << 16),
                                    hb[4] | (hb[5] << 16), hb[6] | (hb[7] << 16));
                    l4 = make_uint4(lb[0] | (lb[1] << 16), lb[2] | (lb[3] << 16),
                                    lb[4] | (lb[5] << 16), lb[6] | (lb[7] << 16));
                } else {
                    h4 = make_uint4(0, 0, 0, 0);
                    l4 = make_uint4(0, 0, 0, 0);
                }
                *(uint4*)&Bh[g][tid][0] = h4;
                *(uint4*)&Bl[g][tid][0] = l4;
            }
        }
        {
            const int row = tid >> 2, g = tid & 3;
            *(uint4*)&Ah[g][row][0]  = *(const uint4*)(dh + (size_t)(m0 + row) * 512 + kc + g * 8);
            *(uint4*)&Alo[g][row][0] = *(const uint4*)(dl + (size_t)(m0 + row) * 512 + kc + g * 8);
        }
        __syncthreads();
        {
            bf16x8 afh[2], afl[2];
            #pragma unroll
            for (int mt = 0; mt < 2; mt++) {
                const int r = wr * 32 + mt * 16 + l15;
                afh[mt] = *(const bf16x8*)&Ah[lk][r][0];
                afl[mt] = *(const bf16x8*)&Alo[lk][r][0];
            }
            #pragma unroll
            for (int nt = 0; nt < 8; nt++) {
                const int nn = wc * 128 + nt * 16 + l15;
                bf16x8 bh = *(const bf16x8*)&Bh[lk][nn][0];
                bf16x8 bl = *(const bf16x8*)&Bl[lk][nn][0];
                #pragma unroll
                for (int mt = 0; mt < 2; mt++) {
                    acc[mt][nt] = __builtin_amdgcn_mfma_f32_16x16x32_bf16(afh[mt], bh, acc[mt][nt], 0, 0, 0);
                    acc[mt][nt] = __builtin_amdgcn_mfma_f32_16x16x32_bf16(afl[mt], bh, acc[mt][nt], 0, 0, 0);
                    acc[mt][nt] = __builtin_amdgcn_mfma_f32_16x16x32_bf16(afh[mt], bl, acc[mt][nt], 0, 0, 0);
                }
            }
        }
        __syncthreads();
    }

    #pragma unroll
    for (int mt = 0; mt < 2; mt++)
        #pragma unroll
        for (int reg = 0; reg < 4; reg++) {
            float bv = -INFINITY; int bi = 0x7fffffff;
            #pragma unroll
            for (int nt = 0; nt < 8; nt++) {
                const int n = n0 + wc * 128 + nt * 16 + l15;
                const float v = (n < V_) ? acc[mt][nt][reg] : -INFINITY;
                if (v > bv || (v == bv && n < bi)) { bv = v; bi = n; }
            }
            #pragma unroll
            for (int mk = 1; mk < 16; mk <<= 1) {
                const float ov = __shfl_xor(bv, mk);
                const int oi = __shfl_xor(bi, mk);
                if (ov > bv || (ov == bv && oi < bi)) { bv = ov; bi = oi; }
            }
            if (l15 == 0) {
                const int rl = wr * 32 + mt * 16 + lk * 4 + reg;
                ep_max[rl][wc] = bv; ep_idx[rl][wc] = bi;
            }
        }
    __syncthreads();
    if (tid < 64) {
        const float a = ep_max[tid][0], b = ep_max[tid][1];
        const int ia = ep_idx[tid][0], ib = ep_idx[tid][1];
        const bool tb = (b > a) || (b == a && ib < ia);
        ep_fin[tid] = tb ? b : a; ep_fidx[tid] = tb ? ib : ia;
    }
    __syncthreads();
    #pragma unroll
    for (int mt = 0; mt < 2; mt++)
        #pragma unroll
        for (int reg = 0; reg < 4; reg++) {
            const int rl = wr * 32 + mt * 16 + lk * 4 + reg;
            const float M = ep_fin[rl];
            const int rel = tgt_out[m0 + rl] - n0;
            float se = 0.f;
            #pragma unroll
            for (int nt = 0; nt < 8; nt++) {
                const int nl = wc * 128 + nt * 16 + l15;
                if (n0 + nl < V_) {
                    const float v = acc[mt][nt][reg];
                    se += expf(v - M);
                    if (nl == rel) tgt_logit[m0 + rl] = v;
                }
            }
            #pragma unroll
            for (int mk = 1; mk < 16; mk <<= 1) se += __shfl_xor(se, mk);
            if (l15 == 0) ep_sum[rl][wc] = se;
        }
    __syncthreads();
    if (tid < 64) {
        part[(size_t)(m0 + tid) * NCH + ch] =
            make_float4(ep_fin[tid], ep_sum[tid][0] + ep_sum[tid][1],
                        __int_as_float(ep_fidx[tid]), 0.f);
    }
}

// ---------------------------------------------------------------------------
// k_merge: combine chunk partials -> loss + argmax
// ---------------------------------------------------------------------------
__global__ __launch_bounds__(256) void k_merge(const float4* __restrict__ part,
                                               const float* __restrict__ tgt_logit,
                                               const int* __restrict__ tgt_out,
                                               float* __restrict__ out) {
    const int tid = threadIdx.x;
    const int w = tid >> 6, lane = tid & 63;
    const int row = blockIdx.x * 4 + w;
    float bm = -INFINITY; int bi = 0x7fffffff;
    for (int ch = lane; ch < NCH; ch += 64) {
        const float4 p = part[(size_t)row * NCH + ch];
        const int pi = __float_as_int(p.z);
        if (p.x > bm || (p.x == bm && pi < bi)) { bm = p.x; bi = pi; }
    }
    #pragma unroll
    for (int mk = 1; mk < 64; mk <<= 1) {
        const float ov = __shfl_xor(bm, mk);
        const int oi = __shfl_xor(bi, mk);
        if (ov > bm || (ov == bm && oi < bi)) { bm = ov; bi = oi; }
    }
    float sum = 0.f;
    for (int ch = lane; ch < NCH; ch += 64) {
        const float4 p = part[(size_t)row * NCH + ch];
        sum += p.y * expf(p.x - bm);
    }
    #pragma unroll
    for (int mk = 1; mk < 64; mk <<= 1) sum += __shfl_xor(sum, mk);
    if (lane == 0) {
        const float lse = bm + logf(sum);
        const int tg = tgt_out[row];
        const float loss = (tg != 0) ? (lse - tgt_logit[row]) : 0.f;
        out[row] = loss;
        out[1024 + row] = (float)bi;
    }
}

// ---------------------------------------------------------------------------
extern "C" void kernel_launch(void* const* d_in, const int* in_sizes, int n_in,
                              void* d_out, int out_size, void* d_ws, size_t ws_size,
                              hipStream_t stream) {
    const int* tgt_in = (const int*)d_in[0];
    const int* tgt_out = (const int*)d_in[1];
    const int* src_lens = (const int*)d_in[2];
    const float* src = (const float*)d_in[3];
    const float* last_state = (const float*)d_in[4];
    const float* last_cell = (const float*)d_in[5];
    const float* emb = (const float*)d_in[6];
    const float* Wih = (const float*)d_in[7];
    const float* Whh = (const float*)d_in[8];
    const float* bih = (const float*)d_in[9];
    const float* bhh = (const float*)d_in[10];
    const float* Wattn = (const float*)d_in[11];
    const float* Wgen = (const float*)d_in[12];
    const float* bgen = (const float*)d_in[13];
    const float* Wread = (const float*)d_in[14];
    float* out = (float*)d_out;

    float* ws = (float*)d_ws;
    float* G0T      = ws;                    // 2,097,152 f
    float* U        = G0T + 2097152;         // 3,276,800 f
    float* WaRT     = U + 3276800;           // 262,144 f
    unsigned short* dh  = (unsigned short*)(WaRT + 262144);  // 524,288 u16
    unsigned short* dl  = dh + 524288;
    unsigned short* dhk = dl + 524288;       // chunk-major
    unsigned short* dlk = dhk + 524288;
    float* h_hist   = (float*)(dlk + 524288);
    float* att_hist = h_hist + 524288;
    float* xT       = att_hist + 524288;     // 49,152 f
    float* h_b      = xT + 49152;            // 16,384 f
    float* scb      = h_b + 16384;           // 8,192 f
    float4* part    = (float4*)(scb + 8192); // 200,704 float4
    float* tgtl     = ((float*)part) + 802816; // 1,024 f
    int* bar        = (int*)(tgtl + 1024);     // 2,048 ints
    unsigned short* whk = (unsigned short*)(bar + 2048);   // VP_*512 u16
    unsigned short* wlk = whk + (size_t)VP_ * 512;
    // prologue/dec bf16 operands
    unsigned short* sh    = wlk + (size_t)VP_ * 512;  // 3,276,800 u16
    unsigned short* sl    = sh + 3276800;
    unsigned short* wah   = sl + 3276800;             // 262,144
    unsigned short* wal   = wah + 262144;
    unsigned short* wih_h = wal + 262144;             // 1,048,576
    unsigned short* wih_l = wih_h + 1048576;
    unsigned short* eh    = wih_l + 1048576;          // 524,288
    unsigned short* el    = eh + 524288;
    unsigned short* wgh   = el + 524288;              // 786,432
    unsigned short* wgl   = wgh + 786432;
    unsigned short* hh    = wgl + 786432;             // 524,288
    unsigned short* hl    = hh + 524288;
    unsigned short* ath   = hl + 524288;
    unsigned short* atl   = ath + 524288;

    const size_t need = (size_t)((char*)(atl + 524288) - (char*)ws);
    const int pre = (ws_size >= need) ? 1 : 0;

    hipMemsetAsync(bar, 0, 8192, stream);

    k_init<<<64, 256, 0, stream>>>(last_state, xT);
    if (pre) {
        k_cvt<<<(CVT_R4 + 255) / 256, 256, 0, stream>>>(src, Wattn, Wih, emb, Wgen, tgt_in,
                                                        sh, sl, wah, wal, wih_h, wih_l,
                                                        eh, el, wgh, wgl);
        k_gbt<<<200, 256, 0, stream>>>(sh, sl, wah, wal, nullptr, nullptr, U, 2, 0);
        k_gbt<<<128, 256, 0, stream>>>(eh, el, wih_h, wih_l, bih, bhh, G0T, 8, 1);
    } else {
        k_g0<<<dim3(16, 16), 256, 0, stream>>>(tgt_in, emb, Wih, bih, bhh, G0T);
        k_u<<<dim3(100, 4), 256, 0, stream>>>(src, Wattn, U);
    }
    k_tr<<<dim3(16, 16), 256, 0, stream>>>(Wattn, WaRT);
    if (pre)
        k_wconv<<<12544, 256, 0, stream>>>(Wread, whk, wlk);

    k_scan<<<256, 512, 0, stream>>>(G0T, U, WaRT, Wih, Whh, src, src_lens, last_cell,
                                    xT, h_b, scb, h_hist, att_hist,
                                    hh, hl, ath, atl, pre, bar);

    if (pre) {
        k_gbt_dec<<<32, 256, 0, stream>>>(eh, el, hh, hl, ath, atl, wgh, wgl, bgen, dhk, dlk);
        k_read_pre<<<3200, 256, 0, stream>>>(dhk, dlk, whk, wlk, tgt_out, part, tgtl);
    } else {
        k_dec<<<dim3(16, 4), 256, 0, stream>>>(tgt_in, emb, h_hist, att_hist, Wgen, bgen, dh, dl);
        k_read<<<3200, 256, 0, stream>>>(dh, dl, Wread, tgt_out, part, tgtl);
    }
    k_merge<<<256, 256, 0, stream>>>(part, tgtl, tgt_out, out);
}

// Round 16
// 900.858 us; speedup vs baseline: 1.3967x; 1.0466x over previous
//
#include <hip/hip_runtime.h>
#include <math.h>

#define T_ 32
#define B_ 32
#define S_ 200
#define E_ 512
#define H_ 512
#define V_ 50000
#define VP_ 50176   // padded rows for chunk-major bf16 W
#define G4_ 2048
#define NCH 196     // ceil(50000/256)

using bf16x8 = __attribute__((ext_vector_type(8))) __bf16;
using f32x4  = __attribute__((ext_vector_type(4))) float;

__device__ __forceinline__ float sigf(float x) { return 1.f / (1.f + expf(-x)); }

__device__ __forceinline__ unsigned short f2bf(float v) {
    unsigned int x = __float_as_uint(v);
    return (unsigned short)((x + 0x7FFFu + ((x >> 16) & 1u)) >> 16);
}
__device__ __forceinline__ float bf2f(unsigned short b) {
    return __uint_as_float(((unsigned int)b) << 16);
}

// async global->LDS 16B copy
__device__ __forceinline__ void async16(void* lds, const void* g) {
    __builtin_amdgcn_global_load_lds(
        (const __attribute__((address_space(1))) unsigned int*)g,
        (__attribute__((address_space(3))) unsigned int*)lds, 16, 0, 0);
}

// Coherent LLC-level exchange (relaxed agent atomics -> sc1 load/store)
__device__ __forceinline__ void g_store(float* p, float v) {
    __hip_atomic_store(p, v, __ATOMIC_RELAXED, __HIP_MEMORY_SCOPE_AGENT);
}
__device__ __forceinline__ float g_load(const float* p) {
    return __hip_atomic_load(p, __ATOMIC_RELAXED, __HIP_MEMORY_SCOPE_AGENT);
}

// ---------------------------------------------------------------------------
// Fence-free grid barrier (proven rounds 5-15).
// ---------------------------------------------------------------------------
__device__ __forceinline__ void full_sync(int* bar, int ep) {
    __syncthreads();
    if (threadIdx.x == 0) {
        const int g = blockIdx.x & 7;
        int a = __hip_atomic_fetch_add(&bar[g * 32], 1, __ATOMIC_RELAXED, __HIP_MEMORY_SCOPE_AGENT);
        if (a == ep * 32 + 31) {
            int q = __hip_atomic_fetch_add(&bar[256], 1, __ATOMIC_RELAXED, __HIP_MEMORY_SCOPE_AGENT);
            if (q == ep * 8 + 7) {
                #pragma unroll
                for (int i = 0; i < 8; i++)
                    __hip_atomic_store(&bar[288 + i * 32], ep + 1, __ATOMIC_RELAXED, __HIP_MEMORY_SCOPE_AGENT);
            }
        }
        while (__hip_atomic_load(&bar[288 + g * 32], __ATOMIC_RELAXED, __HIP_MEMORY_SCOPE_AGENT) < ep + 1)
            __builtin_amdgcn_s_sleep(1);
    }
    __syncthreads();
}

__device__ __forceinline__ void sub_sync(int* bar, int bb, int t) {
    __syncthreads();
    if (threadIdx.x == 0) {
        __hip_atomic_fetch_add(&bar[544 + bb * 32], 1, __ATOMIC_RELAXED, __HIP_MEMORY_SCOPE_AGENT);
        while (__hip_atomic_load(&bar[544 + bb * 32], __ATOMIC_RELAXED, __HIP_MEMORY_SCOPE_AGENT) < (t + 1) * 8)
            __builtin_amdgcn_s_sleep(1);
    }
    __syncthreads();
}

// ---------------------------------------------------------------------------
// k_init: xT rows 0..511 att=0; rows 1024..1535 = last_state^T (h slot 1).
// ---------------------------------------------------------------------------
__global__ __launch_bounds__(256) void k_init(const float* __restrict__ last_state,
                                              float* __restrict__ xT) {
    const int f = blockIdx.x * 256 + threadIdx.x;   // 0..16383
    xT[f] = 0.f;
    const int k = f >> 5, b = f & 31;
    xT[32768 + f] = last_state[b * 512 + k];
}

// ---------------------------------------------------------------------------
// k_cvt: fp32 -> bf16 hi/lo for prologue/dec GEMM operands.
// ---------------------------------------------------------------------------
#define CVT_R0 819200
#define CVT_R1 (CVT_R0 + 65536)
#define CVT_R2 (CVT_R1 + 262144)
#define CVT_R3 (CVT_R2 + 131072)
#define CVT_R4 (CVT_R3 + 196608)
__global__ __launch_bounds__(256) void k_cvt(const float* __restrict__ src,
                                             const float* __restrict__ Wattn,
                                             const float* __restrict__ Wih,
                                             const float* __restrict__ emb,
                                             const float* __restrict__ Wgen,
                                             const int* __restrict__ tgt_in,
                                             unsigned short* __restrict__ sh,
                                             unsigned short* __restrict__ sl,
                                             unsigned short* __restrict__ wah,
                                             unsigned short* __restrict__ wal,
                                             unsigned short* __restrict__ wih_h,
                                             unsigned short* __restrict__ wih_l,
                                             unsigned short* __restrict__ eh,
                                             unsigned short* __restrict__ el,
                                             unsigned short* __restrict__ wgh,
                                             unsigned short* __restrict__ wgl) {
    const int u = blockIdx.x * 256 + threadIdx.x;
    if (u >= CVT_R4) return;
    const float* sp;
    unsigned short *dh_, *dl_;
    size_t doff;
    if (u < CVT_R0) {
        sp = src + (size_t)u * 4;
        dh_ = sh; dl_ = sl; doff = (size_t)u * 4;
    } else if (u < CVT_R1) {
        const int idx = u - CVT_R0;
        const int k4 = idx & 127, n = idx >> 7;
        sp = Wattn + (size_t)n * 1024 + k4 * 4;
        dh_ = wah; dl_ = wal; doff = (size_t)n * 512 + k4 * 4;
    } else if (u < CVT_R2) {
        const int idx = u - CVT_R1;
        const int k4 = idx & 127, j = idx >> 7;
        sp = Wih + (size_t)j * 1024 + k4 * 4;
        dh_ = wih_h; dl_ = wih_l; doff = (size_t)j * 512 + k4 * 4;
    } else if (u < CVT_R3) {
        const int idx = u - CVT_R2;
        const int k4 = idx & 127, m = idx >> 7;
        sp = emb + (size_t)tgt_in[m] * 512 + k4 * 4;
        dh_ = eh; dl_ = el; doff = (size_t)m * 512 + k4 * 4;
    } else {
        const int idx = u - CVT_R3;
        const int n = idx / 384, k4 = idx - n * 384;
        sp = Wgen + (size_t)n * 1536 + k4 * 4;
        dh_ = wgh; dl_ = wgl; doff = (size_t)n * 1536 + k4 * 4;
    }
    const float4 v = *(const float4*)sp;
    const float vv[4] = {v.x, v.y, v.z, v.w};
    unsigned int hb[4], lb[4];
    #pragma unroll
    for (int e = 0; e < 4; e++) {
        hb[e] = f2bf(vv[e]);
        lb[e] = f2bf(vv[e] - bf2f((unsigned short)hb[e]));
    }
    *(uint2*)(dh_ + doff) = make_uint2(hb[0] | (hb[1] << 16), hb[2] | (hb[3] << 16));
    *(uint2*)(dl_ + doff) = make_uint2(lb[0] | (lb[1] << 16), lb[2] | (lb[3] << 16));
}

// ---------------------------------------------------------------------------
// k_gbt: C = A . B^T via bf16-split MFMA with LDS-staged tiles (coalesced
// copies, frag reads from LDS — k_read-fallback pattern). 64x256, K=512.
// mode 0: out[m*512+n] (U). mode 1: out[n*1024+m] + bih[n]+bhh[n] (G0T).
// ---------------------------------------------------------------------------
__global__ __launch_bounds__(256) void k_gbt(const unsigned short* __restrict__ Ah,
                                             const unsigned short* __restrict__ Al,
                                             const unsigned short* __restrict__ Bh,
                                             const unsigned short* __restrict__ Bl,
                                             const float* __restrict__ bih,
                                             const float* __restrict__ bhh,
                                             float* __restrict__ out,
                                             int nbn, int mode) {
    __shared__ __align__(16) unsigned short BhL[4][256][8];
    __shared__ __align__(16) unsigned short BlL[4][256][8];
    __shared__ __align__(16) unsigned short AhL[4][64][8];
    __shared__ __align__(16) unsigned short AlL[4][64][8];
    const int m0 = (blockIdx.x / nbn) * 64;
    const int n0 = (blockIdx.x % nbn) * 256;
    const int tid = threadIdx.x;
    const int lane = tid & 63, wid = tid >> 6;
    const int wr = wid >> 1, wc = wid & 1;
    const int l15 = lane & 15, lk = lane >> 4;

    f32x4 acc[2][8];
    #pragma unroll
    for (int mt = 0; mt < 2; mt++)
        #pragma unroll
        for (int nt = 0; nt < 8; nt++) acc[mt][nt] = {0.f, 0.f, 0.f, 0.f};

    for (int kc = 0; kc < 512; kc += 32) {
        {   // B stage: 256 rows x 64B, coalesced (4 x 16B per thread)
            #pragma unroll
            for (int g = 0; g < 4; g++) {
                const size_t bo = (size_t)(n0 + tid) * 512 + kc + g * 8;
                *(uint4*)&BhL[g][tid][0] = *(const uint4*)(Bh + bo);
                *(uint4*)&BlL[g][tid][0] = *(const uint4*)(Bl + bo);
            }
        }
        {   // A stage: 64 rows x 64B
            const int row = tid >> 2, g = tid & 3;
            const size_t ao = (size_t)(m0 + row) * 512 + kc + g * 8;
            *(uint4*)&AhL[g][row][0] = *(const uint4*)(Ah + ao);
            *(uint4*)&AlL[g][row][0] = *(const uint4*)(Al + ao);
        }
        __syncthreads();
        {
            bf16x8 afh[2], afl[2];
            #pragma unroll
            for (int mt = 0; mt < 2; mt++) {
                const int r = wr * 32 + mt * 16 + l15;
                afh[mt] = *(const bf16x8*)&AhL[lk][r][0];
                afl[mt] = *(const bf16x8*)&AlL[lk][r][0];
            }
            #pragma unroll
            for (int nt = 0; nt < 8; nt++) {
                const int nn = wc * 128 + nt * 16 + l15;
                bf16x8 bh = *(const bf16x8*)&BhL[lk][nn][0];
                bf16x8 bl = *(const bf16x8*)&BlL[lk][nn][0];
                #pragma unroll
                for (int mt = 0; mt < 2; mt++) {
                    acc[mt][nt] = __builtin_amdgcn_mfma_f32_16x16x32_bf16(afh[mt], bh, acc[mt][nt], 0, 0, 0);
                    acc[mt][nt] = __builtin_amdgcn_mfma_f32_16x16x32_bf16(afl[mt], bh, acc[mt][nt], 0, 0, 0);
                    acc[mt][nt] = __builtin_amdgcn_mfma_f32_16x16x32_bf16(afh[mt], bl, acc[mt][nt], 0, 0, 0);
                }
            }
        }
        __syncthreads();
    }
    #pragma unroll
    for (int mt = 0; mt < 2; mt++)
        #pragma unroll
        for (int reg = 0; reg < 4; reg++) {
            const int row = m0 + wr * 32 + mt * 16 + lk * 4 + reg;
            #pragma unroll
            for (int nt = 0; nt < 8; nt++) {
                const int col = n0 + wc * 128 + nt * 16 + l15;
                const float v = acc[mt][nt][reg];
                if (mode == 0) out[(size_t)row * 512 + col] = v;
                else           out[(size_t)col * 1024 + row] = v + bih[col] + bhh[col];
            }
        }
}

// ---------------------------------------------------------------------------
// k_gbt_dec: dec GEMM via bf16-split MFMA, LDS-staged. M=1024, N=512,
// K=1536 (A regions emb|h|att), tanh(+bgen) -> chunk-major dhk/dlk. Grid 32.
// ---------------------------------------------------------------------------
__global__ __launch_bounds__(256) void k_gbt_dec(const unsigned short* __restrict__ eh,
                                                 const unsigned short* __restrict__ el,
                                                 const unsigned short* __restrict__ hh,
                                                 const unsigned short* __restrict__ hl,
                                                 const unsigned short* __restrict__ ath,
                                                 const unsigned short* __restrict__ atl,
                                                 const unsigned short* __restrict__ wgh,
                                                 const unsigned short* __restrict__ wgl,
                                                 const float* __restrict__ bgen,
                                                 unsigned short* __restrict__ dhk,
                                                 unsigned short* __restrict__ dlk) {
    __shared__ __align__(16) unsigned short BhL[4][256][8];
    __shared__ __align__(16) unsigned short BlL[4][256][8];
    __shared__ __align__(16) unsigned short AhL[4][64][8];
    __shared__ __align__(16) unsigned short AlL[4][64][8];
    const int m0 = (blockIdx.x >> 1) * 64;
    const int n0 = (blockIdx.x & 1) * 256;
    const int tid = threadIdx.x;
    const int lane = tid & 63, wid = tid >> 6;
    const int wr = wid >> 1, wc = wid & 1;
    const int l15 = lane & 15, lk = lane >> 4;

    f32x4 acc[2][8];
    #pragma unroll
    for (int mt = 0; mt < 2; mt++)
        #pragma unroll
        for (int nt = 0; nt < 8; nt++) acc[mt][nt] = {0.f, 0.f, 0.f, 0.f};

    for (int kc = 0; kc < 1536; kc += 32) {
        const unsigned short *Ahp, *Alp;
        int ko;
        if (kc < 512)       { Ahp = eh;  Alp = el;  ko = kc; }
        else if (kc < 1024) { Ahp = hh;  Alp = hl;  ko = kc - 512; }
        else                { Ahp = ath; Alp = atl; ko = kc - 1024; }
        {   // B stage (row stride 1536)
            #pragma unroll
            for (int g = 0; g < 4; g++) {
                const size_t bo = (size_t)(n0 + tid) * 1536 + kc + g * 8;
                *(uint4*)&BhL[g][tid][0] = *(const uint4*)(wgh + bo);
                *(uint4*)&BlL[g][tid][0] = *(const uint4*)(wgl + bo);
            }
        }
        {   // A stage
            const int row = tid >> 2, g = tid & 3;
            const size_t ao = (size_t)(m0 + row) * 512 + ko + g * 8;
            *(uint4*)&AhL[g][row][0] = *(const uint4*)(Ahp + ao);
            *(uint4*)&AlL[g][row][0] = *(const uint4*)(Alp + ao);
        }
        __syncthreads();
        {
            bf16x8 afh[2], afl[2];
            #pragma unroll
            for (int mt = 0; mt < 2; mt++) {
                const int r = wr * 32 + mt * 16 + l15;
                afh[mt] = *(const bf16x8*)&AhL[lk][r][0];
                afl[mt] = *(const bf16x8*)&AlL[lk][r][0];
            }
            #pragma unroll
            for (int nt = 0; nt < 8; nt++) {
                const int nn = wc * 128 + nt * 16 + l15;
                bf16x8 bh = *(const bf16x8*)&BhL[lk][nn][0];
                bf16x8 bl = *(const bf16x8*)&BlL[lk][nn][0];
                #pragma unroll
                for (int mt = 0; mt < 2; mt++) {
                    acc[mt][nt] = __builtin_amdgcn_mfma_f32_16x16x32_bf16(afh[mt], bh, acc[mt][nt], 0, 0, 0);
                    acc[mt][nt] = __builtin_amdgcn_mfma_f32_16x16x32_bf16(afl[mt], bh, acc[mt][nt], 0, 0, 0);
                    acc[mt][nt] = __builtin_amdgcn_mfma_f32_16x16x32_bf16(afh[mt], bl, acc[mt][nt], 0, 0, 0);
                }
            }
        }
        __syncthreads();
    }
    #pragma unroll
    for (int mt = 0; mt < 2; mt++)
        #pragma unroll
        for (int reg = 0; reg < 4; reg++) {
            const int row = m0 + wr * 32 + mt * 16 + lk * 4 + reg;
            #pragma unroll
            for (int nt = 0; nt < 8; nt++) {
                const int col = n0 + wc * 128 + nt * 16 + l15;
                const float v = tanhf(acc[mt][nt][reg] + bgen[col]);
                const unsigned short hb = f2bf(v);
                const unsigned short lb = f2bf(v - bf2f(hb));
                const size_t ca = (size_t)(col >> 5) * 32768 + (size_t)(row >> 6) * 2048
                                + (size_t)(row & 63) * 32 + (col & 31);
                dhk[ca] = hb;
                dlk[ca] = lb;
            }
        }
}

// ---------------------------------------------------------------------------
// k_g0 (fp32 fallback)
// ---------------------------------------------------------------------------
__global__ __launch_bounds__(256) void k_g0(const int* __restrict__ tgt_in,
                                            const float* __restrict__ emb,
                                            const float* __restrict__ Wih,
                                            const float* __restrict__ bih,
                                            const float* __restrict__ bhh,
                                            float* __restrict__ G0T) {
    __shared__ float a_s[32][66];
    __shared__ float w_s[32][130];
    const int tid = threadIdx.x;
    const int m0 = blockIdx.x * 64, n0 = blockIdx.y * 128;
    const int mq = tid >> 5, nq = tid & 31;
    float acc[8][4] = {};
    for (int k0 = 0; k0 < 512; k0 += 32) {
        {
            const int mm = tid >> 2, kq = tid & 3, kk = kq * 8;
            const float* row = emb + (size_t)tgt_in[m0 + mm] * E_ + k0 + kk;
            float4 v0 = *(const float4*)(row);
            float4 v1 = *(const float4*)(row + 4);
            a_s[kk + 0][mm] = v0.x; a_s[kk + 1][mm] = v0.y;
            a_s[kk + 2][mm] = v0.z; a_s[kk + 3][mm] = v0.w;
            a_s[kk + 4][mm] = v1.x; a_s[kk + 5][mm] = v1.y;
            a_s[kk + 6][mm] = v1.z; a_s[kk + 7][mm] = v1.w;
        }
        {
            const int nn = tid >> 1, kq = tid & 1, kk = kq * 16;
            const float* row = Wih + (size_t)(n0 + nn) * 1024 + k0 + kk;
            #pragma unroll
            for (int u = 0; u < 4; u++) {
                float4 v = *(const float4*)(row + u * 4);
                w_s[kk + u * 4 + 0][nn] = v.x; w_s[kk + u * 4 + 1][nn] = v.y;
                w_s[kk + u * 4 + 2][nn] = v.z; w_s[kk + u * 4 + 3][nn] = v.w;
            }
        }
        __syncthreads();
        for (int k = 0; k < 32; k++) {
            float a[8], wv[4];
            #pragma unroll
            for (int i = 0; i < 8; i++) a[i] = a_s[k][mq + 8 * i];
            #pragma unroll
            for (int p = 0; p < 4; p++) wv[p] = w_s[k][nq + 32 * p];
            #pragma unroll
            for (int i = 0; i < 8; i++)
                #pragma unroll
                for (int p = 0; p < 4; p++) acc[i][p] += a[i] * wv[p];
        }
        __syncthreads();
    }
    #pragma unroll
    for (int i = 0; i < 8; i++) {
        const int m = m0 + mq + 8 * i;
        #pragma unroll
        for (int p = 0; p < 4; p++) {
            const int n = n0 + nq + 32 * p;
            G0T[(size_t)n * 1024 + m] = acc[i][p] + bih[n] + bhh[n];
        }
    }
}

// ---------------------------------------------------------------------------
// k_u (fp32 fallback)
// ---------------------------------------------------------------------------
__global__ __launch_bounds__(256) void k_u(const float* __restrict__ src,
                                           const float* __restrict__ Wattn,
                                           float* __restrict__ U) {
    __shared__ float a_s[32][66];
    __shared__ float w_s[32][130];
    const int tid = threadIdx.x;
    const int m0 = blockIdx.x * 64, n0 = blockIdx.y * 128;
    const int mq = tid >> 5, nq = tid & 31;
    float acc[8][4] = {};
    for (int k0 = 0; k0 < 512; k0 += 32) {
        {
            const int mm = tid >> 2, kq = tid & 3, kk = kq * 8;
            const float* row = src + (size_t)(m0 + mm) * 512 + k0 + kk;
            float4 v0 = *(const float4*)(row);
            float4 v1 = *(const float4*)(row + 4);
            a_s[kk + 0][mm] = v0.x; a_s[kk + 1][mm] = v0.y;
            a_s[kk + 2][mm] = v0.z; a_s[kk + 3][mm] = v0.w;
            a_s[kk + 4][mm] = v1.x; a_s[kk + 5][mm] = v1.y;
            a_s[kk + 6][mm] = v1.z; a_s[kk + 7][mm] = v1.w;
        }
        {
            const int nn = tid >> 1, kq = tid & 1, kk = kq * 16;
            const float* row = Wattn + (size_t)(n0 + nn) * 1024 + k0 + kk;
            #pragma unroll
            for (int u = 0; u < 4; u++) {
                float4 v = *(const float4*)(row + u * 4);
                w_s[kk + u * 4 + 0][nn] = v.x; w_s[kk + u * 4 + 1][nn] = v.y;
                w_s[kk + u * 4 + 2][nn] = v.z; w_s[kk + u * 4 + 3][nn] = v.w;
            }
        }
        __syncthreads();
        for (int k = 0; k < 32; k++) {
            float a[8], wv[4];
            #pragma unroll
            for (int i = 0; i < 8; i++) a[i] = a_s[k][mq + 8 * i];
            #pragma unroll
            for (int p = 0; p < 4; p++) wv[p] = w_s[k][nq + 32 * p];
            #pragma unroll
            for (int i = 0; i < 8; i++)
                #pragma unroll
                for (int p = 0; p < 4; p++) acc[i][p] += a[i] * wv[p];
        }
        __syncthreads();
    }
    #pragma unroll
    for (int i = 0; i < 8; i++) {
        const int m = m0 + mq + 8 * i;
        #pragma unroll
        for (int p = 0; p < 4; p++)
            U[(size_t)m * 512 + n0 + nq + 32 * p] = acc[i][p];
    }
}

// ---------------------------------------------------------------------------
// k_tr: WaRT[k][j] = W_attn[j][512+k]
// ---------------------------------------------------------------------------
__global__ __launch_bounds__(256) void k_tr(const float* __restrict__ Wattn,
                                            float* __restrict__ WaRT) {
    __shared__ float t_s[32][33];
    const int tid = threadIdx.x;
    const int bx = blockIdx.x, by = blockIdx.y;
    {
        const int jj = tid >> 3, kq = (tid & 7) * 4;
        float4 v = *(const float4*)(Wattn + (size_t)(by * 32 + jj) * 1024 + 512 + bx * 32 + kq);
        t_s[jj][kq + 0] = v.x; t_s[jj][kq + 1] = v.y;
        t_s[jj][kq + 2] = v.z; t_s[jj][kq + 3] = v.w;
    }
    __syncthreads();
    {
        const int kk = tid >> 3, jq = (tid & 7) * 4;
        float4 w;
        w.x = t_s[jq + 0][kk]; w.y = t_s[jq + 1][kk];
        w.z = t_s[jq + 2][kk]; w.w = t_s[jq + 3][kk];
        *(float4*)(WaRT + (size_t)(bx * 32 + kk) * 512 + by * 32 + jq) = w;
    }
}

// ---------------------------------------------------------------------------
// k_wconv: Wread fp32 -> bf16 hi/lo, chunk-major with BAKED bank swizzle.
// ---------------------------------------------------------------------------
__global__ __launch_bounds__(256) void k_wconv(const float* __restrict__ Wread,
                                               unsigned short* __restrict__ whk,
                                               unsigned short* __restrict__ wlk) {
    const size_t q = (size_t)blockIdx.x * 256 + threadIdx.x;
    const size_t k8 = q * 8;
    const int n = (int)(k8 >> 9);
    const int k = (int)(k8 & 511);
    if (n >= VP_) return;
    uint4 h4, l4;
    if (n < V_) {
        float4 p0 = *(const float4*)(Wread + (size_t)n * 512 + k);
        float4 p1 = *(const float4*)(Wread + (size_t)n * 512 + k + 4);
        float v[8] = {p0.x, p0.y, p0.z, p0.w, p1.x, p1.y, p1.z, p1.w};
        unsigned int hb[8], lb[8];
        #pragma unroll
        for (int e = 0; e < 8; e++) {
            hb[e] = f2bf(v[e]);
            lb[e] = f2bf(v[e] - bf2f((unsigned short)hb[e]));
        }
        h4 = make_uint4(hb[0] | (hb[1] << 16), hb[2] | (hb[3] << 16),
                        hb[4] | (hb[5] << 16), hb[6] | (hb[7] << 16));
        l4 = make_uint4(lb[0] | (lb[1] << 16), lb[2] | (lb[3] << 16),
                        lb[4] | (lb[5] << 16), lb[6] | (lb[7] << 16));
    } else {
        h4 = make_uint4(0, 0, 0, 0);
        l4 = make_uint4(0, 0, 0, 0);
    }
    const int lk = (k >> 3) & 3;
    const size_t dst = (size_t)(k >> 5) * ((size_t)VP_ * 32) + (size_t)n * 32
                     + (size_t)((lk ^ ((n >> 1) & 3)) * 8);
    *(uint4*)(whk + dst) = h4;
    *(uint4*)(wlk + dst) = l4;
}

// ---------------------------------------------------------------------------
// Persistent scan (round-11 proven; + bf16-split h/att emission).
// ---------------------------------------------------------------------------
__global__ __launch_bounds__(512) void k_scan(const float* __restrict__ G0T,
                                              const float* __restrict__ U,
                                              const float* __restrict__ WaRT,
                                              const float* __restrict__ Wih,
                                              const float* __restrict__ Whh,
                                              const float* __restrict__ src,
                                              const int* __restrict__ lens,
                                              const float* __restrict__ last_cell,
                                              float* __restrict__ xT,
                                              float* __restrict__ h_b,
                                              float* __restrict__ scb,
                                              float* __restrict__ h_hist,
                                              float* __restrict__ att_hist,
                                              unsigned short* __restrict__ hh,
                                              unsigned short* __restrict__ hl,
                                              unsigned short* __restrict__ ath,
                                              unsigned short* __restrict__ atl,
                                              int pre,
                                              int* __restrict__ bar) {
    __shared__ float Wl[8 * 1024];
    __shared__ float Ul[200 * 64];
    __shared__ float red_s[2048];
    __shared__ float gate_s[256];
    __shared__ float h_s[512];
    __shared__ float al[256];
    __shared__ float pr[512];

    const int blk = blockIdx.x, tid = threadIdx.x;
    const int u0 = blk * 2;
    const int bb = blk & 31, p = blk >> 5;

    for (int f = tid; f < 2048; f += 512) {
        const int r = f >> 8, k = (f & 255) * 4;
        const int j = (r >> 1) * 512 + u0 + (r & 1);
        float4 v;
        if (k < 512) v = *(const float4*)(Wih + (size_t)j * 1024 + 512 + k);
        else         v = *(const float4*)(Whh + (size_t)j * 512 + (k - 512));
        *(float4*)&Wl[r * 1024 + k] = v;
    }
    for (int f = tid; f < 3200; f += 512) {
        const int s = f >> 4, q = (f & 15) * 4;
        *(float4*)&Ul[s * 64 + q] = *(const float4*)(U + ((size_t)bb * S_ + s) * 512 + p * 64 + q);
    }
    float creg = (tid < 64) ? last_cell[(tid & 31) * 512 + u0 + (tid >> 5)] : 0.f;
    __syncthreads();

    const int w = tid >> 6, lane = tid & 63;
    const int hf = lane >> 5, b = lane & 31;
    const int len = lens[bb];

    for (int t = 0; t < T_; t++) {
        // -------- Phase A: gates + pointwise ------------------------------
        {
            const int hoff = ((t + 1) & 1) * 512;        // slot holding h(t-1)
            const int kbase = w * 128 + hf * 64;
            const float* xp = (kbase < 512)
                ? (xT + (size_t)kbase * 32 + b)
                : (xT + (size_t)(512 + hoff + (kbase - 512)) * 32 + b);
            float acc[8] = {};
            #pragma unroll
            for (int kk = 0; kk < 64; kk += 8) {
                float xv[8];
                #pragma unroll
                for (int i = 0; i < 8; i++)
                    xv[i] = g_load(xp + (size_t)(kk + i) * 32);
                #pragma unroll
                for (int r = 0; r < 8; r++) {
                    const float* wr = &Wl[r * 1024 + kbase + kk];
                    float s0 = xv[0] * wr[0] + xv[1] * wr[1] + xv[2] * wr[2] + xv[3] * wr[3];
                    float s1 = xv[4] * wr[4] + xv[5] * wr[5] + xv[6] * wr[6] + xv[7] * wr[7];
                    acc[r] += s0 + s1;
                }
            }
            #pragma unroll
            for (int r = 0; r < 8; r++) acc[r] += __shfl_xor(acc[r], 32);
            if (hf == 0) {
                #pragma unroll
                for (int r = 0; r < 8; r++) red_s[w * 256 + r * 32 + b] = acc[r];
            }
            __syncthreads();
            if (tid < 256) {
                const int r = tid >> 5, b2 = tid & 31;
                const int j = (r >> 1) * 512 + u0 + (r & 1);
                float g = G0T[(size_t)j * 1024 + t * 32 + b2];
                #pragma unroll
                for (int ww = 0; ww < 8; ww++) g += red_s[ww * 256 + r * 32 + b2];
                gate_s[r * 32 + b2] = g;
            }
            __syncthreads();
            if (tid < 64) {
                const int ui = tid >> 5, b2 = tid & 31, u = u0 + ui;
                const float gi = gate_s[(0 + ui) * 32 + b2];
                const float gf = gate_s[(2 + ui) * 32 + b2];
                const float gg = gate_s[(4 + ui) * 32 + b2];
                const float go = gate_s[(6 + ui) * 32 + b2];
                const float cn = sigf(gf) * creg + sigf(gi) * tanhf(gg);
                const float hn = sigf(go) * tanhf(cn);
                creg = cn;
                g_store(&xT[(size_t)(512 + (t & 1) * 512 + u) * 32 + b2], hn);
                g_store(&h_b[b2 * 512 + u], hn);
                h_hist[((size_t)t * B_ + b2) * 512 + u] = hn;
                if (pre) {
                    const unsigned short hb2 = f2bf(hn);
                    const size_t ho = ((size_t)t * B_ + b2) * 512 + u;
                    hh[ho] = hb2;
                    hl[ho] = f2bf(hn - bf2f(hb2));
                }
            }
        }
        full_sync(bar, 2 * t);

        // -------- Phase B: scores -----------------------------------------
        {
            h_s[tid] = g_load(&h_b[bb * 512 + tid]);
            __syncthreads();
            for (int i = w; i < 25; i += 8) {
                const int s = p * 25 + i;
                const float* sr = src + ((size_t)bb * S_ + s) * 512;
                const float4 x0 = *(const float4*)(sr + lane * 4);
                const float4 x1 = *(const float4*)(sr + 256 + lane * 4);
                const float4 h0 = *(const float4*)(&h_s[lane * 4]);
                const float4 h1 = *(const float4*)(&h_s[256 + lane * 4]);
                float a = x0.x * h0.x + x0.y * h0.y + x0.z * h0.z + x0.w * h0.w
                        + x1.x * h1.x + x1.y * h1.y + x1.z * h1.z + x1.w * h1.w;
                #pragma unroll
                for (int mk = 1; mk < 64; mk <<= 1) a += __shfl_xor(a, mk);
                if (lane == 0) g_store(&scb[bb * 256 + s], (s < len) ? a : -INFINITY);
            }
        }
        sub_sync(bar, bb, t);

        // -------- Phase C: softmax + att slice ----------------------------
        {
            if (tid < 64) {
                const float v0 = g_load(&scb[bb * 256 + tid]);
                const float v1 = g_load(&scb[bb * 256 + 64 + tid]);
                const float v2 = g_load(&scb[bb * 256 + 128 + tid]);
                const float v3 = (tid < 8) ? g_load(&scb[bb * 256 + 192 + tid]) : -INFINITY;
                float m = fmaxf(fmaxf(v0, v1), fmaxf(v2, v3));
                #pragma unroll
                for (int mk = 1; mk < 64; mk <<= 1) m = fmaxf(m, __shfl_xor(m, mk));
                const float e0 = expf(v0 - m), e1 = expf(v1 - m), e2 = expf(v2 - m);
                const float e3 = (tid < 8) ? expf(v3 - m) : 0.f;
                float sum = (e0 + e1) + (e2 + e3);
                #pragma unroll
                for (int mk = 1; mk < 64; mk <<= 1) sum += __shfl_xor(sum, mk);
                const float inv = 1.f / sum;
                al[tid] = e0 * inv; al[64 + tid] = e1 * inv; al[128 + tid] = e2 * inv;
                if (tid < 8) al[192 + tid] = e3 * inv;
            }
            __syncthreads();
            const int jl = tid & 63, sg = tid >> 6;
            float uacc = 0.f;
            #pragma unroll 5
            for (int s = sg * 25; s < sg * 25 + 25; s++)
                uacc += al[s] * Ul[s * 64 + jl];
            const float* wc0 = WaRT + (size_t)(sg * 64) * 512 + p * 64 + jl;
            const float* hp = &h_s[sg * 64];
            float c0 = 0.f, c1 = 0.f;
            #pragma unroll 8
            for (int kk = 0; kk < 64; kk += 2) {
                c0 += hp[kk] * wc0[(size_t)kk * 512];
                c1 += hp[kk + 1] * wc0[(size_t)(kk + 1) * 512];
            }
            pr[tid] = uacc + c0 + c1;
            __syncthreads();
            if (tid < 64) {
                float tot = 0.f;
                #pragma unroll
                for (int sgg = 0; sgg < 8; sgg++) tot += pr[sgg * 64 + tid];
                const float a = tanhf(tot);
                g_store(&xT[(size_t)(p * 64 + tid) * 32 + bb], a);
                att_hist[((size_t)t * B_ + bb) * 512 + p * 64 + tid] = a;
                if (pre) {
                    const unsigned short ab = f2bf(a);
                    const size_t ao = ((size_t)t * B_ + bb) * 512 + p * 64 + tid;
                    ath[ao] = ab;
                    atl[ao] = f2bf(a - bf2f(ab));
                }
            }
        }
        full_sync(bar, 2 * t + 1);
    }
}

// ---------------------------------------------------------------------------
// k_dec (fp32 fallback)
// ---------------------------------------------------------------------------
__global__ __launch_bounds__(256) void k_dec(const int* __restrict__ tgt_in,
                                             const float* __restrict__ emb,
                                             const float* __restrict__ h_hist,
                                             const float* __restrict__ att_hist,
                                             const float* __restrict__ Wgen,
                                             const float* __restrict__ bgen,
                                             unsigned short* __restrict__ dh,
                                             unsigned short* __restrict__ dl) {
    __shared__ float a_s[32][66];
    __shared__ float w_s[32][130];
    const int tid = threadIdx.x;
    const int m0 = blockIdx.x * 64, n0 = blockIdx.y * 128;
    const int mq = tid >> 5, nq = tid & 31;
    float acc[8][4] = {};
    for (int k0 = 0; k0 < 1536; k0 += 32) {
        {
            const int mm = tid >> 2, kq = tid & 3, kk = kq * 8;
            const int m = m0 + mm;
            const float* row;
            if (k0 < 512)       row = emb + (size_t)tgt_in[m] * E_ + k0;
            else if (k0 < 1024) row = h_hist + (size_t)m * 512 + (k0 - 512);
            else                row = att_hist + (size_t)m * 512 + (k0 - 1024);
            row += kk;
            float4 v0 = *(const float4*)(row);
            float4 v1 = *(const float4*)(row + 4);
            a_s[kk + 0][mm] = v0.x; a_s[kk + 1][mm] = v0.y;
            a_s[kk + 2][mm] = v0.z; a_s[kk + 3][mm] = v0.w;
            a_s[kk + 4][mm] = v1.x; a_s[kk + 5][mm] = v1.y;
            a_s[kk + 6][mm] = v1.z; a_s[kk + 7][mm] = v1.w;
        }
        {
            const int nn = tid >> 1, kq = tid & 1, kk = kq * 16;
            const float* row = Wgen + (size_t)(n0 + nn) * 1536 + k0 + kk;
            #pragma unroll
            for (int u = 0; u < 4; u++) {
                float4 v = *(const float4*)(row + u * 4);
                w_s[kk + u * 4 + 0][nn] = v.x; w_s[kk + u * 4 + 1][nn] = v.y;
                w_s[kk + u * 4 + 2][nn] = v.z; w_s[kk + u * 4 + 3][nn] = v.w;
            }
        }
        __syncthreads();
        for (int k = 0; k < 32; k++) {
            float a[8], wv[4];
            #pragma unroll
            for (int i = 0; i < 8; i++) a[i] = a_s[k][mq + 8 * i];
            #pragma unroll
            for (int pq = 0; pq < 4; pq++) wv[pq] = w_s[k][nq + 32 * pq];
            #pragma unroll
            for (int i = 0; i < 8; i++)
                #pragma unroll
                for (int pq = 0; pq < 4; pq++) acc[i][pq] += a[i] * wv[pq];
        }
        __syncthreads();
    }
    #pragma unroll
    for (int i = 0; i < 8; i++) {
        const int m = m0 + mq + 8 * i;
        #pragma unroll
        for (int pq = 0; pq < 4; pq++) {
            const int n = n0 + nq + 32 * pq;
            const float v = tanhf(acc[i][pq] + bgen[n]);
            const unsigned short hb = f2bf(v);
            dh[(size_t)m * 512 + n] = hb;
            dl[(size_t)m * 512 + n] = f2bf(v - bf2f(hb));
        }
    }
}

// ===========================================================================
// k_read_pre (round-11 proven): B via global_load_lds from pre-swizzled
// chunk-major whk/wlk; A-frags per-lane direct from chunk-major dhk/dlk.
// ===========================================================================
__global__ __launch_bounds__(256) void k_read_pre(const unsigned short* __restrict__ dhk,
                                                  const unsigned short* __restrict__ dlk,
                                                  const unsigned short* __restrict__ whk,
                                                  const unsigned short* __restrict__ wlk,
                                                  const int* __restrict__ tgt_out,
                                                  float4* __restrict__ part,
                                                  float* __restrict__ tgt_logit) {
    __shared__ __align__(16) unsigned short BhL[8192];   // 16 KB
    __shared__ __align__(16) unsigned short BlL[8192];   // 16 KB
    __shared__ float ep_max[64][2];
    __shared__ int   ep_idx[64][2];
    __shared__ float ep_fin[64];
    __shared__ int   ep_fidx[64];
    __shared__ float ep_sum[64][2];

    const int xcd = blockIdx.x & 7;
    const int idx = blockIdx.x >> 3;
    const int mi  = idx & 15;
    const int group = idx >> 4;
    const int ch = group * 8 + xcd;
    if (ch >= NCH) return;
    const int m0 = mi * 64, n0 = ch * 256;

    const int tid = threadIdx.x;
    const int lane = tid & 63, wid = tid >> 6;
    const int wr = wid >> 1, wc = wid & 1;
    const int l15 = lane & 15, lk = lane >> 4;

    f32x4 acc[2][8];
    #pragma unroll
    for (int mt = 0; mt < 2; mt++)
        #pragma unroll
        for (int nt = 0; nt < 8; nt++) acc[mt][nt] = {0.f, 0.f, 0.f, 0.f};

    const unsigned short* bh_src = whk + (size_t)n0 * 32;
    const unsigned short* bl_src = wlk + (size_t)n0 * 32;
    const unsigned short* ah_base = dhk + (size_t)(m0 >> 6) * 2048 + lk * 8;
    const unsigned short* al_base = dlk + (size_t)(m0 >> 6) * 2048 + lk * 8;

    for (int kc = 0; kc < 16; kc++) {
        {
            const size_t cb = (size_t)kc * ((size_t)VP_ * 32);
            const char* gh = (const char*)(bh_src + cb);
            const char* gl = (const char*)(bl_src + cb);
            #pragma unroll
            for (int c = 0; c < 4; c++) {
                const int ob = wid * 4096 + c * 1024;
                async16((char*)BhL + ob, gh + ob + lane * 16);
                async16((char*)BlL + ob, gl + ob + lane * 16);
            }
        }
        bf16x8 afh[2], afl[2];
        {
            const unsigned short* ah = ah_base + (size_t)kc * 32768;
            const unsigned short* al = al_base + (size_t)kc * 32768;
            #pragma unroll
            for (int mt = 0; mt < 2; mt++) {
                const int r = wr * 32 + mt * 16 + l15;
                afh[mt] = *(const bf16x8*)(ah + r * 32);
                afl[mt] = *(const bf16x8*)(al + r * 32);
            }
        }
        __syncthreads();
        #pragma unroll
        for (int nt = 0; nt < 8; nt++) {
            const int nn = wc * 128 + nt * 16 + l15;
            const int bo = nn * 32 + ((lk ^ ((nn >> 1) & 3)) * 8);
            bf16x8 bh = *(const bf16x8*)&BhL[bo];
            bf16x8 bl = *(const bf16x8*)&BlL[bo];
            #pragma unroll
            for (int mt = 0; mt < 2; mt++) {
                acc[mt][nt] = __builtin_amdgcn_mfma_f32_16x16x32_bf16(afh[mt], bh, acc[mt][nt], 0, 0, 0);
                acc[mt][nt] = __builtin_amdgcn_mfma_f32_16x16x32_bf16(afl[mt], bh, acc[mt][nt], 0, 0, 0);
                acc[mt][nt] = __builtin_amdgcn_mfma_f32_16x16x32_bf16(afh[mt], bl, acc[mt][nt], 0, 0, 0);
            }
        }
        __syncthreads();
    }

    #pragma unroll
    for (int mt = 0; mt < 2; mt++)
        #pragma unroll
        for (int reg = 0; reg < 4; reg++) {
            float bv = -INFINITY; int bi = 0x7fffffff;
            #pragma unroll
            for (int nt = 0; nt < 8; nt++) {
                const int n = n0 + wc * 128 + nt * 16 + l15;
                const float v = (n < V_) ? acc[mt][nt][reg] : -INFINITY;
                if (v > bv || (v == bv && n < bi)) { bv = v; bi = n; }
            }
            #pragma unroll
            for (int mk = 1; mk < 16; mk <<= 1) {
                const float ov = __shfl_xor(bv, mk);
                const int oi = __shfl_xor(bi, mk);
                if (ov > bv || (ov == bv && oi < bi)) { bv = ov; bi = oi; }
            }
            if (l15 == 0) {
                const int rl = wr * 32 + mt * 16 + lk * 4 + reg;
                ep_max[rl][wc] = bv; ep_idx[rl][wc] = bi;
            }
        }
    __syncthreads();
    if (tid < 64) {
        const float a = ep_max[tid][0], b = ep_max[tid][1];
        const int ia = ep_idx[tid][0], ib = ep_idx[tid][1];
        const bool tb = (b > a) || (b == a && ib < ia);
        ep_fin[tid] = tb ? b : a; ep_fidx[tid] = tb ? ib : ia;
    }
    __syncthreads();
    #pragma unroll
    for (int mt = 0; mt < 2; mt++)
        #pragma unroll
        for (int reg = 0; reg < 4; reg++) {
            const int rl = wr * 32 + mt * 16 + lk * 4 + reg;
            const float M = ep_fin[rl];
            const int rel = tgt_out[m0 + rl] - n0;
            float se = 0.f;
            #pragma unroll
            for (int nt = 0; nt < 8; nt++) {
                const int nl = wc * 128 + nt * 16 + l15;
                if (n0 + nl < V_) {
                    const float v = acc[mt][nt][reg];
                    se += expf(v - M);
                    if (nl == rel) tgt_logit[m0 + rl] = v;
                }
            }
            #pragma unroll
            for (int mk = 1; mk < 16; mk <<= 1) se += __shfl_xor(se, mk);
            if (l15 == 0) ep_sum[rl][wc] = se;
        }
    __syncthreads();
    if (tid < 64) {
        part[(size_t)(m0 + tid) * NCH + ch] =
            make_float4(ep_fin[tid], ep_sum[tid][0] + ep_sum[tid][1],
                        __int_as_float(ep_fidx[tid]), 0.f);
    }
}

// ---------------------------------------------------------------------------
// k_read (fallback: in-kernel conversion, row-major dh/dl, grid 3200)
// ---------------------------------------------------------------------------
__global__ __launch_bounds__(256) void k_read(const unsigned short* __restrict__ dh,
                                              const unsigned short* __restrict__ dl,
                                              const float* __restrict__ Wread,
                                              const int* __restrict__ tgt_out,
                                              float4* __restrict__ part,
                                              float* __restrict__ tgt_logit) {
    __shared__ __align__(16) unsigned short Bh[4][256][8];
    __shared__ __align__(16) unsigned short Bl[4][256][8];
    __shared__ __align__(16) unsigned short Ah[4][64][8];
    __shared__ __align__(16) unsigned short Alo[4][64][8];
    __shared__ float ep_max[64][2];
    __shared__ int   ep_idx[64][2];
    __shared__ float ep_fin[64];
    __shared__ int   ep_fidx[64];
    __shared__ float ep_sum[64][2];

    const int xcd = blockIdx.x & 7;
    const int idx = blockIdx.x >> 3;
    const int mi  = idx & 15;
    const int group = idx >> 4;
    const int ch = group * 8 + xcd;
    if (ch >= NCH) return;
    const int m0 = mi * 64, n0 = ch * 256;

    const int tid = threadIdx.x;
    const int lane = tid & 63, wid = tid >> 6;
    const int wr = wid >> 1, wc = wid & 1;
    const int l15 = lane & 15, lk = lane >> 4;

    f32x4 acc[2][8];
    #pragma unroll
    for (int mt = 0; mt < 2; mt++)
        #pragma unroll
        for (int nt = 0; nt < 8; nt++) acc[mt][nt] = {0.f, 0.f, 0.f, 0.f};

    for (int kc = 0; kc < 512; kc += 32) {
        {
            const int n = n0 + tid;
            const float* row = Wread + (size_t)n * 512 + kc;
            #pragma unroll
            for (int g = 0; g < 4; g++) {
                uint4 h4, l4;
                if (n < V_) {
                    float4 p0 = *(const float4*)(row + g * 8);
                    float4 p1 = *(const float4*)(row + g * 8 + 4);
                    float v[8] = {p0.x, p0.y, p0.z, p0.w, p1.x, p1.y, p1.z, p1.w};
                    unsigned int hb[8], lb[8];
                    #pragma unroll
                    for (int e = 0; e < 8; e++) {
                        hb[e] = f2bf(v[e]);
                        lb[e] = f2bf(v[e] - bf2f((unsigned short)hb[e]));
                    }
                    h4 = make_uint4(hb[0] | (hb[1] << 16), hb[2] | (hb[3] << 16),
                                    hb[4] | (hb[5] << 16), hb[6] | (hb[7] << 16));
                    l4 = make_uint4(lb[0] | (lb[1] << 16), lb[2] | (lb[3] << 16),
                                    lb[4] | (lb[5] << 16), lb[6] | (lb[7] << 16));
                } else {
                    h4 = make_uint4(0, 0, 0, 0);
                    l4 = make_uint4(0, 0, 0, 0);
                }
                *(uint4*)&Bh[g][tid][0] = h4;
                *(uint4*)&Bl[g][tid][0] = l4;
            }
        }
        {
            const int row = tid >> 2, g = tid & 3;
            *(uint4*)&Ah[g][row][0]  = *(const uint4*)(dh + (size_t)(m0 + row) * 512 + kc + g * 8);
            *(uint4*)&Alo[g][row][0] = *(const uint4*)(dl + (size_t)(m0 + row) * 512 + kc + g * 8);
        }
        __syncthreads();
        {
            bf16x8 afh[2], afl[2];
            #pragma unroll
            for (int mt = 0; mt < 2; mt++) {
                const int r = wr * 32 + mt * 16 + l15;
                afh[mt] = *(const bf16x8*)&Ah[lk][r][0];
                afl[mt] = *(const bf16x8*)&Alo[lk][r][0];
            }
            #pragma unroll
            for (int nt = 0; nt < 8; nt++) {
                const int nn = wc * 128 + nt * 16 + l15;
                bf16x8 bh = *(const bf16x8*)&Bh[lk][nn][0];
                bf16x8 bl = *(const bf16x8*)&Bl[lk][nn][0];
                #pragma unroll
                for (int mt = 0; mt < 2; mt++) {
                    acc[mt][nt] = __builtin_amdgcn_mfma_f32_16x16x32_bf16(afh[mt], bh, acc[mt][nt], 0, 0, 0);
                    acc[mt][nt] = __builtin_amdgcn_mfma_f32_16x16x32_bf16(afl[mt], bh, acc[mt][nt], 0, 0, 0);
                    acc[mt][nt] = __builtin_amdgcn_mfma_f32_16x16x32_bf16(afh[mt], bl, acc[mt][nt], 0, 0, 0);
                }
            }
        }
        __syncthreads();
    }

    #pragma unroll
    for (int mt = 0; mt < 2; mt++)
        #pragma unroll
        for (int reg = 0; reg < 4; reg++) {
            float bv = -INFINITY; int bi = 0x7fffffff;
            #pragma unroll
            for (int nt = 0; nt < 8; nt++) {
                const int n = n0 + wc * 128 + nt * 16 + l15;
                const float v = (n < V_) ? acc[mt][nt][reg] : -INFINITY;
                if (v > bv || (v == bv && n < bi)) { bv = v; bi = n; }
            }
            #pragma unroll
            for (int mk = 1; mk < 16; mk <<= 1) {
                const float ov = __shfl_xor(bv, mk);
                const int oi = __shfl_xor(bi, mk);
                if (ov > bv || (ov == bv && oi < bi)) { bv = ov; bi = oi; }
            }
            if (l15 == 0) {
                const int rl = wr * 32 + mt * 16 + lk * 4 + reg;
                ep_max[rl][wc] = bv; ep_idx[rl][wc] = bi;
            }
        }
    __syncthreads();
    if (tid < 64) {
        const float a = ep_max[tid][0], b = ep_max[tid][1];
        const int ia = ep_idx[tid][0], ib = ep_idx[tid][1];
        const bool tb = (b > a) || (b == a && ib < ia);
        ep_fin[tid] = tb ? b : a; ep_fidx[tid] = tb ? ib : ia;
    }
    __syncthreads();
    #pragma unroll
    for (int mt = 0; mt < 2; mt++)
        #pragma unroll
        for (int reg = 0; reg < 4; reg++) {
            const int rl = wr * 32 + mt * 16 + lk * 4 + reg;
            const float M = ep_fin[rl];
            const int rel = tgt_out[m0 + rl] - n0;
            float se = 0.f;
            #pragma unroll
            for (int nt = 0; nt < 8; nt++) {
                const int nl = wc * 128 + nt * 16 + l15;
                if (n0 + nl < V_) {
                    const float v = acc[mt][nt][reg];
                    se += expf(v - M);
                    if (nl == rel) tgt_logit[m0 + rl] = v;
                }
            }
            #pragma unroll
            for (int mk = 1; mk < 16; mk <<= 1) se += __shfl_xor(se, mk);
            if (l15 == 0) ep_sum[rl][wc] = se;
        }
    __syncthreads();
    if (tid < 64) {
        part[(size_t)(m0 + tid) * NCH + ch] =
            make_float4(ep_fin[tid], ep_sum[tid][0] + ep_sum[tid][1],
                        __int_as_float(ep_fidx[tid]), 0.f);
    }
}

// ---------------------------------------------------------------------------
// k_merge: combine chunk partials -> loss + argmax
// ---------------------------------------------------------------------------
__global__ __launch_bounds__(256) void k_merge(const float4* __restrict__ part,
                                               const float* __restrict__ tgt_logit,
                                               const int* __restrict__ tgt_out,
                                               float* __restrict__ out) {
    const int tid = threadIdx.x;
    const int w = tid >> 6, lane = tid & 63;
    const int row = blockIdx.x * 4 + w;
    float bm = -INFINITY; int bi = 0x7fffffff;
    for (int ch = lane; ch < NCH; ch += 64) {
        const float4 p = part[(size_t)row * NCH + ch];
        const int pi = __float_as_int(p.z);
        if (p.x > bm || (p.x == bm && pi < bi)) { bm = p.x; bi = pi; }
    }
    #pragma unroll
    for (int mk = 1; mk < 64; mk <<= 1) {
        const float ov = __shfl_xor(bm, mk);
        const int oi = __shfl_xor(bi, mk);
        if (ov > bm || (ov == bm && oi < bi)) { bm = ov; bi = oi; }
    }
    float sum = 0.f;
    for (int ch = lane; ch < NCH; ch += 64) {
        const float4 p = part[(size_t)row * NCH + ch];
        sum += p.y * expf(p.x - bm);
    }
    #pragma unroll
    for (int mk = 1; mk < 64; mk <<= 1) sum += __shfl_xor(sum, mk);
    if (lane == 0) {
        const float lse = bm + logf(sum);
        const int tg = tgt_out[row];
        const float loss = (tg != 0) ? (lse - tgt_logit[row]) : 0.f;
        out[row] = loss;
        out[1024 + row] = (float)bi;
    }
}

// ---------------------------------------------------------------------------
extern "C" void kernel_launch(void* const* d_in, const int* in_sizes, int n_in,
                              void* d_out, int out_size, void* d_ws, size_t ws_size,
                              hipStream_t stream) {
    const int* tgt_in = (const int*)d_in[0];
    const int* tgt_out = (const int*)d_in[1];
    const int* src_lens = (const int*)d_in[2];
    const float* src = (const float*)d_in[3];
    const float* last_state = (const float*)d_in[4];
    const float* last_cell = (const float*)d_in[5];
    const float* emb = (const float*)d_in[6];
    const float* Wih = (const float*)d_in[7];
    const float* Whh = (const float*)d_in[8];
    const float* bih = (const float*)d_in[9];
    const float* bhh = (const float*)d_in[10];
    const float* Wattn = (const float*)d_in[11];
    const float* Wgen = (const float*)d_in[12];
    const float* bgen = (const float*)d_in[13];
    const float* Wread = (const float*)d_in[14];
    float* out = (float*)d_out;

    float* ws = (float*)d_ws;
    float* G0T      = ws;                    // 2,097,152 f
    float* U        = G0T + 2097152;         // 3,276,800 f
    float* WaRT     = U + 3276800;           // 262,144 f
    unsigned short* dh  = (unsigned short*)(WaRT + 262144);  // 524,288 u16
    unsigned short* dl  = dh + 524288;
    unsigned short* dhk = dl + 524288;       // chunk-major
    unsigned short* dlk = dhk + 524288;
    float* h_hist   = (float*)(dlk + 524288);
    float* att_hist = h_hist + 524288;
    float* xT       = att_hist + 524288;     // 49,152 f
    float* h_b      = xT + 49152;            // 16,384 f
    float* scb      = h_b + 16384;           // 8,192 f
    float4* part    = (float4*)(scb + 8192); // 200,704 float4
    float* tgtl     = ((float*)part) + 802816; // 1,024 f
    int* bar        = (int*)(tgtl + 1024);     // 2,048 ints
    unsigned short* whk = (unsigned short*)(bar + 2048);   // VP_*512 u16
    unsigned short* wlk = whk + (size_t)VP_ * 512;
    // prologue/dec bf16 operands
    unsigned short* sh    = wlk + (size_t)VP_ * 512;  // 3,276,800 u16
    unsigned short* sl    = sh + 3276800;
    unsigned short* wah   = sl + 3276800;             // 262,144
    unsigned short* wal   = wah + 262144;
    unsigned short* wih_h = wal + 262144;             // 1,048,576
    unsigned short* wih_l = wih_h + 1048576;
    unsigned short* eh    = wih_l + 1048576;          // 524,288
    unsigned short* el    = eh + 524288;
    unsigned short* wgh   = el + 524288;              // 786,432
    unsigned short* wgl   = wgh + 786432;
    unsigned short* hh    = wgl + 786432;             // 524,288
    unsigned short* hl    = hh + 524288;
    unsigned short* ath   = hl + 524288;
    unsigned short* atl   = ath + 524288;

    const size_t need = (size_t)((char*)(atl + 524288) - (char*)ws);
    const int pre = (ws_size >= need) ? 1 : 0;

    hipMemsetAsync(bar, 0, 8192, stream);

    k_init<<<64, 256, 0, stream>>>(last_state, xT);
    if (pre) {
        k_cvt<<<(CVT_R4 + 255) / 256, 256, 0, stream>>>(src, Wattn, Wih, emb, Wgen, tgt_in,
                                                        sh, sl, wah, wal, wih_h, wih_l,
                                                        eh, el, wgh, wgl);
        k_gbt<<<200, 256, 0, stream>>>(sh, sl, wah, wal, nullptr, nullptr, U, 2, 0);
        k_gbt<<<128, 256, 0, stream>>>(eh, el, wih_h, wih_l, bih, bhh, G0T, 8, 1);
    } else {
        k_g0<<<dim3(16, 16), 256, 0, stream>>>(tgt_in, emb, Wih, bih, bhh, G0T);
        k_u<<<dim3(100, 4), 256, 0, stream>>>(src, Wattn, U);
    }
    k_tr<<<dim3(16, 16), 256, 0, stream>>>(Wattn, WaRT);
    if (pre)
        k_wconv<<<12544, 256, 0, stream>>>(Wread, whk, wlk);

    k_scan<<<256, 512, 0, stream>>>(G0T, U, WaRT, Wih, Whh, src, src_lens, last_cell,
                                    xT, h_b, scb, h_hist, att_hist,
                                    hh, hl, ath, atl, pre, bar);

    if (pre) {
        k_gbt_dec<<<32, 256, 0, stream>>>(eh, el, hh, hl, ath, atl, wgh, wgl, bgen, dhk, dlk);
        k_read_pre<<<3200, 256, 0, stream>>>(dhk, dlk, whk, wlk, tgt_out, part, tgtl);
    } else {
        k_dec<<<dim3(16, 4), 256, 0, stream>>>(tgt_in, emb, h_hist, att_hist, Wgen, bgen, dh, dl);
        k_read<<<3200, 256, 0, stream>>>(dh, dl, Wread, tgt_out, part, tgtl);
    }
    k_merge<<<256, 256, 0, stream>>>(part, tgtl, tgt_out, out);
}

// Round 17
// 875.118 us; speedup vs baseline: 1.4378x; 1.0294x over previous
//
#include <hip/hip_runtime.h>
#include <math.h>

#define T_ 32
#define B_ 32
#define S_ 200
#define E_ 512
#define H_ 512
#define V_ 50000
#define VP_ 50176   // padded rows for chunk-major bf16 W
#define G4_ 2048
#define NCH 196     // ceil(50000/256)

using bf16x8 = __attribute__((ext_vector_type(8))) __bf16;
using f32x4  = __attribute__((ext_vector_type(4))) float;

__device__ __forceinline__ float sigf(float x) { return 1.f / (1.f + expf(-x)); }

__device__ __forceinline__ unsigned short f2bf(float v) {
    unsigned int x = __float_as_uint(v);
    return (unsigned short)((x + 0x7FFFu + ((x >> 16) & 1u)) >> 16);
}
__device__ __forceinline__ float bf2f(unsigned short b) {
    return __uint_as_float(((unsigned int)b) << 16);
}

// async global->LDS 16B copy
__device__ __forceinline__ void async16(void* lds, const void* g) {
    __builtin_amdgcn_global_load_lds(
        (const __attribute__((address_space(1))) unsigned int*)g,
        (__attribute__((address_space(3))) unsigned int*)lds, 16, 0, 0);
}

// Coherent LLC-level exchange (relaxed agent atomics -> sc1 load/store)
__device__ __forceinline__ void g_store(float* p, float v) {
    __hip_atomic_store(p, v, __ATOMIC_RELAXED, __HIP_MEMORY_SCOPE_AGENT);
}
__device__ __forceinline__ float g_load(const float* p) {
    return __hip_atomic_load(p, __ATOMIC_RELAXED, __HIP_MEMORY_SCOPE_AGENT);
}

// ---------------------------------------------------------------------------
// Fence-free grid barrier (proven rounds 5-16).
// ---------------------------------------------------------------------------
__device__ __forceinline__ void full_sync(int* bar, int ep) {
    __syncthreads();
    if (threadIdx.x == 0) {
        const int g = blockIdx.x & 7;
        int a = __hip_atomic_fetch_add(&bar[g * 32], 1, __ATOMIC_RELAXED, __HIP_MEMORY_SCOPE_AGENT);
        if (a == ep * 32 + 31) {
            int q = __hip_atomic_fetch_add(&bar[256], 1, __ATOMIC_RELAXED, __HIP_MEMORY_SCOPE_AGENT);
            if (q == ep * 8 + 7) {
                #pragma unroll
                for (int i = 0; i < 8; i++)
                    __hip_atomic_store(&bar[288 + i * 32], ep + 1, __ATOMIC_RELAXED, __HIP_MEMORY_SCOPE_AGENT);
            }
        }
        while (__hip_atomic_load(&bar[288 + g * 32], __ATOMIC_RELAXED, __HIP_MEMORY_SCOPE_AGENT) < ep + 1)
            __builtin_amdgcn_s_sleep(1);
    }
    __syncthreads();
}

__device__ __forceinline__ void sub_sync(int* bar, int bb, int t) {
    __syncthreads();
    if (threadIdx.x == 0) {
        __hip_atomic_fetch_add(&bar[544 + bb * 32], 1, __ATOMIC_RELAXED, __HIP_MEMORY_SCOPE_AGENT);
        while (__hip_atomic_load(&bar[544 + bb * 32], __ATOMIC_RELAXED, __HIP_MEMORY_SCOPE_AGENT) < (t + 1) * 8)
            __builtin_amdgcn_s_sleep(1);
    }
    __syncthreads();
}

// ---------------------------------------------------------------------------
// k_init: xT rows 0..511 att=0; rows 1024..1535 = last_state^T (h slot 1).
// ---------------------------------------------------------------------------
__global__ __launch_bounds__(256) void k_init(const float* __restrict__ last_state,
                                              float* __restrict__ xT) {
    const int f = blockIdx.x * 256 + threadIdx.x;   // 0..16383
    xT[f] = 0.f;
    const int k = f >> 5, b = f & 31;
    xT[32768 + f] = last_state[b * 512 + k];
}

// ---------------------------------------------------------------------------
// k_cvt: fp32 -> bf16 hi/lo for prologue/dec GEMM operands.
// ---------------------------------------------------------------------------
#define CVT_R0 819200
#define CVT_R1 (CVT_R0 + 65536)
#define CVT_R2 (CVT_R1 + 262144)
#define CVT_R3 (CVT_R2 + 131072)
#define CVT_R4 (CVT_R3 + 196608)
__global__ __launch_bounds__(256) void k_cvt(const float* __restrict__ src,
                                             const float* __restrict__ Wattn,
                                             const float* __restrict__ Wih,
                                             const float* __restrict__ emb,
                                             const float* __restrict__ Wgen,
                                             const int* __restrict__ tgt_in,
                                             unsigned short* __restrict__ sh,
                                             unsigned short* __restrict__ sl,
                                             unsigned short* __restrict__ wah,
                                             unsigned short* __restrict__ wal,
                                             unsigned short* __restrict__ wih_h,
                                             unsigned short* __restrict__ wih_l,
                                             unsigned short* __restrict__ eh,
                                             unsigned short* __restrict__ el,
                                             unsigned short* __restrict__ wgh,
                                             unsigned short* __restrict__ wgl) {
    const int u = blockIdx.x * 256 + threadIdx.x;
    if (u >= CVT_R4) return;
    const float* sp;
    unsigned short *dh_, *dl_;
    size_t doff;
    if (u < CVT_R0) {
        sp = src + (size_t)u * 4;
        dh_ = sh; dl_ = sl; doff = (size_t)u * 4;
    } else if (u < CVT_R1) {
        const int idx = u - CVT_R0;
        const int k4 = idx & 127, n = idx >> 7;
        sp = Wattn + (size_t)n * 1024 + k4 * 4;
        dh_ = wah; dl_ = wal; doff = (size_t)n * 512 + k4 * 4;
    } else if (u < CVT_R2) {
        const int idx = u - CVT_R1;
        const int k4 = idx & 127, j = idx >> 7;
        sp = Wih + (size_t)j * 1024 + k4 * 4;
        dh_ = wih_h; dl_ = wih_l; doff = (size_t)j * 512 + k4 * 4;
    } else if (u < CVT_R3) {
        const int idx = u - CVT_R2;
        const int k4 = idx & 127, m = idx >> 7;
        sp = emb + (size_t)tgt_in[m] * 512 + k4 * 4;
        dh_ = eh; dl_ = el; doff = (size_t)m * 512 + k4 * 4;
    } else {
        const int idx = u - CVT_R3;
        const int n = idx / 384, k4 = idx - n * 384;
        sp = Wgen + (size_t)n * 1536 + k4 * 4;
        dh_ = wgh; dl_ = wgl; doff = (size_t)n * 1536 + k4 * 4;
    }
    const float4 v = *(const float4*)sp;
    const float vv[4] = {v.x, v.y, v.z, v.w};
    unsigned int hb[4], lb[4];
    #pragma unroll
    for (int e = 0; e < 4; e++) {
        hb[e] = f2bf(vv[e]);
        lb[e] = f2bf(vv[e] - bf2f((unsigned short)hb[e]));
    }
    *(uint2*)(dh_ + doff) = make_uint2(hb[0] | (hb[1] << 16), hb[2] | (hb[3] << 16));
    *(uint2*)(dl_ + doff) = make_uint2(lb[0] | (lb[1] << 16), lb[2] | (lb[3] << 16));
}

// ---------------------------------------------------------------------------
// k_gbt: C = A . B^T via bf16-split MFMA with LDS-staged tiles. 64x256, K=512.
// mode 0: out[m*512+n] (U). mode 1: out[n*1024+m] + bih[n]+bhh[n] (G0T).
// ---------------------------------------------------------------------------
__global__ __launch_bounds__(256) void k_gbt(const unsigned short* __restrict__ Ah,
                                             const unsigned short* __restrict__ Al,
                                             const unsigned short* __restrict__ Bh,
                                             const unsigned short* __restrict__ Bl,
                                             const float* __restrict__ bih,
                                             const float* __restrict__ bhh,
                                             float* __restrict__ out,
                                             int nbn, int mode) {
    __shared__ __align__(16) unsigned short BhL[4][256][8];
    __shared__ __align__(16) unsigned short BlL[4][256][8];
    __shared__ __align__(16) unsigned short AhL[4][64][8];
    __shared__ __align__(16) unsigned short AlL[4][64][8];
    const int m0 = (blockIdx.x / nbn) * 64;
    const int n0 = (blockIdx.x % nbn) * 256;
    const int tid = threadIdx.x;
    const int lane = tid & 63, wid = tid >> 6;
    const int wr = wid >> 1, wc = wid & 1;
    const int l15 = lane & 15, lk = lane >> 4;

    f32x4 acc[2][8];
    #pragma unroll
    for (int mt = 0; mt < 2; mt++)
        #pragma unroll
        for (int nt = 0; nt < 8; nt++) acc[mt][nt] = {0.f, 0.f, 0.f, 0.f};

    for (int kc = 0; kc < 512; kc += 32) {
        {
            #pragma unroll
            for (int g = 0; g < 4; g++) {
                const size_t bo = (size_t)(n0 + tid) * 512 + kc + g * 8;
                *(uint4*)&BhL[g][tid][0] = *(const uint4*)(Bh + bo);
                *(uint4*)&BlL[g][tid][0] = *(const uint4*)(Bl + bo);
            }
        }
        {
            const int row = tid >> 2, g = tid & 3;
            const size_t ao = (size_t)(m0 + row) * 512 + kc + g * 8;
            *(uint4*)&AhL[g][row][0] = *(const uint4*)(Ah + ao);
            *(uint4*)&AlL[g][row][0] = *(const uint4*)(Al + ao);
        }
        __syncthreads();
        {
            bf16x8 afh[2], afl[2];
            #pragma unroll
            for (int mt = 0; mt < 2; mt++) {
                const int r = wr * 32 + mt * 16 + l15;
                afh[mt] = *(const bf16x8*)&AhL[lk][r][0];
                afl[mt] = *(const bf16x8*)&AlL[lk][r][0];
            }
            #pragma unroll
            for (int nt = 0; nt < 8; nt++) {
                const int nn = wc * 128 + nt * 16 + l15;
                bf16x8 bh = *(const bf16x8*)&BhL[lk][nn][0];
                bf16x8 bl = *(const bf16x8*)&BlL[lk][nn][0];
                #pragma unroll
                for (int mt = 0; mt < 2; mt++) {
                    acc[mt][nt] = __builtin_amdgcn_mfma_f32_16x16x32_bf16(afh[mt], bh, acc[mt][nt], 0, 0, 0);
                    acc[mt][nt] = __builtin_amdgcn_mfma_f32_16x16x32_bf16(afl[mt], bh, acc[mt][nt], 0, 0, 0);
                    acc[mt][nt] = __builtin_amdgcn_mfma_f32_16x16x32_bf16(afh[mt], bl, acc[mt][nt], 0, 0, 0);
                }
            }
        }
        __syncthreads();
    }
    #pragma unroll
    for (int mt = 0; mt < 2; mt++)
        #pragma unroll
        for (int reg = 0; reg < 4; reg++) {
            const int row = m0 + wr * 32 + mt * 16 + lk * 4 + reg;
            #pragma unroll
            for (int nt = 0; nt < 8; nt++) {
                const int col = n0 + wc * 128 + nt * 16 + l15;
                const float v = acc[mt][nt][reg];
                if (mode == 0) out[(size_t)row * 512 + col] = v;
                else           out[(size_t)col * 1024 + row] = v + bih[col] + bhh[col];
            }
        }
}

// ---------------------------------------------------------------------------
// k_gbt_dec: dec GEMM via bf16-split MFMA, LDS-staged. M=1024, N=512,
// K=1536 (A regions emb|h|att), tanh(+bgen) -> chunk-major dhk/dlk. Grid 32.
// ---------------------------------------------------------------------------
__global__ __launch_bounds__(256) void k_gbt_dec(const unsigned short* __restrict__ eh,
                                                 const unsigned short* __restrict__ el,
                                                 const unsigned short* __restrict__ hh,
                                                 const unsigned short* __restrict__ hl,
                                                 const unsigned short* __restrict__ ath,
                                                 const unsigned short* __restrict__ atl,
                                                 const unsigned short* __restrict__ wgh,
                                                 const unsigned short* __restrict__ wgl,
                                                 const float* __restrict__ bgen,
                                                 unsigned short* __restrict__ dhk,
                                                 unsigned short* __restrict__ dlk) {
    __shared__ __align__(16) unsigned short BhL[4][256][8];
    __shared__ __align__(16) unsigned short BlL[4][256][8];
    __shared__ __align__(16) unsigned short AhL[4][64][8];
    __shared__ __align__(16) unsigned short AlL[4][64][8];
    const int m0 = (blockIdx.x >> 1) * 64;
    const int n0 = (blockIdx.x & 1) * 256;
    const int tid = threadIdx.x;
    const int lane = tid & 63, wid = tid >> 6;
    const int wr = wid >> 1, wc = wid & 1;
    const int l15 = lane & 15, lk = lane >> 4;

    f32x4 acc[2][8];
    #pragma unroll
    for (int mt = 0; mt < 2; mt++)
        #pragma unroll
        for (int nt = 0; nt < 8; nt++) acc[mt][nt] = {0.f, 0.f, 0.f, 0.f};

    for (int kc = 0; kc < 1536; kc += 32) {
        const unsigned short *Ahp, *Alp;
        int ko;
        if (kc < 512)       { Ahp = eh;  Alp = el;  ko = kc; }
        else if (kc < 1024) { Ahp = hh;  Alp = hl;  ko = kc - 512; }
        else                { Ahp = ath; Alp = atl; ko = kc - 1024; }
        {
            #pragma unroll
            for (int g = 0; g < 4; g++) {
                const size_t bo = (size_t)(n0 + tid) * 1536 + kc + g * 8;
                *(uint4*)&BhL[g][tid][0] = *(const uint4*)(wgh + bo);
                *(uint4*)&BlL[g][tid][0] = *(const uint4*)(wgl + bo);
            }
        }
        {
            const int row = tid >> 2, g = tid & 3;
            const size_t ao = (size_t)(m0 + row) * 512 + ko + g * 8;
            *(uint4*)&AhL[g][row][0] = *(const uint4*)(Ahp + ao);
            *(uint4*)&AlL[g][row][0] = *(const uint4*)(Alp + ao);
        }
        __syncthreads();
        {
            bf16x8 afh[2], afl[2];
            #pragma unroll
            for (int mt = 0; mt < 2; mt++) {
                const int r = wr * 32 + mt * 16 + l15;
                afh[mt] = *(const bf16x8*)&AhL[lk][r][0];
                afl[mt] = *(const bf16x8*)&AlL[lk][r][0];
            }
            #pragma unroll
            for (int nt = 0; nt < 8; nt++) {
                const int nn = wc * 128 + nt * 16 + l15;
                bf16x8 bh = *(const bf16x8*)&BhL[lk][nn][0];
                bf16x8 bl = *(const bf16x8*)&BlL[lk][nn][0];
                #pragma unroll
                for (int mt = 0; mt < 2; mt++) {
                    acc[mt][nt] = __builtin_amdgcn_mfma_f32_16x16x32_bf16(afh[mt], bh, acc[mt][nt], 0, 0, 0);
                    acc[mt][nt] = __builtin_amdgcn_mfma_f32_16x16x32_bf16(afl[mt], bh, acc[mt][nt], 0, 0, 0);
                    acc[mt][nt] = __builtin_amdgcn_mfma_f32_16x16x32_bf16(afh[mt], bl, acc[mt][nt], 0, 0, 0);
                }
            }
        }
        __syncthreads();
    }
    #pragma unroll
    for (int mt = 0; mt < 2; mt++)
        #pragma unroll
        for (int reg = 0; reg < 4; reg++) {
            const int row = m0 + wr * 32 + mt * 16 + lk * 4 + reg;
            #pragma unroll
            for (int nt = 0; nt < 8; nt++) {
                const int col = n0 + wc * 128 + nt * 16 + l15;
                const float v = tanhf(acc[mt][nt][reg] + bgen[col]);
                const unsigned short hb = f2bf(v);
                const unsigned short lb = f2bf(v - bf2f(hb));
                const size_t ca = (size_t)(col >> 5) * 32768 + (size_t)(row >> 6) * 2048
                                + (size_t)(row & 63) * 32 + (col & 31);
                dhk[ca] = hb;
                dlk[ca] = lb;
            }
        }
}

// ---------------------------------------------------------------------------
// k_g0 (fp32 fallback)
// ---------------------------------------------------------------------------
__global__ __launch_bounds__(256) void k_g0(const int* __restrict__ tgt_in,
                                            const float* __restrict__ emb,
                                            const float* __restrict__ Wih,
                                            const float* __restrict__ bih,
                                            const float* __restrict__ bhh,
                                            float* __restrict__ G0T) {
    __shared__ float a_s[32][66];
    __shared__ float w_s[32][130];
    const int tid = threadIdx.x;
    const int m0 = blockIdx.x * 64, n0 = blockIdx.y * 128;
    const int mq = tid >> 5, nq = tid & 31;
    float acc[8][4] = {};
    for (int k0 = 0; k0 < 512; k0 += 32) {
        {
            const int mm = tid >> 2, kq = tid & 3, kk = kq * 8;
            const float* row = emb + (size_t)tgt_in[m0 + mm] * E_ + k0 + kk;
            float4 v0 = *(const float4*)(row);
            float4 v1 = *(const float4*)(row + 4);
            a_s[kk + 0][mm] = v0.x; a_s[kk + 1][mm] = v0.y;
            a_s[kk + 2][mm] = v0.z; a_s[kk + 3][mm] = v0.w;
            a_s[kk + 4][mm] = v1.x; a_s[kk + 5][mm] = v1.y;
            a_s[kk + 6][mm] = v1.z; a_s[kk + 7][mm] = v1.w;
        }
        {
            const int nn = tid >> 1, kq = tid & 1, kk = kq * 16;
            const float* row = Wih + (size_t)(n0 + nn) * 1024 + k0 + kk;
            #pragma unroll
            for (int u = 0; u < 4; u++) {
                float4 v = *(const float4*)(row + u * 4);
                w_s[kk + u * 4 + 0][nn] = v.x; w_s[kk + u * 4 + 1][nn] = v.y;
                w_s[kk + u * 4 + 2][nn] = v.z; w_s[kk + u * 4 + 3][nn] = v.w;
            }
        }
        __syncthreads();
        for (int k = 0; k < 32; k++) {
            float a[8], wv[4];
            #pragma unroll
            for (int i = 0; i < 8; i++) a[i] = a_s[k][mq + 8 * i];
            #pragma unroll
            for (int p = 0; p < 4; p++) wv[p] = w_s[k][nq + 32 * p];
            #pragma unroll
            for (int i = 0; i < 8; i++)
                #pragma unroll
                for (int p = 0; p < 4; p++) acc[i][p] += a[i] * wv[p];
        }
        __syncthreads();
    }
    #pragma unroll
    for (int i = 0; i < 8; i++) {
        const int m = m0 + mq + 8 * i;
        #pragma unroll
        for (int p = 0; p < 4; p++) {
            const int n = n0 + nq + 32 * p;
            G0T[(size_t)n * 1024 + m] = acc[i][p] + bih[n] + bhh[n];
        }
    }
}

// ---------------------------------------------------------------------------
// k_u (fp32 fallback)
// ---------------------------------------------------------------------------
__global__ __launch_bounds__(256) void k_u(const float* __restrict__ src,
                                           const float* __restrict__ Wattn,
                                           float* __restrict__ U) {
    __shared__ float a_s[32][66];
    __shared__ float w_s[32][130];
    const int tid = threadIdx.x;
    const int m0 = blockIdx.x * 64, n0 = blockIdx.y * 128;
    const int mq = tid >> 5, nq = tid & 31;
    float acc[8][4] = {};
    for (int k0 = 0; k0 < 512; k0 += 32) {
        {
            const int mm = tid >> 2, kq = tid & 3, kk = kq * 8;
            const float* row = src + (size_t)(m0 + mm) * 512 + k0 + kk;
            float4 v0 = *(const float4*)(row);
            float4 v1 = *(const float4*)(row + 4);
            a_s[kk + 0][mm] = v0.x; a_s[kk + 1][mm] = v0.y;
            a_s[kk + 2][mm] = v0.z; a_s[kk + 3][mm] = v0.w;
            a_s[kk + 4][mm] = v1.x; a_s[kk + 5][mm] = v1.y;
            a_s[kk + 6][mm] = v1.z; a_s[kk + 7][mm] = v1.w;
        }
        {
            const int nn = tid >> 1, kq = tid & 1, kk = kq * 16;
            const float* row = Wattn + (size_t)(n0 + nn) * 1024 + k0 + kk;
            #pragma unroll
            for (int u = 0; u < 4; u++) {
                float4 v = *(const float4*)(row + u * 4);
                w_s[kk + u * 4 + 0][nn] = v.x; w_s[kk + u * 4 + 1][nn] = v.y;
                w_s[kk + u * 4 + 2][nn] = v.z; w_s[kk + u * 4 + 3][nn] = v.w;
            }
        }
        __syncthreads();
        for (int k = 0; k < 32; k++) {
            float a[8], wv[4];
            #pragma unroll
            for (int i = 0; i < 8; i++) a[i] = a_s[k][mq + 8 * i];
            #pragma unroll
            for (int p = 0; p < 4; p++) wv[p] = w_s[k][nq + 32 * p];
            #pragma unroll
            for (int i = 0; i < 8; i++)
                #pragma unroll
                for (int p = 0; p < 4; p++) acc[i][p] += a[i] * wv[p];
        }
        __syncthreads();
    }
    #pragma unroll
    for (int i = 0; i < 8; i++) {
        const int m = m0 + mq + 8 * i;
        #pragma unroll
        for (int p = 0; p < 4; p++)
            U[(size_t)m * 512 + n0 + nq + 32 * p] = acc[i][p];
    }
}

// ---------------------------------------------------------------------------
// k_tr: WaRT[k][j] = W_attn[j][512+k]
// ---------------------------------------------------------------------------
__global__ __launch_bounds__(256) void k_tr(const float* __restrict__ Wattn,
                                            float* __restrict__ WaRT) {
    __shared__ float t_s[32][33];
    const int tid = threadIdx.x;
    const int bx = blockIdx.x, by = blockIdx.y;
    {
        const int jj = tid >> 3, kq = (tid & 7) * 4;
        float4 v = *(const float4*)(Wattn + (size_t)(by * 32 + jj) * 1024 + 512 + bx * 32 + kq);
        t_s[jj][kq + 0] = v.x; t_s[jj][kq + 1] = v.y;
        t_s[jj][kq + 2] = v.z; t_s[jj][kq + 3] = v.w;
    }
    __syncthreads();
    {
        const int kk = tid >> 3, jq = (tid & 7) * 4;
        float4 w;
        w.x = t_s[jq + 0][kk]; w.y = t_s[jq + 1][kk];
        w.z = t_s[jq + 2][kk]; w.w = t_s[jq + 3][kk];
        *(float4*)(WaRT + (size_t)(bx * 32 + kk) * 512 + by * 32 + jq) = w;
    }
}

// ---------------------------------------------------------------------------
// k_wconv: Wread fp32 -> bf16 hi/lo, chunk-major with BAKED bank swizzle.
// ---------------------------------------------------------------------------
__global__ __launch_bounds__(256) void k_wconv(const float* __restrict__ Wread,
                                               unsigned short* __restrict__ whk,
                                               unsigned short* __restrict__ wlk) {
    const size_t q = (size_t)blockIdx.x * 256 + threadIdx.x;
    const size_t k8 = q * 8;
    const int n = (int)(k8 >> 9);
    const int k = (int)(k8 & 511);
    if (n >= VP_) return;
    uint4 h4, l4;
    if (n < V_) {
        float4 p0 = *(const float4*)(Wread + (size_t)n * 512 + k);
        float4 p1 = *(const float4*)(Wread + (size_t)n * 512 + k + 4);
        float v[8] = {p0.x, p0.y, p0.z, p0.w, p1.x, p1.y, p1.z, p1.w};
        unsigned int hb[8], lb[8];
        #pragma unroll
        for (int e = 0; e < 8; e++) {
            hb[e] = f2bf(v[e]);
            lb[e] = f2bf(v[e] - bf2f((unsigned short)hb[e]));
        }
        h4 = make_uint4(hb[0] | (hb[1] << 16), hb[2] | (hb[3] << 16),
                        hb[4] | (hb[5] << 16), hb[6] | (hb[7] << 16));
        l4 = make_uint4(lb[0] | (lb[1] << 16), lb[2] | (lb[3] << 16),
                        lb[4] | (lb[5] << 16), lb[6] | (lb[7] << 16));
    } else {
        h4 = make_uint4(0, 0, 0, 0);
        l4 = make_uint4(0, 0, 0, 0);
    }
    const int lk = (k >> 3) & 3;
    const size_t dst = (size_t)(k >> 5) * ((size_t)VP_ * 32) + (size_t)n * 32
                     + (size_t)((lk ^ ((n >> 1) & 3)) * 8);
    *(uint4*)(whk + dst) = h4;
    *(uint4*)(wlk + dst) = l4;
}

// ---------------------------------------------------------------------------
// Persistent scan (round-11 proven; + bf16-split h/att emission).
// ---------------------------------------------------------------------------
__global__ __launch_bounds__(512) void k_scan(const float* __restrict__ G0T,
                                              const float* __restrict__ U,
                                              const float* __restrict__ WaRT,
                                              const float* __restrict__ Wih,
                                              const float* __restrict__ Whh,
                                              const float* __restrict__ src,
                                              const int* __restrict__ lens,
                                              const float* __restrict__ last_cell,
                                              float* __restrict__ xT,
                                              float* __restrict__ h_b,
                                              float* __restrict__ scb,
                                              float* __restrict__ h_hist,
                                              float* __restrict__ att_hist,
                                              unsigned short* __restrict__ hh,
                                              unsigned short* __restrict__ hl,
                                              unsigned short* __restrict__ ath,
                                              unsigned short* __restrict__ atl,
                                              int pre,
                                              int* __restrict__ bar) {
    __shared__ float Wl[8 * 1024];
    __shared__ float Ul[200 * 64];
    __shared__ float red_s[2048];
    __shared__ float gate_s[256];
    __shared__ float h_s[512];
    __shared__ float al[256];
    __shared__ float pr[512];

    const int blk = blockIdx.x, tid = threadIdx.x;
    const int u0 = blk * 2;
    const int bb = blk & 31, p = blk >> 5;

    for (int f = tid; f < 2048; f += 512) {
        const int r = f >> 8, k = (f & 255) * 4;
        const int j = (r >> 1) * 512 + u0 + (r & 1);
        float4 v;
        if (k < 512) v = *(const float4*)(Wih + (size_t)j * 1024 + 512 + k);
        else         v = *(const float4*)(Whh + (size_t)j * 512 + (k - 512));
        *(float4*)&Wl[r * 1024 + k] = v;
    }
    for (int f = tid; f < 3200; f += 512) {
        const int s = f >> 4, q = (f & 15) * 4;
        *(float4*)&Ul[s * 64 + q] = *(const float4*)(U + ((size_t)bb * S_ + s) * 512 + p * 64 + q);
    }
    float creg = (tid < 64) ? last_cell[(tid & 31) * 512 + u0 + (tid >> 5)] : 0.f;
    __syncthreads();

    const int w = tid >> 6, lane = tid & 63;
    const int hf = lane >> 5, b = lane & 31;
    const int len = lens[bb];

    for (int t = 0; t < T_; t++) {
        // -------- Phase A: gates + pointwise ------------------------------
        {
            const int hoff = ((t + 1) & 1) * 512;        // slot holding h(t-1)
            const int kbase = w * 128 + hf * 64;
            const float* xp = (kbase < 512)
                ? (xT + (size_t)kbase * 32 + b)
                : (xT + (size_t)(512 + hoff + (kbase - 512)) * 32 + b);
            float acc[8] = {};
            #pragma unroll
            for (int kk = 0; kk < 64; kk += 8) {
                float xv[8];
                #pragma unroll
                for (int i = 0; i < 8; i++)
                    xv[i] = g_load(xp + (size_t)(kk + i) * 32);
                #pragma unroll
                for (int r = 0; r < 8; r++) {
                    const float* wr = &Wl[r * 1024 + kbase + kk];
                    float s0 = xv[0] * wr[0] + xv[1] * wr[1] + xv[2] * wr[2] + xv[3] * wr[3];
                    float s1 = xv[4] * wr[4] + xv[5] * wr[5] + xv[6] * wr[6] + xv[7] * wr[7];
                    acc[r] += s0 + s1;
                }
            }
            #pragma unroll
            for (int r = 0; r < 8; r++) acc[r] += __shfl_xor(acc[r], 32);
            if (hf == 0) {
                #pragma unroll
                for (int r = 0; r < 8; r++) red_s[w * 256 + r * 32 + b] = acc[r];
            }
            __syncthreads();
            if (tid < 256) {
                const int r = tid >> 5, b2 = tid & 31;
                const int j = (r >> 1) * 512 + u0 + (r & 1);
                float g = G0T[(size_t)j * 1024 + t * 32 + b2];
                #pragma unroll
                for (int ww = 0; ww < 8; ww++) g += red_s[ww * 256 + r * 32 + b2];
                gate_s[r * 32 + b2] = g;
            }
            __syncthreads();
            if (tid < 64) {
                const int ui = tid >> 5, b2 = tid & 31, u = u0 + ui;
                const float gi = gate_s[(0 + ui) * 32 + b2];
                const float gf = gate_s[(2 + ui) * 32 + b2];
                const float gg = gate_s[(4 + ui) * 32 + b2];
                const float go = gate_s[(6 + ui) * 32 + b2];
                const float cn = sigf(gf) * creg + sigf(gi) * tanhf(gg);
                const float hn = sigf(go) * tanhf(cn);
                creg = cn;
                g_store(&xT[(size_t)(512 + (t & 1) * 512 + u) * 32 + b2], hn);
                g_store(&h_b[b2 * 512 + u], hn);
                h_hist[((size_t)t * B_ + b2) * 512 + u] = hn;
                if (pre) {
                    const unsigned short hb2 = f2bf(hn);
                    const size_t ho = ((size_t)t * B_ + b2) * 512 + u;
                    hh[ho] = hb2;
                    hl[ho] = f2bf(hn - bf2f(hb2));
                }
            }
        }
        full_sync(bar, 2 * t);

        // -------- Phase B: scores -----------------------------------------
        {
            h_s[tid] = g_load(&h_b[bb * 512 + tid]);
            __syncthreads();
            for (int i = w; i < 25; i += 8) {
                const int s = p * 25 + i;
                const float* sr = src + ((size_t)bb * S_ + s) * 512;
                const float4 x0 = *(const float4*)(sr + lane * 4);
                const float4 x1 = *(const float4*)(sr + 256 + lane * 4);
                const float4 h0 = *(const float4*)(&h_s[lane * 4]);
                const float4 h1 = *(const float4*)(&h_s[256 + lane * 4]);
                float a = x0.x * h0.x + x0.y * h0.y + x0.z * h0.z + x0.w * h0.w
                        + x1.x * h1.x + x1.y * h1.y + x1.z * h1.z + x1.w * h1.w;
                #pragma unroll
                for (int mk = 1; mk < 64; mk <<= 1) a += __shfl_xor(a, mk);
                if (lane == 0) g_store(&scb[bb * 256 + s], (s < len) ? a : -INFINITY);
            }
        }
        sub_sync(bar, bb, t);

        // -------- Phase C: softmax + att slice ----------------------------
        {
            if (tid < 64) {
                const float v0 = g_load(&scb[bb * 256 + tid]);
                const float v1 = g_load(&scb[bb * 256 + 64 + tid]);
                const float v2 = g_load(&scb[bb * 256 + 128 + tid]);
                const float v3 = (tid < 8) ? g_load(&scb[bb * 256 + 192 + tid]) : -INFINITY;
                float m = fmaxf(fmaxf(v0, v1), fmaxf(v2, v3));
                #pragma unroll
                for (int mk = 1; mk < 64; mk <<= 1) m = fmaxf(m, __shfl_xor(m, mk));
                const float e0 = expf(v0 - m), e1 = expf(v1 - m), e2 = expf(v2 - m);
                const float e3 = (tid < 8) ? expf(v3 - m) : 0.f;
                float sum = (e0 + e1) + (e2 + e3);
                #pragma unroll
                for (int mk = 1; mk < 64; mk <<= 1) sum += __shfl_xor(sum, mk);
                const float inv = 1.f / sum;
                al[tid] = e0 * inv; al[64 + tid] = e1 * inv; al[128 + tid] = e2 * inv;
                if (tid < 8) al[192 + tid] = e3 * inv;
            }
            __syncthreads();
            const int jl = tid & 63, sg = tid >> 6;
            float uacc = 0.f;
            #pragma unroll 5
            for (int s = sg * 25; s < sg * 25 + 25; s++)
                uacc += al[s] * Ul[s * 64 + jl];
            const float* wc0 = WaRT + (size_t)(sg * 64) * 512 + p * 64 + jl;
            const float* hp = &h_s[sg * 64];
            float c0 = 0.f, c1 = 0.f;
            #pragma unroll 8
            for (int kk = 0; kk < 64; kk += 2) {
                c0 += hp[kk] * wc0[(size_t)kk * 512];
                c1 += hp[kk + 1] * wc0[(size_t)(kk + 1) * 512];
            }
            pr[tid] = uacc + c0 + c1;
            __syncthreads();
            if (tid < 64) {
                float tot = 0.f;
                #pragma unroll
                for (int sgg = 0; sgg < 8; sgg++) tot += pr[sgg * 64 + tid];
                const float a = tanhf(tot);
                g_store(&xT[(size_t)(p * 64 + tid) * 32 + bb], a);
                att_hist[((size_t)t * B_ + bb) * 512 + p * 64 + tid] = a;
                if (pre) {
                    const unsigned short ab = f2bf(a);
                    const size_t ao = ((size_t)t * B_ + bb) * 512 + p * 64 + tid;
                    ath[ao] = ab;
                    atl[ao] = f2bf(a - bf2f(ab));
                }
            }
        }
        full_sync(bar, 2 * t + 1);
    }
}

// ---------------------------------------------------------------------------
// k_dec (fp32 fallback)
// ---------------------------------------------------------------------------
__global__ __launch_bounds__(256) void k_dec(const int* __restrict__ tgt_in,
                                             const float* __restrict__ emb,
                                             const float* __restrict__ h_hist,
                                             const float* __restrict__ att_hist,
                                             const float* __restrict__ Wgen,
                                             const float* __restrict__ bgen,
                                             unsigned short* __restrict__ dh,
                                             unsigned short* __restrict__ dl) {
    __shared__ float a_s[32][66];
    __shared__ float w_s[32][130];
    const int tid = threadIdx.x;
    const int m0 = blockIdx.x * 64, n0 = blockIdx.y * 128;
    const int mq = tid >> 5, nq = tid & 31;
    float acc[8][4] = {};
    for (int k0 = 0; k0 < 1536; k0 += 32) {
        {
            const int mm = tid >> 2, kq = tid & 3, kk = kq * 8;
            const int m = m0 + mm;
            const float* row;
            if (k0 < 512)       row = emb + (size_t)tgt_in[m] * E_ + k0;
            else if (k0 < 1024) row = h_hist + (size_t)m * 512 + (k0 - 512);
            else                row = att_hist + (size_t)m * 512 + (k0 - 1024);
            row += kk;
            float4 v0 = *(const float4*)(row);
            float4 v1 = *(const float4*)(row + 4);
            a_s[kk + 0][mm] = v0.x; a_s[kk + 1][mm] = v0.y;
            a_s[kk + 2][mm] = v0.z; a_s[kk + 3][mm] = v0.w;
            a_s[kk + 4][mm] = v1.x; a_s[kk + 5][mm] = v1.y;
            a_s[kk + 6][mm] = v1.z; a_s[kk + 7][mm] = v1.w;
        }
        {
            const int nn = tid >> 1, kq = tid & 1, kk = kq * 16;
            const float* row = Wgen + (size_t)(n0 + nn) * 1536 + k0 + kk;
            #pragma unroll
            for (int u = 0; u < 4; u++) {
                float4 v = *(const float4*)(row + u * 4);
                w_s[kk + u * 4 + 0][nn] = v.x; w_s[kk + u * 4 + 1][nn] = v.y;
                w_s[kk + u * 4 + 2][nn] = v.z; w_s[kk + u * 4 + 3][nn] = v.w;
            }
        }
        __syncthreads();
        for (int k = 0; k < 32; k++) {
            float a[8], wv[4];
            #pragma unroll
            for (int i = 0; i < 8; i++) a[i] = a_s[k][mq + 8 * i];
            #pragma unroll
            for (int pq = 0; pq < 4; pq++) wv[pq] = w_s[k][nq + 32 * pq];
            #pragma unroll
            for (int i = 0; i < 8; i++)
                #pragma unroll
                for (int pq = 0; pq < 4; pq++) acc[i][pq] += a[i] * wv[pq];
        }
        __syncthreads();
    }
    #pragma unroll
    for (int i = 0; i < 8; i++) {
        const int m = m0 + mq + 8 * i;
        #pragma unroll
        for (int pq = 0; pq < 4; pq++) {
            const int n = n0 + nq + 32 * pq;
            const float v = tanhf(acc[i][pq] + bgen[n]);
            const unsigned short hb = f2bf(v);
            dh[(size_t)m * 512 + n] = hb;
            dl[(size_t)m * 512 + n] = f2bf(v - bf2f(hb));
        }
    }
}

// ===========================================================================
// k_read_pre: 512 threads (8 waves, wr 0..3 x wc 0..1), double-buffered B
// stage via global_load_lds (stage k+1 issued before MFMA of k, ONE sync per
// chunk). acc = 8 f32x4/thread; A-frags per-lane direct from chunk-major
// dhk/dlk. Grid 3200 XCD-grouped, LDS 64 KB + epilogue -> 2 blocks/CU,
// 16 waves/CU.
// ===========================================================================
__global__ __launch_bounds__(512) void k_read_pre(const unsigned short* __restrict__ dhk,
                                                  const unsigned short* __restrict__ dlk,
                                                  const unsigned short* __restrict__ whk,
                                                  const unsigned short* __restrict__ wlk,
                                                  const int* __restrict__ tgt_out,
                                                  float4* __restrict__ part,
                                                  float* __restrict__ tgt_logit) {
    __shared__ __align__(16) unsigned short BhL[2][8192];   // 32 KB
    __shared__ __align__(16) unsigned short BlL[2][8192];   // 32 KB
    __shared__ float ep_max[64][2];
    __shared__ int   ep_idx[64][2];
    __shared__ float ep_fin[64];
    __shared__ int   ep_fidx[64];
    __shared__ float ep_sum[64][2];

    const int xcd = blockIdx.x & 7;
    const int idx = blockIdx.x >> 3;
    const int mi  = idx & 15;
    const int group = idx >> 4;
    const int ch = group * 8 + xcd;
    if (ch >= NCH) return;
    const int m0 = mi * 64, n0 = ch * 256;

    const int tid = threadIdx.x;
    const int lane = tid & 63, wid = tid >> 6;
    const int wr = wid >> 1, wc = wid & 1;
    const int l15 = lane & 15, lk = lane >> 4;

    f32x4 acc[8];
    #pragma unroll
    for (int nt = 0; nt < 8; nt++) acc[nt] = {0.f, 0.f, 0.f, 0.f};

    const unsigned short* bh_src = whk + (size_t)n0 * 32;
    const unsigned short* bl_src = wlk + (size_t)n0 * 32;
    const unsigned short* ah_base = dhk + (size_t)(m0 >> 6) * 2048 + lk * 8;
    const unsigned short* al_base = dlk + (size_t)(m0 >> 6) * 2048 + lk * 8;

    // prologue: stage chunk 0 into buffer 0 (8 waves x 2 KB per array)
    {
        const char* gh = (const char*)bh_src;
        const char* gl = (const char*)bl_src;
        #pragma unroll
        for (int c = 0; c < 2; c++) {
            const int ob = wid * 2048 + c * 1024;
            async16((char*)&BhL[0][0] + ob, gh + ob + lane * 16);
            async16((char*)&BlL[0][0] + ob, gl + ob + lane * 16);
        }
    }
    __syncthreads();

    for (int kc = 0; kc < 16; kc++) {
        const int cur = kc & 1;
        bf16x8 afh, afl;
        {   // A fragments (issued first; compiler waits only for these)
            const unsigned short* ah = ah_base + (size_t)kc * 32768;
            const unsigned short* al = al_base + (size_t)kc * 32768;
            const int r = wr * 16 + l15;
            afh = *(const bf16x8*)(ah + r * 32);
            afl = *(const bf16x8*)(al + r * 32);
        }
        if (kc < 15) {   // stage next chunk into the other buffer
            const size_t cb = (size_t)(kc + 1) * ((size_t)VP_ * 32);
            const char* gh = (const char*)(bh_src + cb);
            const char* gl = (const char*)(bl_src + cb);
            #pragma unroll
            for (int c = 0; c < 2; c++) {
                const int ob = wid * 2048 + c * 1024;
                async16((char*)&BhL[cur ^ 1][0] + ob, gh + ob + lane * 16);
                async16((char*)&BlL[cur ^ 1][0] + ob, gl + ob + lane * 16);
            }
        }
        #pragma unroll
        for (int nt = 0; nt < 8; nt++) {
            const int nn = wc * 128 + nt * 16 + l15;
            const int bo = nn * 32 + ((lk ^ ((nn >> 1) & 3)) * 8);
            bf16x8 bh = *(const bf16x8*)&BhL[cur][bo];
            bf16x8 bl = *(const bf16x8*)&BlL[cur][bo];
            acc[nt] = __builtin_amdgcn_mfma_f32_16x16x32_bf16(afh, bh, acc[nt], 0, 0, 0);
            acc[nt] = __builtin_amdgcn_mfma_f32_16x16x32_bf16(afl, bh, acc[nt], 0, 0, 0);
            acc[nt] = __builtin_amdgcn_mfma_f32_16x16x32_bf16(afh, bl, acc[nt], 0, 0, 0);
        }
        __syncthreads();   // drains vmcnt (next stage landed) + readers done
    }

    // ---- epilogue: per-row max/idx ----
    #pragma unroll
    for (int reg = 0; reg < 4; reg++) {
        float bv = -INFINITY; int bi = 0x7fffffff;
        #pragma unroll
        for (int nt = 0; nt < 8; nt++) {
            const int n = n0 + wc * 128 + nt * 16 + l15;
            const float v = (n < V_) ? acc[nt][reg] : -INFINITY;
            if (v > bv || (v == bv && n < bi)) { bv = v; bi = n; }
        }
        #pragma unroll
        for (int mk = 1; mk < 16; mk <<= 1) {
            const float ov = __shfl_xor(bv, mk);
            const int oi = __shfl_xor(bi, mk);
            if (ov > bv || (ov == bv && oi < bi)) { bv = ov; bi = oi; }
        }
        if (l15 == 0) {
            const int rl = wr * 16 + lk * 4 + reg;
            ep_max[rl][wc] = bv; ep_idx[rl][wc] = bi;
        }
    }
    __syncthreads();
    if (tid < 64) {
        const float a = ep_max[tid][0], b = ep_max[tid][1];
        const int ia = ep_idx[tid][0], ib = ep_idx[tid][1];
        const bool tb = (b > a) || (b == a && ib < ia);
        ep_fin[tid] = tb ? b : a; ep_fidx[tid] = tb ? ib : ia;
    }
    __syncthreads();
    #pragma unroll
    for (int reg = 0; reg < 4; reg++) {
        const int rl = wr * 16 + lk * 4 + reg;
        const float M = ep_fin[rl];
        const int rel = tgt_out[m0 + rl] - n0;
        float se = 0.f;
        #pragma unroll
        for (int nt = 0; nt < 8; nt++) {
            const int nl = wc * 128 + nt * 16 + l15;
            if (n0 + nl < V_) {
                const float v = acc[nt][reg];
                se += expf(v - M);
                if (nl == rel) tgt_logit[m0 + rl] = v;
            }
        }
        #pragma unroll
        for (int mk = 1; mk < 16; mk <<= 1) se += __shfl_xor(se, mk);
        if (l15 == 0) ep_sum[rl][wc] = se;
    }
    __syncthreads();
    if (tid < 64) {
        part[(size_t)(m0 + tid) * NCH + ch] =
            make_float4(ep_fin[tid], ep_sum[tid][0] + ep_sum[tid][1],
                        __int_as_float(ep_fidx[tid]), 0.f);
    }
}

// ---------------------------------------------------------------------------
// k_read (fallback: in-kernel conversion, row-major dh/dl, grid 3200)
// ---------------------------------------------------------------------------
__global__ __launch_bounds__(256) void k_read(const unsigned short* __restrict__ dh,
                                              const unsigned short* __restrict__ dl,
                                              const float* __restrict__ Wread,
                                              const int* __restrict__ tgt_out,
                                              float4* __restrict__ part,
                                              float* __restrict__ tgt_logit) {
    __shared__ __align__(16) unsigned short Bh[4][256][8];
    __shared__ __align__(16) unsigned short Bl[4][256][8];
    __shared__ __align__(16) unsigned short Ah[4][64][8];
    __shared__ __align__(16) unsigned short Alo[4][64][8];
    __shared__ float ep_max[64][2];
    __shared__ int   ep_idx[64][2];
    __shared__ float ep_fin[64];
    __shared__ int   ep_fidx[64];
    __shared__ float ep_sum[64][2];

    const int xcd = blockIdx.x & 7;
    const int idx = blockIdx.x >> 3;
    const int mi  = idx & 15;
    const int group = idx >> 4;
    const int ch = group * 8 + xcd;
    if (ch >= NCH) return;
    const int m0 = mi * 64, n0 = ch * 256;

    const int tid = threadIdx.x;
    const int lane = tid & 63, wid = tid >> 6;
    const int wr = wid >> 1, wc = wid & 1;
    const int l15 = lane & 15, lk = lane >> 4;

    f32x4 acc[2][8];
    #pragma unroll
    for (int mt = 0; mt < 2; mt++)
        #pragma unroll
        for (int nt = 0; nt < 8; nt++) acc[mt][nt] = {0.f, 0.f, 0.f, 0.f};

    for (int kc = 0; kc < 512; kc += 32) {
        {
            const int n = n0 + tid;
            const float* row = Wread + (size_t)n * 512 + kc;
            #pragma unroll
            for (int g = 0; g < 4; g++) {
                uint4 h4, l4;
                if (n < V_) {
                    float4 p0 = *(const float4*)(row + g * 8);
                    float4 p1 = *(const float4*)(row + g * 8 + 4);
                    float v[8] = {p0.x, p0.y, p0.z, p0.w, p1.x, p1.y, p1.z, p1.w};
                    unsigned int hb[8], lb[8];
                    #pragma unroll
                    for (int e = 0; e < 8; e++) {
                        hb[e] = f2bf(v[e]);
                        lb[e] = f2bf(v[e] - bf2f((unsigned short)hb[e]));
                    }
                    h4 = make_uint4(hb[0] | (hb[1] << 16), hb[2] | (hb[3] << 16),
                                    hb[4] | (hb[5] << 16), hb[6] | (hb[7] << 16));
                    l4 = make_uint4(lb[0] | (lb[1] << 16), lb[2] | (lb[3] << 16),
                                    lb[4] | (lb[5] << 16), lb[6] | (lb[7] << 16));
                } else {
                    h4 = make_uint4(0, 0, 0, 0);
                    l4 = make_uint4(0, 0, 0, 0);
                }
                *(uint4*)&Bh[g][tid][0] = h4;
                *(uint4*)&Bl[g][tid][0] = l4;
            }
        }
        {
            const int row = tid >> 2, g = tid & 3;
            *(uint4*)&Ah[g][row][0]  = *(const uint4*)(dh + (size_t)(m0 + row) * 512 + kc + g * 8);
            *(uint4*)&Alo[g][row][0] = *(const uint4*)(dl + (size_t)(m0 + row) * 512 + kc + g * 8);
        }
        __syncthreads();
        {
            bf16x8 afh[2], afl[2];
            #pragma unroll
            for (int mt = 0; mt < 2; mt++) {
                const int r = wr * 32 + mt * 16 + l15;
                afh[mt] = *(const bf16x8*)&Ah[lk][r][0];
                afl[mt] = *(const bf16x8*)&Alo[lk][r][0];
            }
            #pragma unroll
            for (int nt = 0; nt < 8; nt++) {
                const int nn = wc * 128 + nt * 16 + l15;
                bf16x8 bh = *(const bf16x8*)&Bh[lk][nn][0];
                bf16x8 bl = *(const bf16x8*)&Bl[lk][nn][0];
                #pragma unroll
                for (int mt = 0; mt < 2; mt++) {
                    acc[mt][nt] = __builtin_amdgcn_mfma_f32_16x16x32_bf16(afh[mt], bh, acc[mt][nt], 0, 0, 0);
                    acc[mt][nt] = __builtin_amdgcn_mfma_f32_16x16x32_bf16(afl[mt], bh, acc[mt][nt], 0, 0, 0);
                    acc[mt][nt] = __builtin_amdgcn_mfma_f32_16x16x32_bf16(afh[mt], bl, acc[mt][nt], 0, 0, 0);
                }
            }
        }
        __syncthreads();
    }

    #pragma unroll
    for (int mt = 0; mt < 2; mt++)
        #pragma unroll
        for (int reg = 0; reg < 4; reg++) {
            float bv = -INFINITY; int bi = 0x7fffffff;
            #pragma unroll
            for (int nt = 0; nt < 8; nt++) {
                const int n = n0 + wc * 128 + nt * 16 + l15;
                const float v = (n < V_) ? acc[mt][nt][reg] : -INFINITY;
                if (v > bv || (v == bv && n < bi)) { bv = v; bi = n; }
            }
            #pragma unroll
            for (int mk = 1; mk < 16; mk <<= 1) {
                const float ov = __shfl_xor(bv, mk);
                const int oi = __shfl_xor(bi, mk);
                if (ov > bv || (ov == bv && oi < bi)) { bv = ov; bi = oi; }
            }
            if (l15 == 0) {
                const int rl = wr * 32 + mt * 16 + lk * 4 + reg;
                ep_max[rl][wc] = bv; ep_idx[rl][wc] = bi;
            }
        }
    __syncthreads();
    if (tid < 64) {
        const float a = ep_max[tid][0], b = ep_max[tid][1];
        const int ia = ep_idx[tid][0], ib = ep_idx[tid][1];
        const bool tb = (b > a) || (b == a && ib < ia);
        ep_fin[tid] = tb ? b : a; ep_fidx[tid] = tb ? ib : ia;
    }
    __syncthreads();
    #pragma unroll
    for (int mt = 0; mt < 2; mt++)
        #pragma unroll
        for (int reg = 0; reg < 4; reg++) {
            const int rl = wr * 32 + mt * 16 + lk * 4 + reg;
            const float M = ep_fin[rl];
            const int rel = tgt_out[m0 + rl] - n0;
            float se = 0.f;
            #pragma unroll
            for (int nt = 0; nt < 8; nt++) {
                const int nl = wc * 128 + nt * 16 + l15;
                if (n0 + nl < V_) {
                    const float v = acc[mt][nt][reg];
                    se += expf(v - M);
                    if (nl == rel) tgt_logit[m0 + rl] = v;
                }
            }
            #pragma unroll
            for (int mk = 1; mk < 16; mk <<= 1) se += __shfl_xor(se, mk);
            if (l15 == 0) ep_sum[rl][wc] = se;
        }
    __syncthreads();
    if (tid < 64) {
        part[(size_t)(m0 + tid) * NCH + ch] =
            make_float4(ep_fin[tid], ep_sum[tid][0] + ep_sum[tid][1],
                        __int_as_float(ep_fidx[tid]), 0.f);
    }
}

// ---------------------------------------------------------------------------
// k_merge: combine chunk partials -> loss + argmax
// ---------------------------------------------------------------------------
__global__ __launch_bounds__(256) void k_merge(const float4* __restrict__ part,
                                               const float* __restrict__ tgt_logit,
                                               const int* __restrict__ tgt_out,
                                               float* __restrict__ out) {
    const int tid = threadIdx.x;
    const int w = tid >> 6, lane = tid & 63;
    const int row = blockIdx.x * 4 + w;
    float bm = -INFINITY; int bi = 0x7fffffff;
    for (int ch = lane; ch < NCH; ch += 64) {
        const float4 p = part[(size_t)row * NCH + ch];
        const int pi = __float_as_int(p.z);
        if (p.x > bm || (p.x == bm && pi < bi)) { bm = p.x; bi = pi; }
    }
    #pragma unroll
    for (int mk = 1; mk < 64; mk <<= 1) {
        const float ov = __shfl_xor(bm, mk);
        const int oi = __shfl_xor(bi, mk);
        if (ov > bm || (ov == bm && oi < bi)) { bm = ov; bi = oi; }
    }
    float sum = 0.f;
    for (int ch = lane; ch < NCH; ch += 64) {
        const float4 p = part[(size_t)row * NCH + ch];
        sum += p.y * expf(p.x - bm);
    }
    #pragma unroll
    for (int mk = 1; mk < 64; mk <<= 1) sum += __shfl_xor(sum, mk);
    if (lane == 0) {
        const float lse = bm + logf(sum);
        const int tg = tgt_out[row];
        const float loss = (tg != 0) ? (lse - tgt_logit[row]) : 0.f;
        out[row] = loss;
        out[1024 + row] = (float)bi;
    }
}

// ---------------------------------------------------------------------------
extern "C" void kernel_launch(void* const* d_in, const int* in_sizes, int n_in,
                              void* d_out, int out_size, void* d_ws, size_t ws_size,
                              hipStream_t stream) {
    const int* tgt_in = (const int*)d_in[0];
    const int* tgt_out = (const int*)d_in[1];
    const int* src_lens = (const int*)d_in[2];
    const float* src = (const float*)d_in[3];
    const float* last_state = (const float*)d_in[4];
    const float* last_cell = (const float*)d_in[5];
    const float* emb = (const float*)d_in[6];
    const float* Wih = (const float*)d_in[7];
    const float* Whh = (const float*)d_in[8];
    const float* bih = (const float*)d_in[9];
    const float* bhh = (const float*)d_in[10];
    const float* Wattn = (const float*)d_in[11];
    const float* Wgen = (const float*)d_in[12];
    const float* bgen = (const float*)d_in[13];
    const float* Wread = (const float*)d_in[14];
    float* out = (float*)d_out;

    float* ws = (float*)d_ws;
    float* G0T      = ws;                    // 2,097,152 f
    float* U        = G0T + 2097152;         // 3,276,800 f
    float* WaRT     = U + 3276800;           // 262,144 f
    unsigned short* dh  = (unsigned short*)(WaRT + 262144);  // 524,288 u16
    unsigned short* dl  = dh + 524288;
    unsigned short* dhk = dl + 524288;       // chunk-major
    unsigned short* dlk = dhk + 524288;
    float* h_hist   = (float*)(dlk + 524288);
    float* att_hist = h_hist + 524288;
    float* xT       = att_hist + 524288;     // 49,152 f
    float* h_b      = xT + 49152;            // 16,384 f
    float* scb      = h_b + 16384;           // 8,192 f
    float4* part    = (float4*)(scb + 8192); // 200,704 float4
    float* tgtl     = ((float*)part) + 802816; // 1,024 f
    int* bar        = (int*)(tgtl + 1024);     // 2,048 ints
    unsigned short* whk = (unsigned short*)(bar + 2048);   // VP_*512 u16
    unsigned short* wlk = whk + (size_t)VP_ * 512;
    // prologue/dec bf16 operands
    unsigned short* sh    = wlk + (size_t)VP_ * 512;  // 3,276,800 u16
    unsigned short* sl    = sh + 3276800;
    unsigned short* wah   = sl + 3276800;             // 262,144
    unsigned short* wal   = wah + 262144;
    unsigned short* wih_h = wal + 262144;             // 1,048,576
    unsigned short* wih_l = wih_h + 1048576;
    unsigned short* eh    = wih_l + 1048576;          // 524,288
    unsigned short* el    = eh + 524288;
    unsigned short* wgh   = el + 524288;              // 786,432
    unsigned short* wgl   = wgh + 786432;
    unsigned short* hh    = wgl + 786432;             // 524,288
    unsigned short* hl    = hh + 524288;
    unsigned short* ath   = hl + 524288;
    unsigned short* atl   = ath + 524288;

    const size_t need = (size_t)((char*)(atl + 524288) - (char*)ws);
    const int pre = (ws_size >= need) ? 1 : 0;

    hipMemsetAsync(bar, 0, 8192, stream);

    k_init<<<64, 256, 0, stream>>>(last_state, xT);
    if (pre) {
        k_cvt<<<(CVT_R4 + 255) / 256, 256, 0, stream>>>(src, Wattn, Wih, emb, Wgen, tgt_in,
                                                        sh, sl, wah, wal, wih_h, wih_l,
                                                        eh, el, wgh, wgl);
        k_gbt<<<200, 256, 0, stream>>>(sh, sl, wah, wal, nullptr, nullptr, U, 2, 0);
        k_gbt<<<128, 256, 0, stream>>>(eh, el, wih_h, wih_l, bih, bhh, G0T, 8, 1);
    } else {
        k_g0<<<dim3(16, 16), 256, 0, stream>>>(tgt_in, emb, Wih, bih, bhh, G0T);
        k_u<<<dim3(100, 4), 256, 0, stream>>>(src, Wattn, U);
    }
    k_tr<<<dim3(16, 16), 256, 0, stream>>>(Wattn, WaRT);
    if (pre)
        k_wconv<<<12544, 256, 0, stream>>>(Wread, whk, wlk);

    k_scan<<<256, 512, 0, stream>>>(G0T, U, WaRT, Wih, Whh, src, src_lens, last_cell,
                                    xT, h_b, scb, h_hist, att_hist,
                                    hh, hl, ath, atl, pre, bar);

    if (pre) {
        k_gbt_dec<<<32, 256, 0, stream>>>(eh, el, hh, hl, ath, atl, wgh, wgl, bgen, dhk, dlk);
        k_read_pre<<<3200, 512, 0, stream>>>(dhk, dlk, whk, wlk, tgt_out, part, tgtl);
    } else {
        k_dec<<<dim3(16, 4), 256, 0, stream>>>(tgt_in, emb, h_hist, att_hist, Wgen, bgen, dh, dl);
        k_read<<<3200, 256, 0, stream>>>(dh, dl, Wread, tgt_out, part, tgtl);
    }
    k_merge<<<256, 256, 0, stream>>>(part, tgtl, tgt_out, out);
}

// Round 18
// 847.502 us; speedup vs baseline: 1.4846x; 1.0326x over previous
//
#include <hip/hip_runtime.h>
#include <math.h>

#define T_ 32
#define B_ 32
#define S_ 200
#define E_ 512
#define H_ 512
#define V_ 50000
#define VP_ 50176   // padded rows for chunk-major bf16 W
#define G4_ 2048
#define NCH 196     // ceil(50000/256)

using bf16x8 = __attribute__((ext_vector_type(8))) __bf16;
using f32x4  = __attribute__((ext_vector_type(4))) float;

__device__ __forceinline__ float sigf(float x) { return 1.f / (1.f + expf(-x)); }

__device__ __forceinline__ unsigned short f2bf(float v) {
    unsigned int x = __float_as_uint(v);
    return (unsigned short)((x + 0x7FFFu + ((x >> 16) & 1u)) >> 16);
}
__device__ __forceinline__ float bf2f(unsigned short b) {
    return __uint_as_float(((unsigned int)b) << 16);
}

// async global->LDS 16B copy
__device__ __forceinline__ void async16(void* lds, const void* g) {
    __builtin_amdgcn_global_load_lds(
        (const __attribute__((address_space(1))) unsigned int*)g,
        (__attribute__((address_space(3))) unsigned int*)lds, 16, 0, 0);
}

// Coherent LLC-level exchange (relaxed agent atomics -> sc1 load/store)
__device__ __forceinline__ void g_store(float* p, float v) {
    __hip_atomic_store(p, v, __ATOMIC_RELAXED, __HIP_MEMORY_SCOPE_AGENT);
}
__device__ __forceinline__ float g_load(const float* p) {
    return __hip_atomic_load(p, __ATOMIC_RELAXED, __HIP_MEMORY_SCOPE_AGENT);
}

// ---------------------------------------------------------------------------
// Fence-free grid barrier (proven rounds 5-17).
// ---------------------------------------------------------------------------
__device__ __forceinline__ void full_sync(int* bar, int ep) {
    __syncthreads();
    if (threadIdx.x == 0) {
        const int g = blockIdx.x & 7;
        int a = __hip_atomic_fetch_add(&bar[g * 32], 1, __ATOMIC_RELAXED, __HIP_MEMORY_SCOPE_AGENT);
        if (a == ep * 32 + 31) {
            int q = __hip_atomic_fetch_add(&bar[256], 1, __ATOMIC_RELAXED, __HIP_MEMORY_SCOPE_AGENT);
            if (q == ep * 8 + 7) {
                #pragma unroll
                for (int i = 0; i < 8; i++)
                    __hip_atomic_store(&bar[288 + i * 32], ep + 1, __ATOMIC_RELAXED, __HIP_MEMORY_SCOPE_AGENT);
            }
        }
        while (__hip_atomic_load(&bar[288 + g * 32], __ATOMIC_RELAXED, __HIP_MEMORY_SCOPE_AGENT) < ep + 1)
            __builtin_amdgcn_s_sleep(1);
    }
    __syncthreads();
}

__device__ __forceinline__ void sub_sync(int* bar, int bb, int t) {
    __syncthreads();
    if (threadIdx.x == 0) {
        __hip_atomic_fetch_add(&bar[544 + bb * 32], 1, __ATOMIC_RELAXED, __HIP_MEMORY_SCOPE_AGENT);
        while (__hip_atomic_load(&bar[544 + bb * 32], __ATOMIC_RELAXED, __HIP_MEMORY_SCOPE_AGENT) < (t + 1) * 8)
            __builtin_amdgcn_s_sleep(1);
    }
    __syncthreads();
}

// ---------------------------------------------------------------------------
// k_init: xT rows 0..511 att=0; rows 1024..1535 = last_state^T (h slot 1).
// ---------------------------------------------------------------------------
__global__ __launch_bounds__(256) void k_init(const float* __restrict__ last_state,
                                              float* __restrict__ xT) {
    const int f = blockIdx.x * 256 + threadIdx.x;   // 0..16383
    xT[f] = 0.f;
    const int k = f >> 5, b = f & 31;
    xT[32768 + f] = last_state[b * 512 + k];
}

// ---------------------------------------------------------------------------
// k_cvt: fp32 -> bf16 hi/lo for prologue/dec GEMM operands.
// ---------------------------------------------------------------------------
#define CVT_R0 819200
#define CVT_R1 (CVT_R0 + 65536)
#define CVT_R2 (CVT_R1 + 262144)
#define CVT_R3 (CVT_R2 + 131072)
#define CVT_R4 (CVT_R3 + 196608)
__global__ __launch_bounds__(256) void k_cvt(const float* __restrict__ src,
                                             const float* __restrict__ Wattn,
                                             const float* __restrict__ Wih,
                                             const float* __restrict__ emb,
                                             const float* __restrict__ Wgen,
                                             const int* __restrict__ tgt_in,
                                             unsigned short* __restrict__ sh,
                                             unsigned short* __restrict__ sl,
                                             unsigned short* __restrict__ wah,
                                             unsigned short* __restrict__ wal,
                                             unsigned short* __restrict__ wih_h,
                                             unsigned short* __restrict__ wih_l,
                                             unsigned short* __restrict__ eh,
                                             unsigned short* __restrict__ el,
                                             unsigned short* __restrict__ wgh,
                                             unsigned short* __restrict__ wgl) {
    const int u = blockIdx.x * 256 + threadIdx.x;
    if (u >= CVT_R4) return;
    const float* sp;
    unsigned short *dh_, *dl_;
    size_t doff;
    if (u < CVT_R0) {
        sp = src + (size_t)u * 4;
        dh_ = sh; dl_ = sl; doff = (size_t)u * 4;
    } else if (u < CVT_R1) {
        const int idx = u - CVT_R0;
        const int k4 = idx & 127, n = idx >> 7;
        sp = Wattn + (size_t)n * 1024 + k4 * 4;
        dh_ = wah; dl_ = wal; doff = (size_t)n * 512 + k4 * 4;
    } else if (u < CVT_R2) {
        const int idx = u - CVT_R1;
        const int k4 = idx & 127, j = idx >> 7;
        sp = Wih + (size_t)j * 1024 + k4 * 4;
        dh_ = wih_h; dl_ = wih_l; doff = (size_t)j * 512 + k4 * 4;
    } else if (u < CVT_R3) {
        const int idx = u - CVT_R2;
        const int k4 = idx & 127, m = idx >> 7;
        sp = emb + (size_t)tgt_in[m] * 512 + k4 * 4;
        dh_ = eh; dl_ = el; doff = (size_t)m * 512 + k4 * 4;
    } else {
        const int idx = u - CVT_R3;
        const int n = idx / 384, k4 = idx - n * 384;
        sp = Wgen + (size_t)n * 1536 + k4 * 4;
        dh_ = wgh; dl_ = wgl; doff = (size_t)n * 1536 + k4 * 4;
    }
    const float4 v = *(const float4*)sp;
    const float vv[4] = {v.x, v.y, v.z, v.w};
    unsigned int hb[4], lb[4];
    #pragma unroll
    for (int e = 0; e < 4; e++) {
        hb[e] = f2bf(vv[e]);
        lb[e] = f2bf(vv[e] - bf2f((unsigned short)hb[e]));
    }
    *(uint2*)(dh_ + doff) = make_uint2(hb[0] | (hb[1] << 16), hb[2] | (hb[3] << 16));
    *(uint2*)(dl_ + doff) = make_uint2(lb[0] | (lb[1] << 16), lb[2] | (lb[3] << 16));
}

// ---------------------------------------------------------------------------
// k_gbt: C = A . B^T via bf16-split MFMA with LDS-staged tiles. 64x256, K=512.
// mode 0: out[m*512+n] (U). mode 1: out[n*1024+m] + bih[n]+bhh[n] (G0T).
// ---------------------------------------------------------------------------
__global__ __launch_bounds__(256) void k_gbt(const unsigned short* __restrict__ Ah,
                                             const unsigned short* __restrict__ Al,
                                             const unsigned short* __restrict__ Bh,
                                             const unsigned short* __restrict__ Bl,
                                             const float* __restrict__ bih,
                                             const float* __restrict__ bhh,
                                             float* __restrict__ out,
                                             int nbn, int mode) {
    __shared__ __align__(16) unsigned short BhL[4][256][8];
    __shared__ __align__(16) unsigned short BlL[4][256][8];
    __shared__ __align__(16) unsigned short AhL[4][64][8];
    __shared__ __align__(16) unsigned short AlL[4][64][8];
    const int m0 = (blockIdx.x / nbn) * 64;
    const int n0 = (blockIdx.x % nbn) * 256;
    const int tid = threadIdx.x;
    const int lane = tid & 63, wid = tid >> 6;
    const int wr = wid >> 1, wc = wid & 1;
    const int l15 = lane & 15, lk = lane >> 4;

    f32x4 acc[2][8];
    #pragma unroll
    for (int mt = 0; mt < 2; mt++)
        #pragma unroll
        for (int nt = 0; nt < 8; nt++) acc[mt][nt] = {0.f, 0.f, 0.f, 0.f};

    for (int kc = 0; kc < 512; kc += 32) {
        {
            #pragma unroll
            for (int g = 0; g < 4; g++) {
                const size_t bo = (size_t)(n0 + tid) * 512 + kc + g * 8;
                *(uint4*)&BhL[g][tid][0] = *(const uint4*)(Bh + bo);
                *(uint4*)&BlL[g][tid][0] = *(const uint4*)(Bl + bo);
            }
        }
        {
            const int row = tid >> 2, g = tid & 3;
            const size_t ao = (size_t)(m0 + row) * 512 + kc + g * 8;
            *(uint4*)&AhL[g][row][0] = *(const uint4*)(Ah + ao);
            *(uint4*)&AlL[g][row][0] = *(const uint4*)(Al + ao);
        }
        __syncthreads();
        {
            bf16x8 afh[2], afl[2];
            #pragma unroll
            for (int mt = 0; mt < 2; mt++) {
                const int r = wr * 32 + mt * 16 + l15;
                afh[mt] = *(const bf16x8*)&AhL[lk][r][0];
                afl[mt] = *(const bf16x8*)&AlL[lk][r][0];
            }
            #pragma unroll
            for (int nt = 0; nt < 8; nt++) {
                const int nn = wc * 128 + nt * 16 + l15;
                bf16x8 bh = *(const bf16x8*)&BhL[lk][nn][0];
                bf16x8 bl = *(const bf16x8*)&BlL[lk][nn][0];
                #pragma unroll
                for (int mt = 0; mt < 2; mt++) {
                    acc[mt][nt] = __builtin_amdgcn_mfma_f32_16x16x32_bf16(afh[mt], bh, acc[mt][nt], 0, 0, 0);
                    acc[mt][nt] = __builtin_amdgcn_mfma_f32_16x16x32_bf16(afl[mt], bh, acc[mt][nt], 0, 0, 0);
                    acc[mt][nt] = __builtin_amdgcn_mfma_f32_16x16x32_bf16(afh[mt], bl, acc[mt][nt], 0, 0, 0);
                }
            }
        }
        __syncthreads();
    }
    #pragma unroll
    for (int mt = 0; mt < 2; mt++)
        #pragma unroll
        for (int reg = 0; reg < 4; reg++) {
            const int row = m0 + wr * 32 + mt * 16 + lk * 4 + reg;
            #pragma unroll
            for (int nt = 0; nt < 8; nt++) {
                const int col = n0 + wc * 128 + nt * 16 + l15;
                const float v = acc[mt][nt][reg];
                if (mode == 0) out[(size_t)row * 512 + col] = v;
                else           out[(size_t)col * 1024 + row] = v + bih[col] + bhh[col];
            }
        }
}

// ---------------------------------------------------------------------------
// k_gbt_dec: dec GEMM via bf16-split MFMA, LDS-staged. M=1024, N=512,
// K=1536 (A regions emb|h|att), tanh(+bgen) -> chunk-major dhk/dlk. Grid 32.
// ---------------------------------------------------------------------------
__global__ __launch_bounds__(256) void k_gbt_dec(const unsigned short* __restrict__ eh,
                                                 const unsigned short* __restrict__ el,
                                                 const unsigned short* __restrict__ hh,
                                                 const unsigned short* __restrict__ hl,
                                                 const unsigned short* __restrict__ ath,
                                                 const unsigned short* __restrict__ atl,
                                                 const unsigned short* __restrict__ wgh,
                                                 const unsigned short* __restrict__ wgl,
                                                 const float* __restrict__ bgen,
                                                 unsigned short* __restrict__ dhk,
                                                 unsigned short* __restrict__ dlk) {
    __shared__ __align__(16) unsigned short BhL[4][256][8];
    __shared__ __align__(16) unsigned short BlL[4][256][8];
    __shared__ __align__(16) unsigned short AhL[4][64][8];
    __shared__ __align__(16) unsigned short AlL[4][64][8];
    const int m0 = (blockIdx.x >> 1) * 64;
    const int n0 = (blockIdx.x & 1) * 256;
    const int tid = threadIdx.x;
    const int lane = tid & 63, wid = tid >> 6;
    const int wr = wid >> 1, wc = wid & 1;
    const int l15 = lane & 15, lk = lane >> 4;

    f32x4 acc[2][8];
    #pragma unroll
    for (int mt = 0; mt < 2; mt++)
        #pragma unroll
        for (int nt = 0; nt < 8; nt++) acc[mt][nt] = {0.f, 0.f, 0.f, 0.f};

    for (int kc = 0; kc < 1536; kc += 32) {
        const unsigned short *Ahp, *Alp;
        int ko;
        if (kc < 512)       { Ahp = eh;  Alp = el;  ko = kc; }
        else if (kc < 1024) { Ahp = hh;  Alp = hl;  ko = kc - 512; }
        else                { Ahp = ath; Alp = atl; ko = kc - 1024; }
        {
            #pragma unroll
            for (int g = 0; g < 4; g++) {
                const size_t bo = (size_t)(n0 + tid) * 1536 + kc + g * 8;
                *(uint4*)&BhL[g][tid][0] = *(const uint4*)(wgh + bo);
                *(uint4*)&BlL[g][tid][0] = *(const uint4*)(wgl + bo);
            }
        }
        {
            const int row = tid >> 2, g = tid & 3;
            const size_t ao = (size_t)(m0 + row) * 512 + ko + g * 8;
            *(uint4*)&AhL[g][row][0] = *(const uint4*)(Ahp + ao);
            *(uint4*)&AlL[g][row][0] = *(const uint4*)(Alp + ao);
        }
        __syncthreads();
        {
            bf16x8 afh[2], afl[2];
            #pragma unroll
            for (int mt = 0; mt < 2; mt++) {
                const int r = wr * 32 + mt * 16 + l15;
                afh[mt] = *(const bf16x8*)&AhL[lk][r][0];
                afl[mt] = *(const bf16x8*)&AlL[lk][r][0];
            }
            #pragma unroll
            for (int nt = 0; nt < 8; nt++) {
                const int nn = wc * 128 + nt * 16 + l15;
                bf16x8 bh = *(const bf16x8*)&BhL[lk][nn][0];
                bf16x8 bl = *(const bf16x8*)&BlL[lk][nn][0];
                #pragma unroll
                for (int mt = 0; mt < 2; mt++) {
                    acc[mt][nt] = __builtin_amdgcn_mfma_f32_16x16x32_bf16(afh[mt], bh, acc[mt][nt], 0, 0, 0);
                    acc[mt][nt] = __builtin_amdgcn_mfma_f32_16x16x32_bf16(afl[mt], bh, acc[mt][nt], 0, 0, 0);
                    acc[mt][nt] = __builtin_amdgcn_mfma_f32_16x16x32_bf16(afh[mt], bl, acc[mt][nt], 0, 0, 0);
                }
            }
        }
        __syncthreads();
    }
    #pragma unroll
    for (int mt = 0; mt < 2; mt++)
        #pragma unroll
        for (int reg = 0; reg < 4; reg++) {
            const int row = m0 + wr * 32 + mt * 16 + lk * 4 + reg;
            #pragma unroll
            for (int nt = 0; nt < 8; nt++) {
                const int col = n0 + wc * 128 + nt * 16 + l15;
                const float v = tanhf(acc[mt][nt][reg] + bgen[col]);
                const unsigned short hb = f2bf(v);
                const unsigned short lb = f2bf(v - bf2f(hb));
                const size_t ca = (size_t)(col >> 5) * 32768 + (size_t)(row >> 6) * 2048
                                + (size_t)(row & 63) * 32 + (col & 31);
                dhk[ca] = hb;
                dlk[ca] = lb;
            }
        }
}

// ---------------------------------------------------------------------------
// k_g0 (fp32 fallback)
// ---------------------------------------------------------------------------
__global__ __launch_bounds__(256) void k_g0(const int* __restrict__ tgt_in,
                                            const float* __restrict__ emb,
                                            const float* __restrict__ Wih,
                                            const float* __restrict__ bih,
                                            const float* __restrict__ bhh,
                                            float* __restrict__ G0T) {
    __shared__ float a_s[32][66];
    __shared__ float w_s[32][130];
    const int tid = threadIdx.x;
    const int m0 = blockIdx.x * 64, n0 = blockIdx.y * 128;
    const int mq = tid >> 5, nq = tid & 31;
    float acc[8][4] = {};
    for (int k0 = 0; k0 < 512; k0 += 32) {
        {
            const int mm = tid >> 2, kq = tid & 3, kk = kq * 8;
            const float* row = emb + (size_t)tgt_in[m0 + mm] * E_ + k0 + kk;
            float4 v0 = *(const float4*)(row);
            float4 v1 = *(const float4*)(row + 4);
            a_s[kk + 0][mm] = v0.x; a_s[kk + 1][mm] = v0.y;
            a_s[kk + 2][mm] = v0.z; a_s[kk + 3][mm] = v0.w;
            a_s[kk + 4][mm] = v1.x; a_s[kk + 5][mm] = v1.y;
            a_s[kk + 6][mm] = v1.z; a_s[kk + 7][mm] = v1.w;
        }
        {
            const int nn = tid >> 1, kq = tid & 1, kk = kq * 16;
            const float* row = Wih + (size_t)(n0 + nn) * 1024 + k0 + kk;
            #pragma unroll
            for (int u = 0; u < 4; u++) {
                float4 v = *(const float4*)(row + u * 4);
                w_s[kk + u * 4 + 0][nn] = v.x; w_s[kk + u * 4 + 1][nn] = v.y;
                w_s[kk + u * 4 + 2][nn] = v.z; w_s[kk + u * 4 + 3][nn] = v.w;
            }
        }
        __syncthreads();
        for (int k = 0; k < 32; k++) {
            float a[8], wv[4];
            #pragma unroll
            for (int i = 0; i < 8; i++) a[i] = a_s[k][mq + 8 * i];
            #pragma unroll
            for (int p = 0; p < 4; p++) wv[p] = w_s[k][nq + 32 * p];
            #pragma unroll
            for (int i = 0; i < 8; i++)
                #pragma unroll
                for (int p = 0; p < 4; p++) acc[i][p] += a[i] * wv[p];
        }
        __syncthreads();
    }
    #pragma unroll
    for (int i = 0; i < 8; i++) {
        const int m = m0 + mq + 8 * i;
        #pragma unroll
        for (int p = 0; p < 4; p++) {
            const int n = n0 + nq + 32 * p;
            G0T[(size_t)n * 1024 + m] = acc[i][p] + bih[n] + bhh[n];
        }
    }
}

// ---------------------------------------------------------------------------
// k_u (fp32 fallback)
// ---------------------------------------------------------------------------
__global__ __launch_bounds__(256) void k_u(const float* __restrict__ src,
                                           const float* __restrict__ Wattn,
                                           float* __restrict__ U) {
    __shared__ float a_s[32][66];
    __shared__ float w_s[32][130];
    const int tid = threadIdx.x;
    const int m0 = blockIdx.x * 64, n0 = blockIdx.y * 128;
    const int mq = tid >> 5, nq = tid & 31;
    float acc[8][4] = {};
    for (int k0 = 0; k0 < 512; k0 += 32) {
        {
            const int mm = tid >> 2, kq = tid & 3, kk = kq * 8;
            const float* row = src + (size_t)(m0 + mm) * 512 + k0 + kk;
            float4 v0 = *(const float4*)(row);
            float4 v1 = *(const float4*)(row + 4);
            a_s[kk + 0][mm] = v0.x; a_s[kk + 1][mm] = v0.y;
            a_s[kk + 2][mm] = v0.z; a_s[kk + 3][mm] = v0.w;
            a_s[kk + 4][mm] = v1.x; a_s[kk + 5][mm] = v1.y;
            a_s[kk + 6][mm] = v1.z; a_s[kk + 7][mm] = v1.w;
        }
        {
            const int nn = tid >> 1, kq = tid & 1, kk = kq * 16;
            const float* row = Wattn + (size_t)(n0 + nn) * 1024 + k0 + kk;
            #pragma unroll
            for (int u = 0; u < 4; u++) {
                float4 v = *(const float4*)(row + u * 4);
                w_s[kk + u * 4 + 0][nn] = v.x; w_s[kk + u * 4 + 1][nn] = v.y;
                w_s[kk + u * 4 + 2][nn] = v.z; w_s[kk + u * 4 + 3][nn] = v.w;
            }
        }
        __syncthreads();
        for (int k = 0; k < 32; k++) {
            float a[8], wv[4];
            #pragma unroll
            for (int i = 0; i < 8; i++) a[i] = a_s[k][mq + 8 * i];
            #pragma unroll
            for (int p = 0; p < 4; p++) wv[p] = w_s[k][nq + 32 * p];
            #pragma unroll
            for (int i = 0; i < 8; i++)
                #pragma unroll
                for (int p = 0; p < 4; p++) acc[i][p] += a[i] * wv[p];
        }
        __syncthreads();
    }
    #pragma unroll
    for (int i = 0; i < 8; i++) {
        const int m = m0 + mq + 8 * i;
        #pragma unroll
        for (int p = 0; p < 4; p++)
            U[(size_t)m * 512 + n0 + nq + 32 * p] = acc[i][p];
    }
}

// ---------------------------------------------------------------------------
// k_tr: WaRT[k][j] = W_attn[j][512+k]
// ---------------------------------------------------------------------------
__global__ __launch_bounds__(256) void k_tr(const float* __restrict__ Wattn,
                                            float* __restrict__ WaRT) {
    __shared__ float t_s[32][33];
    const int tid = threadIdx.x;
    const int bx = blockIdx.x, by = blockIdx.y;
    {
        const int jj = tid >> 3, kq = (tid & 7) * 4;
        float4 v = *(const float4*)(Wattn + (size_t)(by * 32 + jj) * 1024 + 512 + bx * 32 + kq);
        t_s[jj][kq + 0] = v.x; t_s[jj][kq + 1] = v.y;
        t_s[jj][kq + 2] = v.z; t_s[jj][kq + 3] = v.w;
    }
    __syncthreads();
    {
        const int kk = tid >> 3, jq = (tid & 7) * 4;
        float4 w;
        w.x = t_s[jq + 0][kk]; w.y = t_s[jq + 1][kk];
        w.z = t_s[jq + 2][kk]; w.w = t_s[jq + 3][kk];
        *(float4*)(WaRT + (size_t)(bx * 32 + kk) * 512 + by * 32 + jq) = w;
    }
}

// ---------------------------------------------------------------------------
// k_wconv: Wread fp32 -> bf16 hi/lo, chunk-major with BAKED bank swizzle.
// ---------------------------------------------------------------------------
__global__ __launch_bounds__(256) void k_wconv(const float* __restrict__ Wread,
                                               unsigned short* __restrict__ whk,
                                               unsigned short* __restrict__ wlk) {
    const size_t q = (size_t)blockIdx.x * 256 + threadIdx.x;
    const size_t k8 = q * 8;
    const int n = (int)(k8 >> 9);
    const int k = (int)(k8 & 511);
    if (n >= VP_) return;
    uint4 h4, l4;
    if (n < V_) {
        float4 p0 = *(const float4*)(Wread + (size_t)n * 512 + k);
        float4 p1 = *(const float4*)(Wread + (size_t)n * 512 + k + 4);
        float v[8] = {p0.x, p0.y, p0.z, p0.w, p1.x, p1.y, p1.z, p1.w};
        unsigned int hb[8], lb[8];
        #pragma unroll
        for (int e = 0; e < 8; e++) {
            hb[e] = f2bf(v[e]);
            lb[e] = f2bf(v[e] - bf2f((unsigned short)hb[e]));
        }
        h4 = make_uint4(hb[0] | (hb[1] << 16), hb[2] | (hb[3] << 16),
                        hb[4] | (hb[5] << 16), hb[6] | (hb[7] << 16));
        l4 = make_uint4(lb[0] | (lb[1] << 16), lb[2] | (lb[3] << 16),
                        lb[4] | (lb[5] << 16), lb[6] | (lb[7] << 16));
    } else {
        h4 = make_uint4(0, 0, 0, 0);
        l4 = make_uint4(0, 0, 0, 0);
    }
    const int lk = (k >> 3) & 3;
    const size_t dst = (size_t)(k >> 5) * ((size_t)VP_ * 32) + (size_t)n * 32
                     + (size_t)((lk ^ ((n >> 1) & 3)) * 8);
    *(uint4*)(whk + dst) = h4;
    *(uint4*)(wlk + dst) = l4;
}

// ---------------------------------------------------------------------------
// Persistent scan (round-11 proven; + bf16-split h/att emission).
// ---------------------------------------------------------------------------
__global__ __launch_bounds__(512) void k_scan(const float* __restrict__ G0T,
                                              const float* __restrict__ U,
                                              const float* __restrict__ WaRT,
                                              const float* __restrict__ Wih,
                                              const float* __restrict__ Whh,
                                              const float* __restrict__ src,
                                              const int* __restrict__ lens,
                                              const float* __restrict__ last_cell,
                                              float* __restrict__ xT,
                                              float* __restrict__ h_b,
                                              float* __restrict__ scb,
                                              float* __restrict__ h_hist,
                                              float* __restrict__ att_hist,
                                              unsigned short* __restrict__ hh,
                                              unsigned short* __restrict__ hl,
                                              unsigned short* __restrict__ ath,
                                              unsigned short* __restrict__ atl,
                                              int pre,
                                              int* __restrict__ bar) {
    __shared__ float Wl[8 * 1024];
    __shared__ float Ul[200 * 64];
    __shared__ float red_s[2048];
    __shared__ float gate_s[256];
    __shared__ float h_s[512];
    __shared__ float al[256];
    __shared__ float pr[512];

    const int blk = blockIdx.x, tid = threadIdx.x;
    const int u0 = blk * 2;
    const int bb = blk & 31, p = blk >> 5;

    for (int f = tid; f < 2048; f += 512) {
        const int r = f >> 8, k = (f & 255) * 4;
        const int j = (r >> 1) * 512 + u0 + (r & 1);
        float4 v;
        if (k < 512) v = *(const float4*)(Wih + (size_t)j * 1024 + 512 + k);
        else         v = *(const float4*)(Whh + (size_t)j * 512 + (k - 512));
        *(float4*)&Wl[r * 1024 + k] = v;
    }
    for (int f = tid; f < 3200; f += 512) {
        const int s = f >> 4, q = (f & 15) * 4;
        *(float4*)&Ul[s * 64 + q] = *(const float4*)(U + ((size_t)bb * S_ + s) * 512 + p * 64 + q);
    }
    float creg = (tid < 64) ? last_cell[(tid & 31) * 512 + u0 + (tid >> 5)] : 0.f;
    __syncthreads();

    const int w = tid >> 6, lane = tid & 63;
    const int hf = lane >> 5, b = lane & 31;
    const int len = lens[bb];

    for (int t = 0; t < T_; t++) {
        // -------- Phase A: gates + pointwise ------------------------------
        {
            const int hoff = ((t + 1) & 1) * 512;        // slot holding h(t-1)
            const int kbase = w * 128 + hf * 64;
            const float* xp = (kbase < 512)
                ? (xT + (size_t)kbase * 32 + b)
                : (xT + (size_t)(512 + hoff + (kbase - 512)) * 32 + b);
            float acc[8] = {};
            #pragma unroll
            for (int kk = 0; kk < 64; kk += 8) {
                float xv[8];
                #pragma unroll
                for (int i = 0; i < 8; i++)
                    xv[i] = g_load(xp + (size_t)(kk + i) * 32);
                #pragma unroll
                for (int r = 0; r < 8; r++) {
                    const float* wr = &Wl[r * 1024 + kbase + kk];
                    float s0 = xv[0] * wr[0] + xv[1] * wr[1] + xv[2] * wr[2] + xv[3] * wr[3];
                    float s1 = xv[4] * wr[4] + xv[5] * wr[5] + xv[6] * wr[6] + xv[7] * wr[7];
                    acc[r] += s0 + s1;
                }
            }
            #pragma unroll
            for (int r = 0; r < 8; r++) acc[r] += __shfl_xor(acc[r], 32);
            if (hf == 0) {
                #pragma unroll
                for (int r = 0; r < 8; r++) red_s[w * 256 + r * 32 + b] = acc[r];
            }
            __syncthreads();
            if (tid < 256) {
                const int r = tid >> 5, b2 = tid & 31;
                const int j = (r >> 1) * 512 + u0 + (r & 1);
                float g = G0T[(size_t)j * 1024 + t * 32 + b2];
                #pragma unroll
                for (int ww = 0; ww < 8; ww++) g += red_s[ww * 256 + r * 32 + b2];
                gate_s[r * 32 + b2] = g;
            }
            __syncthreads();
            if (tid < 64) {
                const int ui = tid >> 5, b2 = tid & 31, u = u0 + ui;
                const float gi = gate_s[(0 + ui) * 32 + b2];
                const float gf = gate_s[(2 + ui) * 32 + b2];
                const float gg = gate_s[(4 + ui) * 32 + b2];
                const float go = gate_s[(6 + ui) * 32 + b2];
                const float cn = sigf(gf) * creg + sigf(gi) * tanhf(gg);
                const float hn = sigf(go) * tanhf(cn);
                creg = cn;
                g_store(&xT[(size_t)(512 + (t & 1) * 512 + u) * 32 + b2], hn);
                g_store(&h_b[b2 * 512 + u], hn);
                h_hist[((size_t)t * B_ + b2) * 512 + u] = hn;
                if (pre) {
                    const unsigned short hb2 = f2bf(hn);
                    const size_t ho = ((size_t)t * B_ + b2) * 512 + u;
                    hh[ho] = hb2;
                    hl[ho] = f2bf(hn - bf2f(hb2));
                }
            }
        }
        full_sync(bar, 2 * t);

        // -------- Phase B: scores -----------------------------------------
        {
            h_s[tid] = g_load(&h_b[bb * 512 + tid]);
            __syncthreads();
            for (int i = w; i < 25; i += 8) {
                const int s = p * 25 + i;
                const float* sr = src + ((size_t)bb * S_ + s) * 512;
                const float4 x0 = *(const float4*)(sr + lane * 4);
                const float4 x1 = *(const float4*)(sr + 256 + lane * 4);
                const float4 h0 = *(const float4*)(&h_s[lane * 4]);
                const float4 h1 = *(const float4*)(&h_s[256 + lane * 4]);
                float a = x0.x * h0.x + x0.y * h0.y + x0.z * h0.z + x0.w * h0.w
                        + x1.x * h1.x + x1.y * h1.y + x1.z * h1.z + x1.w * h1.w;
                #pragma unroll
                for (int mk = 1; mk < 64; mk <<= 1) a += __shfl_xor(a, mk);
                if (lane == 0) g_store(&scb[bb * 256 + s], (s < len) ? a : -INFINITY);
            }
        }
        sub_sync(bar, bb, t);

        // -------- Phase C: softmax + att slice ----------------------------
        {
            if (tid < 64) {
                const float v0 = g_load(&scb[bb * 256 + tid]);
                const float v1 = g_load(&scb[bb * 256 + 64 + tid]);
                const float v2 = g_load(&scb[bb * 256 + 128 + tid]);
                const float v3 = (tid < 8) ? g_load(&scb[bb * 256 + 192 + tid]) : -INFINITY;
                float m = fmaxf(fmaxf(v0, v1), fmaxf(v2, v3));
                #pragma unroll
                for (int mk = 1; mk < 64; mk <<= 1) m = fmaxf(m, __shfl_xor(m, mk));
                const float e0 = expf(v0 - m), e1 = expf(v1 - m), e2 = expf(v2 - m);
                const float e3 = (tid < 8) ? expf(v3 - m) : 0.f;
                float sum = (e0 + e1) + (e2 + e3);
                #pragma unroll
                for (int mk = 1; mk < 64; mk <<= 1) sum += __shfl_xor(sum, mk);
                const float inv = 1.f / sum;
                al[tid] = e0 * inv; al[64 + tid] = e1 * inv; al[128 + tid] = e2 * inv;
                if (tid < 8) al[192 + tid] = e3 * inv;
            }
            __syncthreads();
            const int jl = tid & 63, sg = tid >> 6;
            float uacc = 0.f;
            #pragma unroll 5
            for (int s = sg * 25; s < sg * 25 + 25; s++)
                uacc += al[s] * Ul[s * 64 + jl];
            const float* wc0 = WaRT + (size_t)(sg * 64) * 512 + p * 64 + jl;
            const float* hp = &h_s[sg * 64];
            float c0 = 0.f, c1 = 0.f;
            #pragma unroll 8
            for (int kk = 0; kk < 64; kk += 2) {
                c0 += hp[kk] * wc0[(size_t)kk * 512];
                c1 += hp[kk + 1] * wc0[(size_t)(kk + 1) * 512];
            }
            pr[tid] = uacc + c0 + c1;
            __syncthreads();
            if (tid < 64) {
                float tot = 0.f;
                #pragma unroll
                for (int sgg = 0; sgg < 8; sgg++) tot += pr[sgg * 64 + tid];
                const float a = tanhf(tot);
                g_store(&xT[(size_t)(p * 64 + tid) * 32 + bb], a);
                att_hist[((size_t)t * B_ + bb) * 512 + p * 64 + tid] = a;
                if (pre) {
                    const unsigned short ab = f2bf(a);
                    const size_t ao = ((size_t)t * B_ + bb) * 512 + p * 64 + tid;
                    ath[ao] = ab;
                    atl[ao] = f2bf(a - bf2f(ab));
                }
            }
        }
        full_sync(bar, 2 * t + 1);
    }
}

// ---------------------------------------------------------------------------
// k_dec (fp32 fallback)
// ---------------------------------------------------------------------------
__global__ __launch_bounds__(256) void k_dec(const int* __restrict__ tgt_in,
                                             const float* __restrict__ emb,
                                             const float* __restrict__ h_hist,
                                             const float* __restrict__ att_hist,
                                             const float* __restrict__ Wgen,
                                             const float* __restrict__ bgen,
                                             unsigned short* __restrict__ dh,
                                             unsigned short* __restrict__ dl) {
    __shared__ float a_s[32][66];
    __shared__ float w_s[32][130];
    const int tid = threadIdx.x;
    const int m0 = blockIdx.x * 64, n0 = blockIdx.y * 128;
    const int mq = tid >> 5, nq = tid & 31;
    float acc[8][4] = {};
    for (int k0 = 0; k0 < 1536; k0 += 32) {
        {
            const int mm = tid >> 2, kq = tid & 3, kk = kq * 8;
            const int m = m0 + mm;
            const float* row;
            if (k0 < 512)       row = emb + (size_t)tgt_in[m] * E_ + k0;
            else if (k0 < 1024) row = h_hist + (size_t)m * 512 + (k0 - 512);
            else                row = att_hist + (size_t)m * 512 + (k0 - 1024);
            row += kk;
            float4 v0 = *(const float4*)(row);
            float4 v1 = *(const float4*)(row + 4);
            a_s[kk + 0][mm] = v0.x; a_s[kk + 1][mm] = v0.y;
            a_s[kk + 2][mm] = v0.z; a_s[kk + 3][mm] = v0.w;
            a_s[kk + 4][mm] = v1.x; a_s[kk + 5][mm] = v1.y;
            a_s[kk + 6][mm] = v1.z; a_s[kk + 7][mm] = v1.w;
        }
        {
            const int nn = tid >> 1, kq = tid & 1, kk = kq * 16;
            const float* row = Wgen + (size_t)(n0 + nn) * 1536 + k0 + kk;
            #pragma unroll
            for (int u = 0; u < 4; u++) {
                float4 v = *(const float4*)(row + u * 4);
                w_s[kk + u * 4 + 0][nn] = v.x; w_s[kk + u * 4 + 1][nn] = v.y;
                w_s[kk + u * 4 + 2][nn] = v.z; w_s[kk + u * 4 + 3][nn] = v.w;
            }
        }
        __syncthreads();
        for (int k = 0; k < 32; k++) {
            float a[8], wv[4];
            #pragma unroll
            for (int i = 0; i < 8; i++) a[i] = a_s[k][mq + 8 * i];
            #pragma unroll
            for (int pq = 0; pq < 4; pq++) wv[pq] = w_s[k][nq + 32 * pq];
            #pragma unroll
            for (int i = 0; i < 8; i++)
                #pragma unroll
                for (int pq = 0; pq < 4; pq++) acc[i][pq] += a[i] * wv[pq];
        }
        __syncthreads();
    }
    #pragma unroll
    for (int i = 0; i < 8; i++) {
        const int m = m0 + mq + 8 * i;
        #pragma unroll
        for (int pq = 0; pq < 4; pq++) {
            const int n = n0 + nq + 32 * pq;
            const float v = tanhf(acc[i][pq] + bgen[n]);
            const unsigned short hb = f2bf(v);
            dh[(size_t)m * 512 + n] = hb;
            dl[(size_t)m * 512 + n] = f2bf(v - bf2f(hb));
        }
    }
}

// ===========================================================================
// k_read_pre: 512 threads (8 waves), 2 m-tiles per block (128 rows),
// double-buffered B stage via global_load_lds (stage k+1 before MFMA of k,
// ONE sync per chunk). acc = 2x8 f32x4/thread (~64 VGPR); A-frags per-lane
// direct from chunk-major dhk/dlk. Grid 1600 XCD-grouped, LDS 64 KB.
// ===========================================================================
__global__ __launch_bounds__(512) void k_read_pre(const unsigned short* __restrict__ dhk,
                                                  const unsigned short* __restrict__ dlk,
                                                  const unsigned short* __restrict__ whk,
                                                  const unsigned short* __restrict__ wlk,
                                                  const int* __restrict__ tgt_out,
                                                  float4* __restrict__ part,
                                                  float* __restrict__ tgt_logit) {
    __shared__ __align__(16) unsigned short BhL[2][8192];   // 32 KB
    __shared__ __align__(16) unsigned short BlL[2][8192];   // 32 KB
    __shared__ float ep_max[128][2];
    __shared__ int   ep_idx[128][2];
    __shared__ float ep_fin[128];
    __shared__ int   ep_fidx[128];
    __shared__ float ep_sum[128][2];

    const int xcd = blockIdx.x & 7;
    const int idx = blockIdx.x >> 3;
    const int m2  = idx & 7;              // 128-row tile 0..7
    const int group = idx >> 3;           // 0..24
    const int ch = group * 8 + xcd;
    if (ch >= NCH) return;
    const int m0 = m2 * 128, n0 = ch * 256;

    const int tid = threadIdx.x;
    const int lane = tid & 63, wid = tid >> 6;
    const int wr = wid >> 1, wc = wid & 1;
    const int l15 = lane & 15, lk = lane >> 4;

    f32x4 acc[2][8];
    #pragma unroll
    for (int mh = 0; mh < 2; mh++)
        #pragma unroll
        for (int nt = 0; nt < 8; nt++) acc[mh][nt] = {0.f, 0.f, 0.f, 0.f};

    const unsigned short* bh_src = whk + (size_t)n0 * 32;
    const unsigned short* bl_src = wlk + (size_t)n0 * 32;
    const unsigned short* ah_base = dhk + (size_t)(m0 >> 6) * 2048 + lk * 8;
    const unsigned short* al_base = dlk + (size_t)(m0 >> 6) * 2048 + lk * 8;

    // prologue: stage chunk 0 into buffer 0 (8 waves x 2 KB per array)
    {
        const char* gh = (const char*)bh_src;
        const char* gl = (const char*)bl_src;
        #pragma unroll
        for (int c = 0; c < 2; c++) {
            const int ob = wid * 2048 + c * 1024;
            async16((char*)&BhL[0][0] + ob, gh + ob + lane * 16);
            async16((char*)&BlL[0][0] + ob, gl + ob + lane * 16);
        }
    }
    __syncthreads();

    for (int kc = 0; kc < 16; kc++) {
        const int cur = kc & 1;
        bf16x8 afh[2], afl[2];
        {   // A fragments (issued first)
            const unsigned short* ah = ah_base + (size_t)kc * 32768;
            const unsigned short* al = al_base + (size_t)kc * 32768;
            const int r = wr * 16 + l15;
            #pragma unroll
            for (int mh = 0; mh < 2; mh++) {
                afh[mh] = *(const bf16x8*)(ah + mh * 2048 + r * 32);
                afl[mh] = *(const bf16x8*)(al + mh * 2048 + r * 32);
            }
        }
        if (kc < 15) {   // stage next chunk into the other buffer
            const size_t cb = (size_t)(kc + 1) * ((size_t)VP_ * 32);
            const char* gh = (const char*)(bh_src + cb);
            const char* gl = (const char*)(bl_src + cb);
            #pragma unroll
            for (int c = 0; c < 2; c++) {
                const int ob = wid * 2048 + c * 1024;
                async16((char*)&BhL[cur ^ 1][0] + ob, gh + ob + lane * 16);
                async16((char*)&BlL[cur ^ 1][0] + ob, gl + ob + lane * 16);
            }
        }
        #pragma unroll
        for (int nt = 0; nt < 8; nt++) {
            const int nn = wc * 128 + nt * 16 + l15;
            const int bo = nn * 32 + ((lk ^ ((nn >> 1) & 3)) * 8);
            bf16x8 bh = *(const bf16x8*)&BhL[cur][bo];
            bf16x8 bl = *(const bf16x8*)&BlL[cur][bo];
            #pragma unroll
            for (int mh = 0; mh < 2; mh++) {
                acc[mh][nt] = __builtin_amdgcn_mfma_f32_16x16x32_bf16(afh[mh], bh, acc[mh][nt], 0, 0, 0);
                acc[mh][nt] = __builtin_amdgcn_mfma_f32_16x16x32_bf16(afl[mh], bh, acc[mh][nt], 0, 0, 0);
                acc[mh][nt] = __builtin_amdgcn_mfma_f32_16x16x32_bf16(afh[mh], bl, acc[mh][nt], 0, 0, 0);
            }
        }
        __syncthreads();   // drains vmcnt (next stage landed) + readers done
    }

    // ---- epilogue: per-row max/idx ----
    #pragma unroll
    for (int mh = 0; mh < 2; mh++)
        #pragma unroll
        for (int reg = 0; reg < 4; reg++) {
            float bv = -INFINITY; int bi = 0x7fffffff;
            #pragma unroll
            for (int nt = 0; nt < 8; nt++) {
                const int n = n0 + wc * 128 + nt * 16 + l15;
                const float v = (n < V_) ? acc[mh][nt][reg] : -INFINITY;
                if (v > bv || (v == bv && n < bi)) { bv = v; bi = n; }
            }
            #pragma unroll
            for (int mk = 1; mk < 16; mk <<= 1) {
                const float ov = __shfl_xor(bv, mk);
                const int oi = __shfl_xor(bi, mk);
                if (ov > bv || (ov == bv && oi < bi)) { bv = ov; bi = oi; }
            }
            if (l15 == 0) {
                const int rl = mh * 64 + wr * 16 + lk * 4 + reg;
                ep_max[rl][wc] = bv; ep_idx[rl][wc] = bi;
            }
        }
    __syncthreads();
    if (tid < 128) {
        const float a = ep_max[tid][0], b = ep_max[tid][1];
        const int ia = ep_idx[tid][0], ib = ep_idx[tid][1];
        const bool tb = (b > a) || (b == a && ib < ia);
        ep_fin[tid] = tb ? b : a; ep_fidx[tid] = tb ? ib : ia;
    }
    __syncthreads();
    #pragma unroll
    for (int mh = 0; mh < 2; mh++)
        #pragma unroll
        for (int reg = 0; reg < 4; reg++) {
            const int rl = mh * 64 + wr * 16 + lk * 4 + reg;
            const float M = ep_fin[rl];
            const int rel = tgt_out[m0 + rl] - n0;
            float se = 0.f;
            #pragma unroll
            for (int nt = 0; nt < 8; nt++) {
                const int nl = wc * 128 + nt * 16 + l15;
                if (n0 + nl < V_) {
                    const float v = acc[mh][nt][reg];
                    se += expf(v - M);
                    if (nl == rel) tgt_logit[m0 + rl] = v;
                }
            }
            #pragma unroll
            for (int mk = 1; mk < 16; mk <<= 1) se += __shfl_xor(se, mk);
            if (l15 == 0) ep_sum[rl][wc] = se;
        }
    __syncthreads();
    if (tid < 128) {
        part[(size_t)(m0 + tid) * NCH + ch] =
            make_float4(ep_fin[tid], ep_sum[tid][0] + ep_sum[tid][1],
                        __int_as_float(ep_fidx[tid]), 0.f);
    }
}

// ---------------------------------------------------------------------------
// k_read (fallback: in-kernel conversion, row-major dh/dl, grid 3200)
// ---------------------------------------------------------------------------
__global__ __launch_bounds__(256) void k_read(const unsigned short* __restrict__ dh,
                                              const unsigned short* __restrict__ dl,
                                              const float* __restrict__ Wread,
                                              const int* __restrict__ tgt_out,
                                              float4* __restrict__ part,
                                              float* __restrict__ tgt_logit) {
    __shared__ __align__(16) unsigned short Bh[4][256][8];
    __shared__ __align__(16) unsigned short Bl[4][256][8];
    __shared__ __align__(16) unsigned short Ah[4][64][8];
    __shared__ __align__(16) unsigned short Alo[4][64][8];
    __shared__ float ep_max[64][2];
    __shared__ int   ep_idx[64][2];
    __shared__ float ep_fin[64];
    __shared__ int   ep_fidx[64];
    __shared__ float ep_sum[64][2];

    const int xcd = blockIdx.x & 7;
    const int idx = blockIdx.x >> 3;
    const int mi  = idx & 15;
    const int group = idx >> 4;
    const int ch = group * 8 + xcd;
    if (ch >= NCH) return;
    const int m0 = mi * 64, n0 = ch * 256;

    const int tid = threadIdx.x;
    const int lane = tid & 63, wid = tid >> 6;
    const int wr = wid >> 1, wc = wid & 1;
    const int l15 = lane & 15, lk = lane >> 4;

    f32x4 acc[2][8];
    #pragma unroll
    for (int mt = 0; mt < 2; mt++)
        #pragma unroll
        for (int nt = 0; nt < 8; nt++) acc[mt][nt] = {0.f, 0.f, 0.f, 0.f};

    for (int kc = 0; kc < 512; kc += 32) {
        {
            const int n = n0 + tid;
            const float* row = Wread + (size_t)n * 512 + kc;
            #pragma unroll
            for (int g = 0; g < 4; g++) {
                uint4 h4, l4;
                if (n < V_) {
                    float4 p0 = *(const float4*)(row + g * 8);
                    float4 p1 = *(const float4*)(row + g * 8 + 4);
                    float v[8] = {p0.x, p0.y, p0.z, p0.w, p1.x, p1.y, p1.z, p1.w};
                    unsigned int hb[8], lb[8];
                    #pragma unroll
                    for (int e = 0; e < 8; e++) {
                        hb[e] = f2bf(v[e]);
                        lb[e] = f2bf(v[e] - bf2f((unsigned short)hb[e]));
                    }
                    h4 = make_uint4(hb[0] | (hb[1] << 16), hb[2] | (hb[3] << 16),
                                    hb[4] | (hb[5] << 16), hb[6] | (hb[7] << 16));
                    l4 = make_uint4(lb[0] | (lb[1] << 16), lb[2] | (lb[3] << 16),
                                    lb[4] | (lb[5] << 16), lb[6] | (lb[7] << 16));
                } else {
                    h4 = make_uint4(0, 0, 0, 0);
                    l4 = make_uint4(0, 0, 0, 0);
                }
                *(uint4*)&Bh[g][tid][0] = h4;
                *(uint4*)&Bl[g][tid][0] = l4;
            }
        }
        {
            const int row = tid >> 2, g = tid & 3;
            *(uint4*)&Ah[g][row][0]  = *(const uint4*)(dh + (size_t)(m0 + row) * 512 + kc + g * 8);
            *(uint4*)&Alo[g][row][0] = *(const uint4*)(dl + (size_t)(m0 + row) * 512 + kc + g * 8);
        }
        __syncthreads();
        {
            bf16x8 afh[2], afl[2];
            #pragma unroll
            for (int mt = 0; mt < 2; mt++) {
                const int r = wr * 32 + mt * 16 + l15;
                afh[mt] = *(const bf16x8*)&Ah[lk][r][0];
                afl[mt] = *(const bf16x8*)&Alo[lk][r][0];
            }
            #pragma unroll
            for (int nt = 0; nt < 8; nt++) {
                const int nn = wc * 128 + nt * 16 + l15;
                bf16x8 bh = *(const bf16x8*)&Bh[lk][nn][0];
                bf16x8 bl = *(const bf16x8*)&Bl[lk][nn][0];
                #pragma unroll
                for (int mt = 0; mt < 2; mt++) {
                    acc[mt][nt] = __builtin_amdgcn_mfma_f32_16x16x32_bf16(afh[mt], bh, acc[mt][nt], 0, 0, 0);
                    acc[mt][nt] = __builtin_amdgcn_mfma_f32_16x16x32_bf16(afl[mt], bh, acc[mt][nt], 0, 0, 0);
                    acc[mt][nt] = __builtin_amdgcn_mfma_f32_16x16x32_bf16(afh[mt], bl, acc[mt][nt], 0, 0, 0);
                }
            }
        }
        __syncthreads();
    }

    #pragma unroll
    for (int mt = 0; mt < 2; mt++)
        #pragma unroll
        for (int reg = 0; reg < 4; reg++) {
            float bv = -INFINITY; int bi = 0x7fffffff;
            #pragma unroll
            for (int nt = 0; nt < 8; nt++) {
                const int n = n0 + wc * 128 + nt * 16 + l15;
                const float v = (n < V_) ? acc[mt][nt][reg] : -INFINITY;
                if (v > bv || (v == bv && n < bi)) { bv = v; bi = n; }
            }
            #pragma unroll
            for (int mk = 1; mk < 16; mk <<= 1) {
                const float ov = __shfl_xor(bv, mk);
                const int oi = __shfl_xor(bi, mk);
                if (ov > bv || (ov == bv && oi < bi)) { bv = ov; bi = oi; }
            }
            if (l15 == 0) {
                const int rl = wr * 32 + mt * 16 + lk * 4 + reg;
                ep_max[rl][wc] = bv; ep_idx[rl][wc] = bi;
            }
        }
    __syncthreads();
    if (tid < 64) {
        const float a = ep_max[tid][0], b = ep_max[tid][1];
        const int ia = ep_idx[tid][0], ib = ep_idx[tid][1];
        const bool tb = (b > a) || (b == a && ib < ia);
        ep_fin[tid] = tb ? b : a; ep_fidx[tid] = tb ? ib : ia;
    }
    __syncthreads();
    #pragma unroll
    for (int mt = 0; mt < 2; mt++)
        #pragma unroll
        for (int reg = 0; reg < 4; reg++) {
            const int rl = wr * 32 + mt * 16 + lk * 4 + reg;
            const float M = ep_fin[rl];
            const int rel = tgt_out[m0 + rl] - n0;
            float se = 0.f;
            #pragma unroll
            for (int nt = 0; nt < 8; nt++) {
                const int nl = wc * 128 + nt * 16 + l15;
                if (n0 + nl < V_) {
                    const float v = acc[mt][nt][reg];
                    se += expf(v - M);
                    if (nl == rel) tgt_logit[m0 + rl] = v;
                }
            }
            #pragma unroll
            for (int mk = 1; mk < 16; mk <<= 1) se += __shfl_xor(se, mk);
            if (l15 == 0) ep_sum[rl][wc] = se;
        }
    __syncthreads();
    if (tid < 64) {
        part[(size_t)(m0 + tid) * NCH + ch] =
            make_float4(ep_fin[tid], ep_sum[tid][0] + ep_sum[tid][1],
                        __int_as_float(ep_fidx[tid]), 0.f);
    }
}

// ---------------------------------------------------------------------------
// k_merge: combine chunk partials -> loss + argmax
// ---------------------------------------------------------------------------
__global__ __launch_bounds__(256) void k_merge(const float4* __restrict__ part,
                                               const float* __restrict__ tgt_logit,
                                               const int* __restrict__ tgt_out,
                                               float* __restrict__ out) {
    const int tid = threadIdx.x;
    const int w = tid >> 6, lane = tid & 63;
    const int row = blockIdx.x * 4 + w;
    float bm = -INFINITY; int bi = 0x7fffffff;
    for (int ch = lane; ch < NCH; ch += 64) {
        const float4 p = part[(size_t)row * NCH + ch];
        const int pi = __float_as_int(p.z);
        if (p.x > bm || (p.x == bm && pi < bi)) { bm = p.x; bi = pi; }
    }
    #pragma unroll
    for (int mk = 1; mk < 64; mk <<= 1) {
        const float ov = __shfl_xor(bm, mk);
        const int oi = __shfl_xor(bi, mk);
        if (ov > bm || (ov == bm && oi < bi)) { bm = ov; bi = oi; }
    }
    float sum = 0.f;
    for (int ch = lane; ch < NCH; ch += 64) {
        const float4 p = part[(size_t)row * NCH + ch];
        sum += p.y * expf(p.x - bm);
    }
    #pragma unroll
    for (int mk = 1; mk < 64; mk <<= 1) sum += __shfl_xor(sum, mk);
    if (lane == 0) {
        const float lse = bm + logf(sum);
        const int tg = tgt_out[row];
        const float loss = (tg != 0) ? (lse - tgt_logit[row]) : 0.f;
        out[row] = loss;
        out[1024 + row] = (float)bi;
    }
}

// ---------------------------------------------------------------------------
extern "C" void kernel_launch(void* const* d_in, const int* in_sizes, int n_in,
                              void* d_out, int out_size, void* d_ws, size_t ws_size,
                              hipStream_t stream) {
    const int* tgt_in = (const int*)d_in[0];
    const int* tgt_out = (const int*)d_in[1];
    const int* src_lens = (const int*)d_in[2];
    const float* src = (const float*)d_in[3];
    const float* last_state = (const float*)d_in[4];
    const float* last_cell = (const float*)d_in[5];
    const float* emb = (const float*)d_in[6];
    const float* Wih = (const float*)d_in[7];
    const float* Whh = (const float*)d_in[8];
    const float* bih = (const float*)d_in[9];
    const float* bhh = (const float*)d_in[10];
    const float* Wattn = (const float*)d_in[11];
    const float* Wgen = (const float*)d_in[12];
    const float* bgen = (const float*)d_in[13];
    const float* Wread = (const float*)d_in[14];
    float* out = (float*)d_out;

    float* ws = (float*)d_ws;
    float* G0T      = ws;                    // 2,097,152 f
    float* U        = G0T + 2097152;         // 3,276,800 f
    float* WaRT     = U + 3276800;           // 262,144 f
    unsigned short* dh  = (unsigned short*)(WaRT + 262144);  // 524,288 u16
    unsigned short* dl  = dh + 524288;
    unsigned short* dhk = dl + 524288;       // chunk-major
    unsigned short* dlk = dhk + 524288;
    float* h_hist   = (float*)(dlk + 524288);
    float* att_hist = h_hist + 524288;
    float* xT       = att_hist + 524288;     // 49,152 f
    float* h_b      = xT + 49152;            // 16,384 f
    float* scb      = h_b + 16384;           // 8,192 f
    float4* part    = (float4*)(scb + 8192); // 200,704 float4
    float* tgtl     = ((float*)part) + 802816; // 1,024 f
    int* bar        = (int*)(tgtl + 1024);     // 2,048 ints
    unsigned short* whk = (unsigned short*)(bar + 2048);   // VP_*512 u16
    unsigned short* wlk = whk + (size_t)VP_ * 512;
    // prologue/dec bf16 operands
    unsigned short* sh    = wlk + (size_t)VP_ * 512;  // 3,276,800 u16
    unsigned short* sl    = sh + 3276800;
    unsigned short* wah   = sl + 3276800;             // 262,144
    unsigned short* wal   = wah + 262144;
    unsigned short* wih_h = wal + 262144;             // 1,048,576
    unsigned short* wih_l = wih_h + 1048576;
    unsigned short* eh    = wih_l + 1048576;          // 524,288
    unsigned short* el    = eh + 524288;
    unsigned short* wgh   = el + 524288;              // 786,432
    unsigned short* wgl   = wgh + 786432;
    unsigned short* hh    = wgl + 786432;             // 524,288
    unsigned short* hl    = hh + 524288;
    unsigned short* ath   = hl + 524288;
    unsigned short* atl   = ath + 524288;

    const size_t need = (size_t)((char*)(atl + 524288) - (char*)ws);
    const int pre = (ws_size >= need) ? 1 : 0;

    hipMemsetAsync(bar, 0, 8192, stream);

    k_init<<<64, 256, 0, stream>>>(last_state, xT);
    if (pre) {
        k_cvt<<<(CVT_R4 + 255) / 256, 256, 0, stream>>>(src, Wattn, Wih, emb, Wgen, tgt_in,
                                                        sh, sl, wah, wal, wih_h, wih_l,
                                                        eh, el, wgh, wgl);
        k_gbt<<<200, 256, 0, stream>>>(sh, sl, wah, wal, nullptr, nullptr, U, 2, 0);
        k_gbt<<<128, 256, 0, stream>>>(eh, el, wih_h, wih_l, bih, bhh, G0T, 8, 1);
    } else {
        k_g0<<<dim3(16, 16), 256, 0, stream>>>(tgt_in, emb, Wih, bih, bhh, G0T);
        k_u<<<dim3(100, 4), 256, 0, stream>>>(src, Wattn, U);
    }
    k_tr<<<dim3(16, 16), 256, 0, stream>>>(Wattn, WaRT);
    if (pre)
        k_wconv<<<12544, 256, 0, stream>>>(Wread, whk, wlk);

    k_scan<<<256, 512, 0, stream>>>(G0T, U, WaRT, Wih, Whh, src, src_lens, last_cell,
                                    xT, h_b, scb, h_hist, att_hist,
                                    hh, hl, ath, atl, pre, bar);

    if (pre) {
        k_gbt_dec<<<32, 256, 0, stream>>>(eh, el, hh, hl, ath, atl, wgh, wgl, bgen, dhk, dlk);
        k_read_pre<<<1600, 512, 0, stream>>>(dhk, dlk, whk, wlk, tgt_out, part, tgtl);
    } else {
        k_dec<<<dim3(16, 4), 256, 0, stream>>>(tgt_in, emb, h_hist, att_hist, Wgen, bgen, dh, dl);
        k_read<<<3200, 256, 0, stream>>>(dh, dl, Wread, tgt_out, part, tgtl);
    }
    k_merge<<<256, 256, 0, stream>>>(part, tgtl, tgt_out, out);
}